// Round 4
// baseline (695.985 us; speedup 1.0000x reference)
//
#include <hip/hip_runtime.h>

// B=8 N=96 H=8 HS=32 NS=256.  bf16 MFMA 16x16x32 for all edge-side matmuls.
// v4: occupancy attack. edge_update j-split (jtile=48, LDS 37.8KB, 4 blocks/CU);
// node_attn widened to 512 threads (8 waves); prep_frags LDS-staged coalesced.

#define DI __device__ __forceinline__

typedef float f32x4 __attribute__((ext_vector_type(4)));
typedef short bf16x8 __attribute__((ext_vector_type(8)));

DI unsigned short f2bf(float f) {
  union { float f; unsigned u; } v; v.f = f;
  return (unsigned short)((v.u + 0x7FFFu + ((v.u >> 16) & 1u)) >> 16);
}
DI float bf2f(unsigned short h) {
  union { unsigned u; float f; } v; v.u = ((unsigned)h) << 16;
  return v.f;
}

#define LDE 264            // padded bf16 row stride
#define SCALE 0.17677669529663687f   // 1/sqrt(32)

#define MFMA(A, B, C) __builtin_amdgcn_mfma_f32_16x16x32_bf16((A), (B), (C), 0, 0, 0)

// ---------------------------------------------------------------------------
// K0: pack weights into bf16 MFMA B-fragment layout (LDS-staged, coalesced).
// frag[( (kt*NT + nt)*64 + l )*8 + i] = W[kt*32 + (l>>4)*8 + i][nt*16 + (l&15)]
// grid = 64: blockIdx = matslot*8 + kt. matslot: 0-2 We, 3-5 Wee, 6 EL1, 7 EL2.
// ---------------------------------------------------------------------------
__global__ __launch_bounds__(256)
void prep_frags(const float* __restrict__ We_w, const float* __restrict__ Wee_w,
                const float* __restrict__ EL1_w, const float* __restrict__ EL2_w,
                unsigned short* __restrict__ fb)
{
  __shared__ float Wl[32 * 256];
  const int blk = blockIdx.x, kt = blk & 7, ms = blk >> 3;
  const float* src; unsigned short* dst; int NT, ntbase;
  if (ms < 3)       { src = We_w  + ms * 65536;       dst = fb;          NT = 48; ntbase = ms * 16; }
  else if (ms < 6)  { src = Wee_w + (ms - 3) * 65536; dst = fb + 196608; NT = 48; ntbase = (ms - 3) * 16; }
  else if (ms == 6) { src = EL1_w;                    dst = fb + 393216; NT = 16; ntbase = 0; }
  else              { src = EL2_w;                    dst = fb + 458752; NT = 16; ntbase = 0; }
  const int t = threadIdx.x;
  for (int u = t; u < 32 * 64; u += 256) {
    const int r = u >> 6, c4 = (u & 63) << 2;
    *(float4*)(Wl + r * 256 + c4) = *(const float4*)(src + (kt * 32 + r) * 256 + c4);
  }
  __syncthreads();
  for (int u = t; u < 16 * 64; u += 256) {
    const int ntl = u >> 6, l = u & 63;
    const int kb = (l >> 4) << 3, c = ntl * 16 + (l & 15);
    unsigned short tmp[8];
    #pragma unroll
    for (int i = 0; i < 8; ++i) tmp[i] = f2bf(Wl[(kb + i) * 256 + c]);
    const int nt = ntbase + ntl;
    *(uint4*)(dst + ((size_t)(kt * NT + nt) * 64 + l) * 8) = *(const uint4*)tmp;
  }
}

// ---------------------------------------------------------------------------
// K1: nQ/nK/nV = node @ Wn_w[q] + Wn_b[q], stored as [B,H,N,HS].
// ---------------------------------------------------------------------------
__global__ __launch_bounds__(256)
void node_qkv(const float* __restrict__ node, const float* __restrict__ Ww,
              const float* __restrict__ Wb, float* __restrict__ nQ,
              float* __restrict__ nK, float* __restrict__ nV)
{
  __shared__ float x[4][256];
  const int t = threadIdx.x, r0 = blockIdx.x * 4;
  #pragma unroll
  for (int rr = 0; rr < 4; ++rr) x[rr][t] = node[(r0 + rr) * 256 + t];
  __syncthreads();
  float a0[4], a1[4], a2[4];
  #pragma unroll
  for (int rr = 0; rr < 4; ++rr) { a0[rr] = Wb[t]; a1[rr] = Wb[256 + t]; a2[rr] = Wb[512 + t]; }
  for (int k = 0; k < 256; ++k) {
    const float w0 = Ww[k * 256 + t], w1 = Ww[65536 + k * 256 + t], w2 = Ww[131072 + k * 256 + t];
    #pragma unroll
    for (int rr = 0; rr < 4; ++rr) {
      const float xv = x[rr][k];
      a0[rr] += xv * w0; a1[rr] += xv * w1; a2[rr] += xv * w2;
    }
  }
  const int h = t >> 5, c = t & 31;
  #pragma unroll
  for (int rr = 0; rr < 4; ++rr) {
    const int row = r0 + rr, b = row / 96, j = row - b * 96;
    const int oi = ((b * 8 + h) * 96 + j) * 32 + c;
    nQ[oi] = a0[rr]; nK[oi] = a1[rr]; nV[oi] = a2[rr];
  }
}

// ---------------------------------------------------------------------------
// K2: fused node attention for one (b,i). 512 threads (8 waves). LDS 57856 B.
//  Phase A: wave w owns head w; Q,K projections folded into score dot.
//  softmax; Phase B: wave w owns col tiles {w, w+8}; attn@V in registers.
// ---------------------------------------------------------------------------
__global__ __launch_bounds__(512, 4)
void node_attn(const float* __restrict__ edge, const float* __restrict__ We_b,
               const unsigned short* __restrict__ WeF,
               const float* __restrict__ nQ, const float* __restrict__ nK,
               const float* __restrict__ nV, float* __restrict__ attw)
{
  __shared__ unsigned short Elds[96 * LDE];   // 50688 B
  __shared__ float sc[768];                   // 3072 B
  __shared__ float nQp[256];                  // 1024 B
  __shared__ float bias[768];                 // 3072 B

  const int tid = threadIdx.x, lane = tid & 63, wid = tid >> 6;
  const int bi = blockIdx.x, b = bi / 96, i = bi - b * 96;

  if (tid < 256) nQp[tid] = nQ[((b * 8 + (tid >> 5)) * 96 + i) * 32 + (tid & 31)];
  for (int u = tid; u < 768; u += 512) bias[u] = We_b[u];

  const float* Erow = edge + (size_t)bi * 24576;
  for (int u = tid; u < 96 * 64; u += 512) {
    const int j = u >> 6, g = u & 63;
    const float4 v = *(const float4*)(Erow + j * 256 + g * 4);
    const unsigned lo = (unsigned)f2bf(v.x) | ((unsigned)f2bf(v.y) << 16);
    const unsigned hi = (unsigned)f2bf(v.z) | ((unsigned)f2bf(v.w) << 16);
    *(uint2*)(Elds + j * LDE + g * 4) = make_uint2(lo, hi);
  }
  __syncthreads();

  // ---- Phase A: head h = wid; Q,K projections folded into score dot ----
  for (int mt = 0; mt < 6; ++mt) {
    bf16x8 afr[8];
    const unsigned short* ab = Elds + (mt * 16 + (lane & 15)) * LDE + ((lane >> 4) << 3);
    #pragma unroll
    for (int kt = 0; kt < 8; ++kt) afr[kt] = *(const bf16x8*)(ab + kt * 32);
    const int h = wid;
    f32x4 q0 = {0.f, 0.f, 0.f, 0.f}, q1 = q0, k0 = q0, k1 = q0;
    const unsigned short* wq0 = WeF + ((2 * h) * 64 + lane) * 8;
    const unsigned short* wq1 = WeF + ((2 * h + 1) * 64 + lane) * 8;
    const unsigned short* wk0 = WeF + ((16 + 2 * h) * 64 + lane) * 8;
    const unsigned short* wk1 = WeF + ((17 + 2 * h) * 64 + lane) * 8;
    #pragma unroll
    for (int kt = 0; kt < 8; ++kt) {
      q0 = MFMA(afr[kt], *(const bf16x8*)(wq0 + kt * 24576), q0);
      q1 = MFMA(afr[kt], *(const bf16x8*)(wq1 + kt * 24576), q1);
      k0 = MFMA(afr[kt], *(const bf16x8*)(wk0 + kt * 24576), k0);
      k1 = MFMA(afr[kt], *(const bf16x8*)(wk1 + kt * 24576), k1);
    }
    const int c0 = h * 32 + (lane & 15), c1 = c0 + 16;
    const float qb0 = bias[c0] + nQp[c0], qb1 = bias[c1] + nQp[c1];
    const float kb0 = bias[256 + c0], kb1 = bias[256 + c1];
    float prod[4];
    #pragma unroll
    for (int r = 0; r < 4; ++r) {
      const int j = mt * 16 + ((lane >> 4) << 2) + r;
      const int g = ((b * 8 + h) * 96 + j) * 32;
      const float k0v = k0[r] + kb0 + nK[g + (lane & 15)];
      const float k1v = k1[r] + kb1 + nK[g + 16 + (lane & 15)];
      prod[r] = (q0[r] + qb0) * k0v + (q1[r] + qb1) * k1v;
    }
    #pragma unroll
    for (int m = 1; m < 16; m <<= 1) {
      #pragma unroll
      for (int r = 0; r < 4; ++r) prod[r] += __shfl_xor(prod[r], m, 64);
    }
    if ((lane & 15) == 0) {
      #pragma unroll
      for (int r = 0; r < 4; ++r)
        sc[h * 96 + mt * 16 + ((lane >> 4) << 2) + r] = prod[r];
    }
  }
  __syncthreads();

  // ---- softmax: wave wid = head; 96 j over 64 lanes ----
  {
    const int h = wid;
    const float s0 = sc[h * 96 + lane] * SCALE;
    const float s1 = (lane < 32) ? sc[h * 96 + 64 + lane] * SCALE : -1e30f;
    float mx = fmaxf(s0, s1);
    #pragma unroll
    for (int m = 1; m < 64; m <<= 1) mx = fmaxf(mx, __shfl_xor(mx, m, 64));
    const float e0 = __expf(s0 - mx);
    const float e1 = (lane < 32) ? __expf(s1 - mx) : 0.f;
    float sm = e0 + e1;
    #pragma unroll
    for (int m = 1; m < 64; m <<= 1) sm += __shfl_xor(sm, m, 64);
    const float inv = 1.f / sm;
    sc[h * 96 + lane] = e0 * inv;
    if (lane < 32) sc[h * 96 + 64 + lane] = e1 * inv;
  }
  __syncthreads();

  // ---- Phase B: wave wid owns col tiles {wid, wid+8}; attn@V in regs ----
  {
    float nn[2] = {0.f, 0.f};
    for (int mt = 0; mt < 6; ++mt) {
      bf16x8 afr[8];
      const unsigned short* ab = Elds + (mt * 16 + (lane & 15)) * LDE + ((lane >> 4) << 3);
      #pragma unroll
      for (int kt = 0; kt < 8; ++kt) afr[kt] = *(const bf16x8*)(ab + kt * 32);
      const int nt0 = 32 + wid, nt1 = 40 + wid;
      f32x4 a0 = {0.f, 0.f, 0.f, 0.f}, a1 = a0;
      const unsigned short* wb0 = WeF + (nt0 * 64 + lane) * 8;
      const unsigned short* wb1 = WeF + (nt1 * 64 + lane) * 8;
      #pragma unroll
      for (int kt = 0; kt < 8; ++kt) {
        a0 = MFMA(afr[kt], *(const bf16x8*)(wb0 + kt * 24576), a0);
        a1 = MFMA(afr[kt], *(const bf16x8*)(wb1 + kt * 24576), a1);
      }
      #pragma unroll
      for (int s = 0; s < 2; ++s) {
        const f32x4 aa = s ? a1 : a0;
        const int col = (wid + (s << 3)) * 16 + (lane & 15);
        const int h = col >> 5, cc = col & 31;
        const float base = bias[512 + col];
        #pragma unroll
        for (int r = 0; r < 4; ++r) {
          const int j = mt * 16 + ((lane >> 4) << 2) + r;
          const float v = aa[r] + base + nV[((b * 8 + h) * 96 + j) * 32 + cc];
          nn[s] += sc[h * 96 + j] * v;
        }
      }
    }
    #pragma unroll
    for (int s = 0; s < 2; ++s) {
      nn[s] += __shfl_xor(nn[s], 16, 64);
      nn[s] += __shfl_xor(nn[s], 32, 64);
    }
    if (lane < 16) {
      attw[(size_t)bi * 256 + wid * 16 + lane] = nn[0];
      attw[(size_t)bi * 256 + (wid + 8) * 16 + lane] = nn[1];
    }
  }
}

// ---------------------------------------------------------------------------
// K3: node FFN + residual + LayerNorm. 96 blocks x 256 threads, 8 rows each.
// ---------------------------------------------------------------------------
__global__ __launch_bounds__(256)
void node_ffn_ln(const float* __restrict__ attw, const float* __restrict__ node,
                 const float* __restrict__ W1, const float* __restrict__ B1,
                 const float* __restrict__ W2, const float* __restrict__ B2,
                 const float* __restrict__ g, const float* __restrict__ be,
                 float* __restrict__ node_out)
{
  __shared__ float xa[8][256];
  __shared__ float h1[8][256];
  __shared__ float xr[8][256];
  const int t = threadIdx.x, r0 = blockIdx.x * 8;
  #pragma unroll
  for (int rr = 0; rr < 8; ++rr) xa[rr][t] = attw[(r0 + rr) * 256 + t];
  __syncthreads();
  float acc[8];
  #pragma unroll
  for (int rr = 0; rr < 8; ++rr) acc[rr] = B1[t];
  for (int k = 0; k < 256; ++k) {
    const float w = W1[k * 256 + t];
    #pragma unroll
    for (int rr = 0; rr < 8; ++rr) acc[rr] += xa[rr][k] * w;
  }
  #pragma unroll
  for (int rr = 0; rr < 8; ++rr) h1[rr][t] = fmaxf(acc[rr], 0.f);
  __syncthreads();
  #pragma unroll
  for (int rr = 0; rr < 8; ++rr) acc[rr] = B2[t];
  for (int k = 0; k < 256; ++k) {
    const float w = W2[k * 256 + t];
    #pragma unroll
    for (int rr = 0; rr < 8; ++rr) acc[rr] += h1[rr][k] * w;
  }
  #pragma unroll
  for (int rr = 0; rr < 8; ++rr) xr[rr][t] = node[(r0 + rr) * 256 + t] + acc[rr];
  __syncthreads();
  const int wid = t >> 6, lane = t & 63;
  const float4 gv = *(const float4*)(g + (lane << 2));
  const float4 bv = *(const float4*)(be + (lane << 2));
  for (int rr = wid * 2; rr < wid * 2 + 2; ++rr) {
    const float4 xv = *(const float4*)(&xr[rr][lane << 2]);
    float s = xv.x + xv.y + xv.z + xv.w;
    float sq = xv.x * xv.x + xv.y * xv.y + xv.z * xv.z + xv.w * xv.w;
    #pragma unroll
    for (int m = 1; m < 64; m <<= 1) { s += __shfl_xor(s, m, 64); sq += __shfl_xor(sq, m, 64); }
    const float mean = s * (1.f / 256.f);
    const float rs = rsqrtf(sq * (1.f / 256.f) - mean * mean + 1e-5f);
    float4 o;
    o.x = (xv.x - mean) * rs * gv.x + bv.x;
    o.y = (xv.y - mean) * rs * gv.y + bv.y;
    o.z = (xv.z - mean) * rs * gv.z + bv.z;
    o.w = (xv.w - mean) * rs * gv.w + bv.w;
    *(float4*)(node_out + (r0 + rr) * 256 + (lane << 2)) = o;
  }
}

// ---------------------------------------------------------------------------
// K4: n1Q..n2V = node_out @ {Wn1,Wn2} (+bias), stored [B,H,N,HS].
// ---------------------------------------------------------------------------
__global__ __launch_bounds__(256)
void node_proj6(const float* __restrict__ nodeo,
                const float* __restrict__ W1, const float* __restrict__ B1,
                const float* __restrict__ W2, const float* __restrict__ B2,
                float* __restrict__ n1Q, float* __restrict__ n1K, float* __restrict__ n1V,
                float* __restrict__ n2Q, float* __restrict__ n2K, float* __restrict__ n2V)
{
  __shared__ float x[4][256];
  const int t = threadIdx.x, r0 = blockIdx.x * 4;
  #pragma unroll
  for (int rr = 0; rr < 4; ++rr) x[rr][t] = nodeo[(r0 + rr) * 256 + t];
  __syncthreads();
  float a[6][4];
  #pragma unroll
  for (int rr = 0; rr < 4; ++rr) {
    a[0][rr] = B1[t]; a[1][rr] = B1[256 + t]; a[2][rr] = B1[512 + t];
    a[3][rr] = B2[t]; a[4][rr] = B2[256 + t]; a[5][rr] = B2[512 + t];
  }
  for (int k = 0; k < 256; ++k) {
    const float w0 = W1[k * 256 + t], w1 = W1[65536 + k * 256 + t], w2 = W1[131072 + k * 256 + t];
    const float w3 = W2[k * 256 + t], w4 = W2[65536 + k * 256 + t], w5 = W2[131072 + k * 256 + t];
    #pragma unroll
    for (int rr = 0; rr < 4; ++rr) {
      const float xv = x[rr][k];
      a[0][rr] += xv * w0; a[1][rr] += xv * w1; a[2][rr] += xv * w2;
      a[3][rr] += xv * w3; a[4][rr] += xv * w4; a[5][rr] += xv * w5;
    }
  }
  const int h = t >> 5, c = t & 31;
  #pragma unroll
  for (int rr = 0; rr < 4; ++rr) {
    const int row = r0 + rr, b = row / 96, j = row - b * 96;
    const int oi = ((b * 8 + h) * 96 + j) * 32 + c;
    n1Q[oi] = a[0][rr]; n1K[oi] = a[1][rr]; n1V[oi] = a[2][rr];
    n2Q[oi] = a[3][rr]; n2K[oi] = a[4][rr]; n2V[oi] = a[5][rr];
  }
}

// ---------------------------------------------------------------------------
// K5: fused edge update for one (b,i,jt): 48-row j-tile. Static LDS = 37760 B
// -> 4 blocks/CU. Phases as v3 but 3 mt-tiles. LN fused into EL2 epilogue.
// ---------------------------------------------------------------------------
__global__ __launch_bounds__(256, 4)
void edge_update(const float* __restrict__ edge, const float* __restrict__ Wee_b,
                 const unsigned short* __restrict__ WeeF,
                 const unsigned short* __restrict__ EL1F,
                 const unsigned short* __restrict__ EL2F,
                 const float* __restrict__ EL1_b, const float* __restrict__ EL2_b,
                 const float* __restrict__ n1Q, const float* __restrict__ n1K, const float* __restrict__ n1V,
                 const float* __restrict__ n2Q, const float* __restrict__ n2K, const float* __restrict__ n2V,
                 const float* __restrict__ lng, const float* __restrict__ lnb,
                 float* __restrict__ edge_out)
{
  __shared__ unsigned short Elds[48 * LDE];   // 25344 B (E -> attw_e -> hidden)
  __shared__ float se[384];                   // 1536 B
  __shared__ float n1p[768];                  // 3072 B
  __shared__ float bias[768];                 // 3072 B
  __shared__ float b12[512];                  // 2048 B
  __shared__ float lg[256], lb[256];          // 2048 B
  __shared__ float psum[4][16], psq[4][16];   // 512 B
  __shared__ float statm[16], statr[16];      // 128 B

  const int tid = threadIdx.x, lane = tid & 63, wid = tid >> 6;
  const int bi = blockIdx.x >> 1, jt = blockIdx.x & 1;
  const int b = bi / 96, i = bi - b * 96, jbase = jt * 48;

  for (int u = tid; u < 768; u += 256) {
    bias[u] = Wee_b[u];
    const int q = u >> 8, cn = u & 255, h = cn >> 5, c = cn & 31;
    const float* s = (q == 0) ? n1Q : (q == 1) ? n1K : n1V;
    n1p[u] = s[((b * 8 + h) * 96 + i) * 32 + c];
  }
  for (int u = tid; u < 512; u += 256) b12[u] = (u < 256) ? EL1_b[u] : EL2_b[u - 256];
  lg[tid] = lng[tid]; lb[tid] = lnb[tid];

  const float* Erow = edge + (size_t)bi * 24576 + jbase * 256;
  for (int u = tid; u < 48 * 64; u += 256) {
    const int j = u >> 6, g = u & 63;
    const float4 v = *(const float4*)(Erow + j * 256 + g * 4);
    const unsigned lo = (unsigned)f2bf(v.x) | ((unsigned)f2bf(v.y) << 16);
    const unsigned hi = (unsigned)f2bf(v.z) | ((unsigned)f2bf(v.w) << 16);
    *(uint2*)(Elds + j * LDE + g * 4) = make_uint2(lo, hi);
  }
  __syncthreads();

  // ---- Phase A: Qe,Ke projections folded into se dot ----
  for (int mt = 0; mt < 3; ++mt) {
    bf16x8 afr[8];
    const unsigned short* ab = Elds + (mt * 16 + (lane & 15)) * LDE + ((lane >> 4) << 3);
    #pragma unroll
    for (int kt = 0; kt < 8; ++kt) afr[kt] = *(const bf16x8*)(ab + kt * 32);
    #pragma unroll
    for (int pp = 0; pp < 2; ++pp) {
      const int h = wid + (pp << 2);
      f32x4 q0 = {0.f, 0.f, 0.f, 0.f}, q1 = q0, k0 = q0, k1 = q0;
      const unsigned short* wq0 = WeeF + ((2 * h) * 64 + lane) * 8;
      const unsigned short* wq1 = WeeF + ((2 * h + 1) * 64 + lane) * 8;
      const unsigned short* wk0 = WeeF + ((16 + 2 * h) * 64 + lane) * 8;
      const unsigned short* wk1 = WeeF + ((17 + 2 * h) * 64 + lane) * 8;
      #pragma unroll
      for (int kt = 0; kt < 8; ++kt) {
        q0 = MFMA(afr[kt], *(const bf16x8*)(wq0 + kt * 24576), q0);
        q1 = MFMA(afr[kt], *(const bf16x8*)(wq1 + kt * 24576), q1);
        k0 = MFMA(afr[kt], *(const bf16x8*)(wk0 + kt * 24576), k0);
        k1 = MFMA(afr[kt], *(const bf16x8*)(wk1 + kt * 24576), k1);
      }
      const int c0 = h * 32 + (lane & 15), c1 = c0 + 16;
      const float qb0 = bias[c0] + n1p[c0], qb1 = bias[c1] + n1p[c1];
      const float kb0 = bias[256 + c0] + n1p[256 + c0];
      const float kb1 = bias[256 + c1] + n1p[256 + c1];
      float prod[4];
      #pragma unroll
      for (int r = 0; r < 4; ++r) {
        const int j = mt * 16 + ((lane >> 4) << 2) + r;
        const int g = ((b * 8 + h) * 96 + jbase + j) * 32;
        const float q0v = q0[r] + qb0 + n2Q[g + (lane & 15)];
        const float q1v = q1[r] + qb1 + n2Q[g + 16 + (lane & 15)];
        const float k0v = k0[r] + kb0 + n2K[g + (lane & 15)];
        const float k1v = k1[r] + kb1 + n2K[g + 16 + (lane & 15)];
        prod[r] = q0v * k0v + q1v * k1v;
      }
      #pragma unroll
      for (int m = 1; m < 16; m <<= 1) {
        #pragma unroll
        for (int r = 0; r < 4; ++r) prod[r] += __shfl_xor(prod[r], m, 64);
      }
      if ((lane & 15) == 0) {
        #pragma unroll
        for (int r = 0; r < 4; ++r)
          se[h * 48 + mt * 16 + ((lane >> 4) << 2) + r] = prod[r];
      }
    }
  }
  __syncthreads();

  // ---- silu ----
  for (int u = tid; u < 384; u += 256) {
    const float s = se[u] * SCALE;
    se[u] = s / (1.f + __expf(-s));
  }
  __syncthreads();

  // ---- Phase B: Ve projection, scale by silu, in-place over E tile ----
  for (int mt = 0; mt < 3; ++mt) {
    bf16x8 afr[8];
    const unsigned short* ab = Elds + (mt * 16 + (lane & 15)) * LDE + ((lane >> 4) << 3);
    #pragma unroll
    for (int kt = 0; kt < 8; ++kt) afr[kt] = *(const bf16x8*)(ab + kt * 32);
    float vals[2][2][4];
    int colb[2][2];
    #pragma unroll
    for (int pp = 0; pp < 2; ++pp) {
      const int nt0 = 32 + wid + (pp << 3), nt1 = nt0 + 4;
      f32x4 a0 = {0.f, 0.f, 0.f, 0.f}, a1 = a0;
      const unsigned short* wb0 = WeeF + (nt0 * 64 + lane) * 8;
      const unsigned short* wb1 = WeeF + (nt1 * 64 + lane) * 8;
      #pragma unroll
      for (int kt = 0; kt < 8; ++kt) {
        a0 = MFMA(afr[kt], *(const bf16x8*)(wb0 + kt * 24576), a0);
        a1 = MFMA(afr[kt], *(const bf16x8*)(wb1 + kt * 24576), a1);
      }
      #pragma unroll
      for (int s = 0; s < 2; ++s) {
        const f32x4 aa = s ? a1 : a0;
        const int col = ((s ? nt1 : nt0) - 32) * 16 + (lane & 15);
        const int h = col >> 5, cc = col & 31;
        const float base = bias[512 + col] + n1p[512 + col];
        colb[pp][s] = col;
        #pragma unroll
        for (int r = 0; r < 4; ++r) {
          const int j = mt * 16 + ((lane >> 4) << 2) + r;
          const float v = aa[r] + base + n2V[((b * 8 + h) * 96 + jbase + j) * 32 + cc];
          vals[pp][s][r] = se[h * 48 + j] * v;
        }
      }
    }
    __syncthreads();   // all waves done reading E rows of this tile
    #pragma unroll
    for (int pp = 0; pp < 2; ++pp)
      #pragma unroll
      for (int s = 0; s < 2; ++s)
        #pragma unroll
        for (int r = 0; r < 4; ++r) {
          const int j = mt * 16 + ((lane >> 4) << 2) + r;
          Elds[j * LDE + colb[pp][s]] = f2bf(vals[pp][s][r]);
        }
  }
  __syncthreads();

  // ---- EL1 + relu, in place (attw_e -> hidden) ----
  for (int mt = 0; mt < 3; ++mt) {
    bf16x8 afr[8];
    const unsigned short* ab = Elds + (mt * 16 + (lane & 15)) * LDE + ((lane >> 4) << 3);
    #pragma unroll
    for (int kt = 0; kt < 8; ++kt) afr[kt] = *(const bf16x8*)(ab + kt * 32);
    float vals[2][2][4];
    int colb[2][2];
    #pragma unroll
    for (int pp = 0; pp < 2; ++pp) {
      const int nt0 = wid + (pp << 3), nt1 = nt0 + 4;
      f32x4 a0 = {0.f, 0.f, 0.f, 0.f}, a1 = a0;
      const unsigned short* wb0 = EL1F + (nt0 * 64 + lane) * 8;
      const unsigned short* wb1 = EL1F + (nt1 * 64 + lane) * 8;
      #pragma unroll
      for (int kt = 0; kt < 8; ++kt) {
        a0 = MFMA(afr[kt], *(const bf16x8*)(wb0 + kt * 8192), a0);
        a1 = MFMA(afr[kt], *(const bf16x8*)(wb1 + kt * 8192), a1);
      }
      #pragma unroll
      for (int s = 0; s < 2; ++s) {
        const f32x4 aa = s ? a1 : a0;
        const int col = (s ? nt1 : nt0) * 16 + (lane & 15);
        const float bv = b12[col];
        colb[pp][s] = col;
        #pragma unroll
        for (int r = 0; r < 4; ++r) vals[pp][s][r] = fmaxf(aa[r] + bv, 0.f);
      }
    }
    __syncthreads();
    #pragma unroll
    for (int pp = 0; pp < 2; ++pp)
      #pragma unroll
      for (int s = 0; s < 2; ++s)
        #pragma unroll
        for (int r = 0; r < 4; ++r) {
          const int j = mt * 16 + ((lane >> 4) << 2) + r;
          Elds[j * LDE + colb[pp][s]] = f2bf(vals[pp][s][r]);
        }
  }
  __syncthreads();

  // ---- EL2 + residual + LayerNorm fused, fp32 regs -> edge_out ----
  float* orow = edge_out + (size_t)bi * 24576 + jbase * 256;
  for (int mt = 0; mt < 3; ++mt) {
    bf16x8 afr[8];
    const unsigned short* ab = Elds + (mt * 16 + (lane & 15)) * LDE + ((lane >> 4) << 3);
    #pragma unroll
    for (int kt = 0; kt < 8; ++kt) afr[kt] = *(const bf16x8*)(ab + kt * 32);
    float vals[2][2][4];
    int colb[2][2];
    #pragma unroll
    for (int pp = 0; pp < 2; ++pp) {
      const int nt0 = wid + (pp << 3), nt1 = nt0 + 4;
      f32x4 a0 = {0.f, 0.f, 0.f, 0.f}, a1 = a0;
      const unsigned short* wb0 = EL2F + (nt0 * 64 + lane) * 8;
      const unsigned short* wb1 = EL2F + (nt1 * 64 + lane) * 8;
      #pragma unroll
      for (int kt = 0; kt < 8; ++kt) {
        a0 = MFMA(afr[kt], *(const bf16x8*)(wb0 + kt * 8192), a0);
        a1 = MFMA(afr[kt], *(const bf16x8*)(wb1 + kt * 8192), a1);
      }
      #pragma unroll
      for (int s = 0; s < 2; ++s) {
        const f32x4 aa = s ? a1 : a0;
        const int col = (s ? nt1 : nt0) * 16 + (lane & 15);
        const float bv = b12[256 + col];
        colb[pp][s] = col;
        #pragma unroll
        for (int r = 0; r < 4; ++r) {
          const int j = mt * 16 + ((lane >> 4) << 2) + r;
          vals[pp][s][r] = aa[r] + bv + Erow[j * 256 + col];
        }
      }
    }
    // per-row partial sums (this lane covers 4 cols per row over pp,s)
    #pragma unroll
    for (int r = 0; r < 4; ++r) {
      float s = 0.f, q = 0.f;
      #pragma unroll
      for (int pp = 0; pp < 2; ++pp)
        #pragma unroll
        for (int ss = 0; ss < 2; ++ss) {
          const float v = vals[pp][ss][r];
          s += v; q += v * v;
        }
      #pragma unroll
      for (int m = 1; m < 16; m <<= 1) { s += __shfl_xor(s, m, 64); q += __shfl_xor(q, m, 64); }
      if ((lane & 15) == 0) {
        const int rloc = ((lane >> 4) << 2) + r;
        psum[wid][rloc] = s; psq[wid][rloc] = q;
      }
    }
    __syncthreads();
    if (tid < 16) {
      const float s = psum[0][tid] + psum[1][tid] + psum[2][tid] + psum[3][tid];
      const float q = psq[0][tid] + psq[1][tid] + psq[2][tid] + psq[3][tid];
      const float mean = s * (1.f / 256.f);
      statm[tid] = mean;
      statr[tid] = rsqrtf(q * (1.f / 256.f) - mean * mean + 1e-5f);
    }
    __syncthreads();
    #pragma unroll
    for (int pp = 0; pp < 2; ++pp)
      #pragma unroll
      for (int ss = 0; ss < 2; ++ss) {
        const int col = colb[pp][ss];
        const float gv = lg[col], bvv = lb[col];
        #pragma unroll
        for (int r = 0; r < 4; ++r) {
          const int rloc = ((lane >> 4) << 2) + r;
          const int j = mt * 16 + rloc;
          orow[j * 256 + col] = (vals[pp][ss][r] - statm[rloc]) * statr[rloc] * gv + bvv;
        }
      }
  }
}

// ---------------------------------------------------------------------------
extern "C" void kernel_launch(void* const* d_in, const int* in_sizes, int n_in,
                              void* d_out, int out_size, void* d_ws, size_t ws_size,
                              hipStream_t stream)
{
  (void)in_sizes; (void)n_in; (void)out_size; (void)ws_size;

  const float* node   = (const float*)d_in[0];
  const float* edge   = (const float*)d_in[1];
  const float* Wn_w   = (const float*)d_in[2];
  const float* Wn_b   = (const float*)d_in[3];
  const float* We_w   = (const float*)d_in[4];
  const float* We_b   = (const float*)d_in[5];
  const float* Wn1_w  = (const float*)d_in[6];
  const float* Wn1_b  = (const float*)d_in[7];
  const float* Wn2_w  = (const float*)d_in[8];
  const float* Wn2_b  = (const float*)d_in[9];
  const float* Wee_w  = (const float*)d_in[10];
  const float* Wee_b  = (const float*)d_in[11];
  const float* NL1_w  = (const float*)d_in[12];
  const float* NL1_b  = (const float*)d_in[13];
  const float* NL2_w  = (const float*)d_in[14];
  const float* NL2_b  = (const float*)d_in[15];
  const float* EL1_w  = (const float*)d_in[16];
  const float* EL1_b  = (const float*)d_in[17];
  const float* EL2_w  = (const float*)d_in[18];
  const float* EL2_b  = (const float*)d_in[19];
  const float* NLN1_g = (const float*)d_in[20];
  const float* NLN1_b = (const float*)d_in[21];
  const float* ELN1_g = (const float*)d_in[22];
  const float* ELN1_b = (const float*)d_in[23];

  float* out = (float*)d_out;
  float* node_out = out;               // [8,96,256]
  float* edge_out = out + 196608;      // [8,96,96,256]

  float* wsf = (float*)d_ws;
  float* nQ  = wsf;                float* nK  = wsf + 196608;   float* nV  = wsf + 393216;
  float* n1Q = wsf + 589824;       float* n1K = wsf + 786432;   float* n1V = wsf + 983040;
  float* n2Q = wsf + 1179648;      float* n2K = wsf + 1376256;  float* n2V = wsf + 1572864;
  float* attw = wsf + 1769472;
  unsigned short* fb   = (unsigned short*)(wsf + 1966080);
  unsigned short* WeF  = fb;                 // 196608
  unsigned short* WeeF = fb + 196608;        // 196608
  unsigned short* EL1F = fb + 393216;        // 65536
  unsigned short* EL2F = fb + 458752;        // 65536

  prep_frags<<<64, 256, 0, stream>>>(We_w, Wee_w, EL1_w, EL2_w, fb);
  node_qkv<<<192, 256, 0, stream>>>(node, Wn_w, Wn_b, nQ, nK, nV);
  node_attn<<<768, 512, 0, stream>>>(edge, We_b, WeF, nQ, nK, nV, attw);
  node_ffn_ln<<<96, 256, 0, stream>>>(attw, node, NL1_w, NL1_b, NL2_w, NL2_b,
                                      NLN1_g, NLN1_b, node_out);
  node_proj6<<<192, 256, 0, stream>>>(node_out, Wn1_w, Wn1_b, Wn2_w, Wn2_b,
                                      n1Q, n1K, n1V, n2Q, n2K, n2V);
  edge_update<<<1536, 256, 0, stream>>>(edge, Wee_b, WeeF, EL1F, EL2F,
                                        EL1_b, EL2_b, n1Q, n1K, n1V,
                                        n2Q, n2K, n2V, ELN1_g, ELN1_b, edge_out);
}

// Round 5
// 426.774 us; speedup vs baseline: 1.6308x; 1.6308x over previous
//
#include <hip/hip_runtime.h>

// B=8 N=96 H=8 HS=32 NS=256.  bf16 MFMA 16x16x32 for all edge-side matmuls.
// v5: full-96 edge blocks with 512 threads (16 waves/CU), b->XCD swizzle for
// L2 locality of per-(b,h,j) side reads, coalesced edge_out writeback via
// bf16 LDS staging of the LN output.

#define DI __device__ __forceinline__

typedef float f32x4 __attribute__((ext_vector_type(4)));
typedef short bf16x8 __attribute__((ext_vector_type(8)));

DI unsigned short f2bf(float f) {
  union { float f; unsigned u; } v; v.f = f;
  return (unsigned short)((v.u + 0x7FFFu + ((v.u >> 16) & 1u)) >> 16);
}
DI float bf2f(unsigned short h) {
  union { unsigned u; float f; } v; v.u = ((unsigned)h) << 16;
  return v.f;
}

#define LDE 264            // padded bf16 row stride
#define SCALE 0.17677669529663687f   // 1/sqrt(32)

#define MFMA(A, B, C) __builtin_amdgcn_mfma_f32_16x16x32_bf16((A), (B), (C), 0, 0, 0)

// ---------------------------------------------------------------------------
// K0: pack weights into bf16 MFMA B-fragment layout (LDS-staged, coalesced).
// frag[( (kt*NT + nt)*64 + l )*8 + i] = W[kt*32 + (l>>4)*8 + i][nt*16 + (l&15)]
// ---------------------------------------------------------------------------
__global__ __launch_bounds__(256)
void prep_frags(const float* __restrict__ We_w, const float* __restrict__ Wee_w,
                const float* __restrict__ EL1_w, const float* __restrict__ EL2_w,
                unsigned short* __restrict__ fb)
{
  __shared__ float Wl[32 * 256];
  const int blk = blockIdx.x, kt = blk & 7, ms = blk >> 3;
  const float* src; unsigned short* dst; int NT, ntbase;
  if (ms < 3)       { src = We_w  + ms * 65536;       dst = fb;          NT = 48; ntbase = ms * 16; }
  else if (ms < 6)  { src = Wee_w + (ms - 3) * 65536; dst = fb + 196608; NT = 48; ntbase = (ms - 3) * 16; }
  else if (ms == 6) { src = EL1_w;                    dst = fb + 393216; NT = 16; ntbase = 0; }
  else              { src = EL2_w;                    dst = fb + 458752; NT = 16; ntbase = 0; }
  const int t = threadIdx.x;
  for (int u = t; u < 32 * 64; u += 256) {
    const int r = u >> 6, c4 = (u & 63) << 2;
    *(float4*)(Wl + r * 256 + c4) = *(const float4*)(src + (kt * 32 + r) * 256 + c4);
  }
  __syncthreads();
  for (int u = t; u < 16 * 64; u += 256) {
    const int ntl = u >> 6, l = u & 63;
    const int kb = (l >> 4) << 3, c = ntl * 16 + (l & 15);
    unsigned short tmp[8];
    #pragma unroll
    for (int i = 0; i < 8; ++i) tmp[i] = f2bf(Wl[(kb + i) * 256 + c]);
    const int nt = ntbase + ntl;
    *(uint4*)(dst + ((size_t)(kt * NT + nt) * 64 + l) * 8) = *(const uint4*)tmp;
  }
}

// ---------------------------------------------------------------------------
// K1: nQ/nK/nV = node @ Wn_w[q] + Wn_b[q], stored as [B,H,N,HS].
// ---------------------------------------------------------------------------
__global__ __launch_bounds__(256)
void node_qkv(const float* __restrict__ node, const float* __restrict__ Ww,
              const float* __restrict__ Wb, float* __restrict__ nQ,
              float* __restrict__ nK, float* __restrict__ nV)
{
  __shared__ float x[4][256];
  const int t = threadIdx.x, r0 = blockIdx.x * 4;
  #pragma unroll
  for (int rr = 0; rr < 4; ++rr) x[rr][t] = node[(r0 + rr) * 256 + t];
  __syncthreads();
  float a0[4], a1[4], a2[4];
  #pragma unroll
  for (int rr = 0; rr < 4; ++rr) { a0[rr] = Wb[t]; a1[rr] = Wb[256 + t]; a2[rr] = Wb[512 + t]; }
  for (int k = 0; k < 256; ++k) {
    const float w0 = Ww[k * 256 + t], w1 = Ww[65536 + k * 256 + t], w2 = Ww[131072 + k * 256 + t];
    #pragma unroll
    for (int rr = 0; rr < 4; ++rr) {
      const float xv = x[rr][k];
      a0[rr] += xv * w0; a1[rr] += xv * w1; a2[rr] += xv * w2;
    }
  }
  const int h = t >> 5, c = t & 31;
  #pragma unroll
  for (int rr = 0; rr < 4; ++rr) {
    const int row = r0 + rr, b = row / 96, j = row - b * 96;
    const int oi = ((b * 8 + h) * 96 + j) * 32 + c;
    nQ[oi] = a0[rr]; nK[oi] = a1[rr]; nV[oi] = a2[rr];
  }
}

// ---------------------------------------------------------------------------
// K2: fused node attention for one (b,i). 512 threads (8 waves). LDS 57856 B.
// b->XCD swizzle: b = blockIdx&7.
// ---------------------------------------------------------------------------
__global__ __launch_bounds__(512, 4)
void node_attn(const float* __restrict__ edge, const float* __restrict__ We_b,
               const unsigned short* __restrict__ WeF,
               const float* __restrict__ nQ, const float* __restrict__ nK,
               const float* __restrict__ nV, float* __restrict__ attw)
{
  __shared__ unsigned short Elds[96 * LDE];   // 50688 B
  __shared__ float sc[768];                   // 3072 B
  __shared__ float nQp[256];                  // 1024 B
  __shared__ float bias[768];                 // 3072 B

  const int tid = threadIdx.x, lane = tid & 63, wid = tid >> 6;
  const int b = blockIdx.x & 7, i = blockIdx.x >> 3;
  const size_t bi = (size_t)(b * 96 + i);

  if (tid < 256) nQp[tid] = nQ[((b * 8 + (tid >> 5)) * 96 + i) * 32 + (tid & 31)];
  for (int u = tid; u < 768; u += 512) bias[u] = We_b[u];

  const float* Erow = edge + bi * 24576;
  for (int u = tid; u < 96 * 64; u += 512) {
    const int j = u >> 6, g = u & 63;
    const float4 v = *(const float4*)(Erow + j * 256 + g * 4);
    const unsigned lo = (unsigned)f2bf(v.x) | ((unsigned)f2bf(v.y) << 16);
    const unsigned hi = (unsigned)f2bf(v.z) | ((unsigned)f2bf(v.w) << 16);
    *(uint2*)(Elds + j * LDE + g * 4) = make_uint2(lo, hi);
  }
  __syncthreads();

  // ---- Phase A: head h = wid; Q,K projections folded into score dot ----
  for (int mt = 0; mt < 6; ++mt) {
    bf16x8 afr[8];
    const unsigned short* ab = Elds + (mt * 16 + (lane & 15)) * LDE + ((lane >> 4) << 3);
    #pragma unroll
    for (int kt = 0; kt < 8; ++kt) afr[kt] = *(const bf16x8*)(ab + kt * 32);
    const int h = wid;
    f32x4 q0 = {0.f, 0.f, 0.f, 0.f}, q1 = q0, k0 = q0, k1 = q0;
    const unsigned short* wq0 = WeF + ((2 * h) * 64 + lane) * 8;
    const unsigned short* wq1 = WeF + ((2 * h + 1) * 64 + lane) * 8;
    const unsigned short* wk0 = WeF + ((16 + 2 * h) * 64 + lane) * 8;
    const unsigned short* wk1 = WeF + ((17 + 2 * h) * 64 + lane) * 8;
    #pragma unroll
    for (int kt = 0; kt < 8; ++kt) {
      q0 = MFMA(afr[kt], *(const bf16x8*)(wq0 + kt * 24576), q0);
      q1 = MFMA(afr[kt], *(const bf16x8*)(wq1 + kt * 24576), q1);
      k0 = MFMA(afr[kt], *(const bf16x8*)(wk0 + kt * 24576), k0);
      k1 = MFMA(afr[kt], *(const bf16x8*)(wk1 + kt * 24576), k1);
    }
    const int c0 = h * 32 + (lane & 15), c1 = c0 + 16;
    const float qb0 = bias[c0] + nQp[c0], qb1 = bias[c1] + nQp[c1];
    const float kb0 = bias[256 + c0], kb1 = bias[256 + c1];
    float prod[4];
    #pragma unroll
    for (int r = 0; r < 4; ++r) {
      const int j = mt * 16 + ((lane >> 4) << 2) + r;
      const int g = ((b * 8 + h) * 96 + j) * 32;
      const float k0v = k0[r] + kb0 + nK[g + (lane & 15)];
      const float k1v = k1[r] + kb1 + nK[g + 16 + (lane & 15)];
      prod[r] = (q0[r] + qb0) * k0v + (q1[r] + qb1) * k1v;
    }
    #pragma unroll
    for (int m = 1; m < 16; m <<= 1) {
      #pragma unroll
      for (int r = 0; r < 4; ++r) prod[r] += __shfl_xor(prod[r], m, 64);
    }
    if ((lane & 15) == 0) {
      #pragma unroll
      for (int r = 0; r < 4; ++r)
        sc[h * 96 + mt * 16 + ((lane >> 4) << 2) + r] = prod[r];
    }
  }
  __syncthreads();

  // ---- softmax: wave wid = head; 96 j over 64 lanes ----
  {
    const int h = wid;
    const float s0 = sc[h * 96 + lane] * SCALE;
    const float s1 = (lane < 32) ? sc[h * 96 + 64 + lane] * SCALE : -1e30f;
    float mx = fmaxf(s0, s1);
    #pragma unroll
    for (int m = 1; m < 64; m <<= 1) mx = fmaxf(mx, __shfl_xor(mx, m, 64));
    const float e0 = __expf(s0 - mx);
    const float e1 = (lane < 32) ? __expf(s1 - mx) : 0.f;
    float sm = e0 + e1;
    #pragma unroll
    for (int m = 1; m < 64; m <<= 1) sm += __shfl_xor(sm, m, 64);
    const float inv = 1.f / sm;
    sc[h * 96 + lane] = e0 * inv;
    if (lane < 32) sc[h * 96 + 64 + lane] = e1 * inv;
  }
  __syncthreads();

  // ---- Phase B: wave wid owns col tiles {wid, wid+8}; attn@V in regs ----
  {
    float nn[2] = {0.f, 0.f};
    for (int mt = 0; mt < 6; ++mt) {
      bf16x8 afr[8];
      const unsigned short* ab = Elds + (mt * 16 + (lane & 15)) * LDE + ((lane >> 4) << 3);
      #pragma unroll
      for (int kt = 0; kt < 8; ++kt) afr[kt] = *(const bf16x8*)(ab + kt * 32);
      const int nt0 = 32 + wid, nt1 = 40 + wid;
      f32x4 a0 = {0.f, 0.f, 0.f, 0.f}, a1 = a0;
      const unsigned short* wb0 = WeF + (nt0 * 64 + lane) * 8;
      const unsigned short* wb1 = WeF + (nt1 * 64 + lane) * 8;
      #pragma unroll
      for (int kt = 0; kt < 8; ++kt) {
        a0 = MFMA(afr[kt], *(const bf16x8*)(wb0 + kt * 24576), a0);
        a1 = MFMA(afr[kt], *(const bf16x8*)(wb1 + kt * 24576), a1);
      }
      #pragma unroll
      for (int s = 0; s < 2; ++s) {
        const f32x4 aa = s ? a1 : a0;
        const int col = (wid + (s << 3)) * 16 + (lane & 15);
        const int h = col >> 5, cc = col & 31;
        const float base = bias[512 + col];
        #pragma unroll
        for (int r = 0; r < 4; ++r) {
          const int j = mt * 16 + ((lane >> 4) << 2) + r;
          const float v = aa[r] + base + nV[((b * 8 + h) * 96 + j) * 32 + cc];
          nn[s] += sc[h * 96 + j] * v;
        }
      }
    }
    #pragma unroll
    for (int s = 0; s < 2; ++s) {
      nn[s] += __shfl_xor(nn[s], 16, 64);
      nn[s] += __shfl_xor(nn[s], 32, 64);
    }
    if (lane < 16) {
      attw[bi * 256 + wid * 16 + lane] = nn[0];
      attw[bi * 256 + (wid + 8) * 16 + lane] = nn[1];
    }
  }
}

// ---------------------------------------------------------------------------
// K3: node FFN + residual + LayerNorm. 96 blocks x 256 threads, 8 rows each.
// ---------------------------------------------------------------------------
__global__ __launch_bounds__(256)
void node_ffn_ln(const float* __restrict__ attw, const float* __restrict__ node,
                 const float* __restrict__ W1, const float* __restrict__ B1,
                 const float* __restrict__ W2, const float* __restrict__ B2,
                 const float* __restrict__ g, const float* __restrict__ be,
                 float* __restrict__ node_out)
{
  __shared__ float xa[8][256];
  __shared__ float h1[8][256];
  __shared__ float xr[8][256];
  const int t = threadIdx.x, r0 = blockIdx.x * 8;
  #pragma unroll
  for (int rr = 0; rr < 8; ++rr) xa[rr][t] = attw[(r0 + rr) * 256 + t];
  __syncthreads();
  float acc[8];
  #pragma unroll
  for (int rr = 0; rr < 8; ++rr) acc[rr] = B1[t];
  for (int k = 0; k < 256; ++k) {
    const float w = W1[k * 256 + t];
    #pragma unroll
    for (int rr = 0; rr < 8; ++rr) acc[rr] += xa[rr][k] * w;
  }
  #pragma unroll
  for (int rr = 0; rr < 8; ++rr) h1[rr][t] = fmaxf(acc[rr], 0.f);
  __syncthreads();
  #pragma unroll
  for (int rr = 0; rr < 8; ++rr) acc[rr] = B2[t];
  for (int k = 0; k < 256; ++k) {
    const float w = W2[k * 256 + t];
    #pragma unroll
    for (int rr = 0; rr < 8; ++rr) acc[rr] += h1[rr][k] * w;
  }
  #pragma unroll
  for (int rr = 0; rr < 8; ++rr) xr[rr][t] = node[(r0 + rr) * 256 + t] + acc[rr];
  __syncthreads();
  const int wid = t >> 6, lane = t & 63;
  const float4 gv = *(const float4*)(g + (lane << 2));
  const float4 bv = *(const float4*)(be + (lane << 2));
  for (int rr = wid * 2; rr < wid * 2 + 2; ++rr) {
    const float4 xv = *(const float4*)(&xr[rr][lane << 2]);
    float s = xv.x + xv.y + xv.z + xv.w;
    float sq = xv.x * xv.x + xv.y * xv.y + xv.z * xv.z + xv.w * xv.w;
    #pragma unroll
    for (int m = 1; m < 64; m <<= 1) { s += __shfl_xor(s, m, 64); sq += __shfl_xor(sq, m, 64); }
    const float mean = s * (1.f / 256.f);
    const float rs = rsqrtf(sq * (1.f / 256.f) - mean * mean + 1e-5f);
    float4 o;
    o.x = (xv.x - mean) * rs * gv.x + bv.x;
    o.y = (xv.y - mean) * rs * gv.y + bv.y;
    o.z = (xv.z - mean) * rs * gv.z + bv.z;
    o.w = (xv.w - mean) * rs * gv.w + bv.w;
    *(float4*)(node_out + (r0 + rr) * 256 + (lane << 2)) = o;
  }
}

// ---------------------------------------------------------------------------
// K4: n1Q..n2V = node_out @ {Wn1,Wn2} (+bias), stored [B,H,N,HS].
// ---------------------------------------------------------------------------
__global__ __launch_bounds__(256)
void node_proj6(const float* __restrict__ nodeo,
                const float* __restrict__ W1, const float* __restrict__ B1,
                const float* __restrict__ W2, const float* __restrict__ B2,
                float* __restrict__ n1Q, float* __restrict__ n1K, float* __restrict__ n1V,
                float* __restrict__ n2Q, float* __restrict__ n2K, float* __restrict__ n2V)
{
  __shared__ float x[4][256];
  const int t = threadIdx.x, r0 = blockIdx.x * 4;
  #pragma unroll
  for (int rr = 0; rr < 4; ++rr) x[rr][t] = nodeo[(r0 + rr) * 256 + t];
  __syncthreads();
  float a[6][4];
  #pragma unroll
  for (int rr = 0; rr < 4; ++rr) {
    a[0][rr] = B1[t]; a[1][rr] = B1[256 + t]; a[2][rr] = B1[512 + t];
    a[3][rr] = B2[t]; a[4][rr] = B2[256 + t]; a[5][rr] = B2[512 + t];
  }
  for (int k = 0; k < 256; ++k) {
    const float w0 = W1[k * 256 + t], w1 = W1[65536 + k * 256 + t], w2 = W1[131072 + k * 256 + t];
    const float w3 = W2[k * 256 + t], w4 = W2[65536 + k * 256 + t], w5 = W2[131072 + k * 256 + t];
    #pragma unroll
    for (int rr = 0; rr < 4; ++rr) {
      const float xv = x[rr][k];
      a[0][rr] += xv * w0; a[1][rr] += xv * w1; a[2][rr] += xv * w2;
      a[3][rr] += xv * w3; a[4][rr] += xv * w4; a[5][rr] += xv * w5;
    }
  }
  const int h = t >> 5, c = t & 31;
  #pragma unroll
  for (int rr = 0; rr < 4; ++rr) {
    const int row = r0 + rr, b = row / 96, j = row - b * 96;
    const int oi = ((b * 8 + h) * 96 + j) * 32 + c;
    n1Q[oi] = a[0][rr]; n1K[oi] = a[1][rr]; n1V[oi] = a[2][rr];
    n2Q[oi] = a[3][rr]; n2K[oi] = a[4][rr]; n2V[oi] = a[5][rr];
  }
}

// ---------------------------------------------------------------------------
// K5: fused edge update for one (b,i). 512 threads (8 waves). LDS 65152 B.
// b->XCD swizzle. LN output staged bf16 in Elds; final coalesced fp32 rows.
// ---------------------------------------------------------------------------
__global__ __launch_bounds__(512, 4)
void edge_update(const float* __restrict__ edge, const float* __restrict__ Wee_b,
                 const unsigned short* __restrict__ WeeF,
                 const unsigned short* __restrict__ EL1F,
                 const unsigned short* __restrict__ EL2F,
                 const float* __restrict__ EL1_b, const float* __restrict__ EL2_b,
                 const float* __restrict__ n1Q, const float* __restrict__ n1K, const float* __restrict__ n1V,
                 const float* __restrict__ n2Q, const float* __restrict__ n2K, const float* __restrict__ n2V,
                 const float* __restrict__ lng, const float* __restrict__ lnb,
                 float* __restrict__ edge_out)
{
  __shared__ unsigned short Elds[96 * LDE];   // 50688 B (E -> attw_e -> hidden -> LN out)
  __shared__ float se[768];                   // 3072 B
  __shared__ float n1p[768];                  // 3072 B
  __shared__ float bias[768];                 // 3072 B
  __shared__ float b12[512];                  // 2048 B
  __shared__ float lg[256], lb[256];          // 2048 B
  __shared__ float psum[8][16], psq[8][16];   // 1024 B
  __shared__ float statm[16], statr[16];      // 128 B

  const int tid = threadIdx.x, lane = tid & 63, wid = tid >> 6;
  const int b = blockIdx.x & 7, i = blockIdx.x >> 3;
  const size_t bi = (size_t)(b * 96 + i);

  for (int u = tid; u < 768; u += 512) {
    bias[u] = Wee_b[u];
    const int q = u >> 8, cn = u & 255, h = cn >> 5, c = cn & 31;
    const float* s = (q == 0) ? n1Q : (q == 1) ? n1K : n1V;
    n1p[u] = s[((b * 8 + h) * 96 + i) * 32 + c];
  }
  b12[tid] = (tid < 256) ? EL1_b[tid] : EL2_b[tid - 256];
  if (tid < 256) { lg[tid] = lng[tid]; lb[tid] = lnb[tid]; }

  const float* Erow = edge + bi * 24576;
  for (int u = tid; u < 96 * 64; u += 512) {
    const int j = u >> 6, g = u & 63;
    const float4 v = *(const float4*)(Erow + j * 256 + g * 4);
    const unsigned lo = (unsigned)f2bf(v.x) | ((unsigned)f2bf(v.y) << 16);
    const unsigned hi = (unsigned)f2bf(v.z) | ((unsigned)f2bf(v.w) << 16);
    *(uint2*)(Elds + j * LDE + g * 4) = make_uint2(lo, hi);
  }
  __syncthreads();

  // ---- Phase A: head h = wid; Qe,Ke projections folded into se dot ----
  for (int mt = 0; mt < 6; ++mt) {
    bf16x8 afr[8];
    const unsigned short* ab = Elds + (mt * 16 + (lane & 15)) * LDE + ((lane >> 4) << 3);
    #pragma unroll
    for (int kt = 0; kt < 8; ++kt) afr[kt] = *(const bf16x8*)(ab + kt * 32);
    const int h = wid;
    f32x4 q0 = {0.f, 0.f, 0.f, 0.f}, q1 = q0, k0 = q0, k1 = q0;
    const unsigned short* wq0 = WeeF + ((2 * h) * 64 + lane) * 8;
    const unsigned short* wq1 = WeeF + ((2 * h + 1) * 64 + lane) * 8;
    const unsigned short* wk0 = WeeF + ((16 + 2 * h) * 64 + lane) * 8;
    const unsigned short* wk1 = WeeF + ((17 + 2 * h) * 64 + lane) * 8;
    #pragma unroll
    for (int kt = 0; kt < 8; ++kt) {
      q0 = MFMA(afr[kt], *(const bf16x8*)(wq0 + kt * 24576), q0);
      q1 = MFMA(afr[kt], *(const bf16x8*)(wq1 + kt * 24576), q1);
      k0 = MFMA(afr[kt], *(const bf16x8*)(wk0 + kt * 24576), k0);
      k1 = MFMA(afr[kt], *(const bf16x8*)(wk1 + kt * 24576), k1);
    }
    const int c0 = h * 32 + (lane & 15), c1 = c0 + 16;
    const float qb0 = bias[c0] + n1p[c0], qb1 = bias[c1] + n1p[c1];
    const float kb0 = bias[256 + c0] + n1p[256 + c0];
    const float kb1 = bias[256 + c1] + n1p[256 + c1];
    float prod[4];
    #pragma unroll
    for (int r = 0; r < 4; ++r) {
      const int j = mt * 16 + ((lane >> 4) << 2) + r;
      const int g = ((b * 8 + h) * 96 + j) * 32;
      const float q0v = q0[r] + qb0 + n2Q[g + (lane & 15)];
      const float q1v = q1[r] + qb1 + n2Q[g + 16 + (lane & 15)];
      const float k0v = k0[r] + kb0 + n2K[g + (lane & 15)];
      const float k1v = k1[r] + kb1 + n2K[g + 16 + (lane & 15)];
      prod[r] = q0v * k0v + q1v * k1v;
    }
    #pragma unroll
    for (int m = 1; m < 16; m <<= 1) {
      #pragma unroll
      for (int r = 0; r < 4; ++r) prod[r] += __shfl_xor(prod[r], m, 64);
    }
    if ((lane & 15) == 0) {
      #pragma unroll
      for (int r = 0; r < 4; ++r)
        se[h * 96 + mt * 16 + ((lane >> 4) << 2) + r] = prod[r];
    }
  }
  __syncthreads();

  // ---- silu ----
  for (int u = tid; u < 768; u += 512) {
    const float s = se[u] * SCALE;
    se[u] = s / (1.f + __expf(-s));
  }
  __syncthreads();

  // ---- Phase B: Ve projection, scale by silu, in-place over E tile ----
  for (int mt = 0; mt < 6; ++mt) {
    bf16x8 afr[8];
    const unsigned short* ab = Elds + (mt * 16 + (lane & 15)) * LDE + ((lane >> 4) << 3);
    #pragma unroll
    for (int kt = 0; kt < 8; ++kt) afr[kt] = *(const bf16x8*)(ab + kt * 32);
    const int nt0 = 32 + wid, nt1 = 40 + wid;
    f32x4 a0 = {0.f, 0.f, 0.f, 0.f}, a1 = a0;
    const unsigned short* wb0 = WeeF + (nt0 * 64 + lane) * 8;
    const unsigned short* wb1 = WeeF + (nt1 * 64 + lane) * 8;
    #pragma unroll
    for (int kt = 0; kt < 8; ++kt) {
      a0 = MFMA(afr[kt], *(const bf16x8*)(wb0 + kt * 24576), a0);
      a1 = MFMA(afr[kt], *(const bf16x8*)(wb1 + kt * 24576), a1);
    }
    float vals[2][4];
    int colb[2];
    #pragma unroll
    for (int s = 0; s < 2; ++s) {
      const f32x4 aa = s ? a1 : a0;
      const int col = (wid + (s << 3)) * 16 + (lane & 15);
      const int h = col >> 5, cc = col & 31;
      const float base = bias[512 + col] + n1p[512 + col];
      colb[s] = col;
      #pragma unroll
      for (int r = 0; r < 4; ++r) {
        const int j = mt * 16 + ((lane >> 4) << 2) + r;
        const float v = aa[r] + base + n2V[((b * 8 + h) * 96 + j) * 32 + cc];
        vals[s][r] = se[h * 96 + j] * v;
      }
    }
    __syncthreads();   // all waves done reading E rows of this tile
    #pragma unroll
    for (int s = 0; s < 2; ++s)
      #pragma unroll
      for (int r = 0; r < 4; ++r) {
        const int j = mt * 16 + ((lane >> 4) << 2) + r;
        Elds[j * LDE + colb[s]] = f2bf(vals[s][r]);
      }
  }
  __syncthreads();

  // ---- EL1 + relu, in place (attw_e -> hidden) ----
  for (int mt = 0; mt < 6; ++mt) {
    bf16x8 afr[8];
    const unsigned short* ab = Elds + (mt * 16 + (lane & 15)) * LDE + ((lane >> 4) << 3);
    #pragma unroll
    for (int kt = 0; kt < 8; ++kt) afr[kt] = *(const bf16x8*)(ab + kt * 32);
    const int nt0 = wid, nt1 = wid + 8;
    f32x4 a0 = {0.f, 0.f, 0.f, 0.f}, a1 = a0;
    const unsigned short* wb0 = EL1F + (nt0 * 64 + lane) * 8;
    const unsigned short* wb1 = EL1F + (nt1 * 64 + lane) * 8;
    #pragma unroll
    for (int kt = 0; kt < 8; ++kt) {
      a0 = MFMA(afr[kt], *(const bf16x8*)(wb0 + kt * 8192), a0);
      a1 = MFMA(afr[kt], *(const bf16x8*)(wb1 + kt * 8192), a1);
    }
    float vals[2][4];
    int colb[2];
    #pragma unroll
    for (int s = 0; s < 2; ++s) {
      const f32x4 aa = s ? a1 : a0;
      const int col = (wid + (s << 3)) * 16 + (lane & 15);
      const float bv = b12[col];
      colb[s] = col;
      #pragma unroll
      for (int r = 0; r < 4; ++r) vals[s][r] = fmaxf(aa[r] + bv, 0.f);
    }
    __syncthreads();
    #pragma unroll
    for (int s = 0; s < 2; ++s)
      #pragma unroll
      for (int r = 0; r < 4; ++r) {
        const int j = mt * 16 + ((lane >> 4) << 2) + r;
        Elds[j * LDE + colb[s]] = f2bf(vals[s][r]);
      }
  }
  __syncthreads();

  // ---- EL2 + residual + LayerNorm fused; bf16 LN out staged in place ----
  for (int mt = 0; mt < 6; ++mt) {
    bf16x8 afr[8];
    const unsigned short* ab = Elds + (mt * 16 + (lane & 15)) * LDE + ((lane >> 4) << 3);
    #pragma unroll
    for (int kt = 0; kt < 8; ++kt) afr[kt] = *(const bf16x8*)(ab + kt * 32);
    const int nt0 = wid, nt1 = wid + 8;
    f32x4 a0 = {0.f, 0.f, 0.f, 0.f}, a1 = a0;
    const unsigned short* wb0 = EL2F + (nt0 * 64 + lane) * 8;
    const unsigned short* wb1 = EL2F + (nt1 * 64 + lane) * 8;
    #pragma unroll
    for (int kt = 0; kt < 8; ++kt) {
      a0 = MFMA(afr[kt], *(const bf16x8*)(wb0 + kt * 8192), a0);
      a1 = MFMA(afr[kt], *(const bf16x8*)(wb1 + kt * 8192), a1);
    }
    float vals[2][4];
    int colb[2];
    #pragma unroll
    for (int s = 0; s < 2; ++s) {
      const f32x4 aa = s ? a1 : a0;
      const int col = (wid + (s << 3)) * 16 + (lane & 15);
      const float bv = b12[256 + col];
      colb[s] = col;
      #pragma unroll
      for (int r = 0; r < 4; ++r) {
        const int j = mt * 16 + ((lane >> 4) << 2) + r;
        vals[s][r] = aa[r] + bv + Erow[j * 256 + col];
      }
    }
    // per-row partials: this lane covers 2 cols per row
    #pragma unroll
    for (int r = 0; r < 4; ++r) {
      float s = vals[0][r] + vals[1][r];
      float q = vals[0][r] * vals[0][r] + vals[1][r] * vals[1][r];
      #pragma unroll
      for (int m = 1; m < 16; m <<= 1) { s += __shfl_xor(s, m, 64); q += __shfl_xor(q, m, 64); }
      if ((lane & 15) == 0) {
        const int rloc = ((lane >> 4) << 2) + r;
        psum[wid][rloc] = s; psq[wid][rloc] = q;
      }
    }
    __syncthreads();
    if (tid < 16) {
      float s = 0.f, q = 0.f;
      #pragma unroll
      for (int w = 0; w < 8; ++w) { s += psum[w][tid]; q += psq[w][tid]; }
      const float mean = s * (1.f / 256.f);
      statm[tid] = mean;
      statr[tid] = rsqrtf(q * (1.f / 256.f) - mean * mean + 1e-5f);
    }
    __syncthreads();
    #pragma unroll
    for (int s = 0; s < 2; ++s) {
      const int col = colb[s];
      const float gv = lg[col], bvv = lb[col];
      #pragma unroll
      for (int r = 0; r < 4; ++r) {
        const int rloc = ((lane >> 4) << 2) + r;
        const int j = mt * 16 + rloc;
        Elds[j * LDE + col] = f2bf((vals[s][r] - statm[rloc]) * statr[rloc] * gv + bvv);
      }
    }
  }
  __syncthreads();

  // ---- coalesced fp32 writeback: full 1KB rows ----
  float* orow = edge_out + bi * 24576;
  for (int j = wid; j < 96; j += 8) {
    const uint2 pk = *(const uint2*)(Elds + j * LDE + (lane << 2));
    float4 o;
    o.x = bf2f((unsigned short)(pk.x & 0xffff));
    o.y = bf2f((unsigned short)(pk.x >> 16));
    o.z = bf2f((unsigned short)(pk.y & 0xffff));
    o.w = bf2f((unsigned short)(pk.y >> 16));
    *(float4*)(orow + j * 256 + (lane << 2)) = o;
  }
}

// ---------------------------------------------------------------------------
extern "C" void kernel_launch(void* const* d_in, const int* in_sizes, int n_in,
                              void* d_out, int out_size, void* d_ws, size_t ws_size,
                              hipStream_t stream)
{
  (void)in_sizes; (void)n_in; (void)out_size; (void)ws_size;

  const float* node   = (const float*)d_in[0];
  const float* edge   = (const float*)d_in[1];
  const float* Wn_w   = (const float*)d_in[2];
  const float* Wn_b   = (const float*)d_in[3];
  const float* We_w   = (const float*)d_in[4];
  const float* We_b   = (const float*)d_in[5];
  const float* Wn1_w  = (const float*)d_in[6];
  const float* Wn1_b  = (const float*)d_in[7];
  const float* Wn2_w  = (const float*)d_in[8];
  const float* Wn2_b  = (const float*)d_in[9];
  const float* Wee_w  = (const float*)d_in[10];
  const float* Wee_b  = (const float*)d_in[11];
  const float* NL1_w  = (const float*)d_in[12];
  const float* NL1_b  = (const float*)d_in[13];
  const float* NL2_w  = (const float*)d_in[14];
  const float* NL2_b  = (const float*)d_in[15];
  const float* EL1_w  = (const float*)d_in[16];
  const float* EL1_b  = (const float*)d_in[17];
  const float* EL2_w  = (const float*)d_in[18];
  const float* EL2_b  = (const float*)d_in[19];
  const float* NLN1_g = (const float*)d_in[20];
  const float* NLN1_b = (const float*)d_in[21];
  const float* ELN1_g = (const float*)d_in[22];
  const float* ELN1_b = (const float*)d_in[23];

  float* out = (float*)d_out;
  float* node_out = out;               // [8,96,256]
  float* edge_out = out + 196608;      // [8,96,96,256]

  float* wsf = (float*)d_ws;
  float* nQ  = wsf;                float* nK  = wsf + 196608;   float* nV  = wsf + 393216;
  float* n1Q = wsf + 589824;       float* n1K = wsf + 786432;   float* n1V = wsf + 983040;
  float* n2Q = wsf + 1179648;      float* n2K = wsf + 1376256;  float* n2V = wsf + 1572864;
  float* attw = wsf + 1769472;
  unsigned short* fb   = (unsigned short*)(wsf + 1966080);
  unsigned short* WeF  = fb;                 // 196608
  unsigned short* WeeF = fb + 196608;        // 196608
  unsigned short* EL1F = fb + 393216;        // 65536
  unsigned short* EL2F = fb + 458752;        // 65536

  prep_frags<<<64, 256, 0, stream>>>(We_w, Wee_w, EL1_w, EL2_w, fb);
  node_qkv<<<192, 256, 0, stream>>>(node, Wn_w, Wn_b, nQ, nK, nV);
  node_attn<<<768, 512, 0, stream>>>(edge, We_b, WeF, nQ, nK, nV, attw);
  node_ffn_ln<<<96, 256, 0, stream>>>(attw, node, NL1_w, NL1_b, NL2_w, NL2_b,
                                      NLN1_g, NLN1_b, node_out);
  node_proj6<<<192, 256, 0, stream>>>(node_out, Wn1_w, Wn1_b, Wn2_w, Wn2_b,
                                      n1Q, n1K, n1V, n2Q, n2K, n2V);
  edge_update<<<768, 512, 0, stream>>>(edge, Wee_b, WeeF, EL1F, EL2F,
                                       EL1_b, EL2_b, n1Q, n1K, n1V,
                                       n2Q, n2K, n2V, ELN1_g, ELN1_b, edge_out);
}

// Round 6
// 293.553 us; speedup vs baseline: 2.3709x; 1.4538x over previous
//
#include <hip/hip_runtime.h>

// B=8 N=96 H=8 HS=32 NS=256.  bf16 MFMA 16x16x32 for all edge-side matmuls.
// v6: kt-outer / mt-inner loop order so each B-fragment (L2) is loaded once
// and reused across row tiles in registers (3.3x cut in L2 B-traffic, the
// round-5 limiter). VGPR cap raised to 128 via __launch_bounds__(512,2).

#define DI __device__ __forceinline__

typedef float f32x4 __attribute__((ext_vector_type(4)));
typedef short bf16x8 __attribute__((ext_vector_type(8)));

DI unsigned short f2bf(float f) {
  union { float f; unsigned u; } v; v.f = f;
  return (unsigned short)((v.u + 0x7FFFu + ((v.u >> 16) & 1u)) >> 16);
}
DI float bf2f(unsigned short h) {
  union { unsigned u; float f; } v; v.u = ((unsigned)h) << 16;
  return v.f;
}

#define LDE 264            // padded bf16 row stride
#define SCALE 0.17677669529663687f   // 1/sqrt(32)

#define MFMA(A, B, C) __builtin_amdgcn_mfma_f32_16x16x32_bf16((A), (B), (C), 0, 0, 0)

// ---------------------------------------------------------------------------
// K0: pack weights into bf16 MFMA B-fragment layout (LDS-staged, coalesced).
// frag[( (kt*NT + nt)*64 + l )*8 + i] = W[kt*32 + (l>>4)*8 + i][nt*16 + (l&15)]
// ---------------------------------------------------------------------------
__global__ __launch_bounds__(256)
void prep_frags(const float* __restrict__ We_w, const float* __restrict__ Wee_w,
                const float* __restrict__ EL1_w, const float* __restrict__ EL2_w,
                unsigned short* __restrict__ fb)
{
  __shared__ float Wl[32 * 256];
  const int blk = blockIdx.x, kt = blk & 7, ms = blk >> 3;
  const float* src; unsigned short* dst; int NT, ntbase;
  if (ms < 3)       { src = We_w  + ms * 65536;       dst = fb;          NT = 48; ntbase = ms * 16; }
  else if (ms < 6)  { src = Wee_w + (ms - 3) * 65536; dst = fb + 196608; NT = 48; ntbase = (ms - 3) * 16; }
  else if (ms == 6) { src = EL1_w;                    dst = fb + 393216; NT = 16; ntbase = 0; }
  else              { src = EL2_w;                    dst = fb + 458752; NT = 16; ntbase = 0; }
  const int t = threadIdx.x;
  for (int u = t; u < 32 * 64; u += 256) {
    const int r = u >> 6, c4 = (u & 63) << 2;
    *(float4*)(Wl + r * 256 + c4) = *(const float4*)(src + (kt * 32 + r) * 256 + c4);
  }
  __syncthreads();
  for (int u = t; u < 16 * 64; u += 256) {
    const int ntl = u >> 6, l = u & 63;
    const int kb = (l >> 4) << 3, c = ntl * 16 + (l & 15);
    unsigned short tmp[8];
    #pragma unroll
    for (int i = 0; i < 8; ++i) tmp[i] = f2bf(Wl[(kb + i) * 256 + c]);
    const int nt = ntbase + ntl;
    *(uint4*)(dst + ((size_t)(kt * NT + nt) * 64 + l) * 8) = *(const uint4*)tmp;
  }
}

// ---------------------------------------------------------------------------
// K1: nQ/nK/nV = node @ Wn_w[q] + Wn_b[q], stored as [B,H,N,HS].
// ---------------------------------------------------------------------------
__global__ __launch_bounds__(256)
void node_qkv(const float* __restrict__ node, const float* __restrict__ Ww,
              const float* __restrict__ Wb, float* __restrict__ nQ,
              float* __restrict__ nK, float* __restrict__ nV)
{
  __shared__ float x[4][256];
  const int t = threadIdx.x, r0 = blockIdx.x * 4;
  #pragma unroll
  for (int rr = 0; rr < 4; ++rr) x[rr][t] = node[(r0 + rr) * 256 + t];
  __syncthreads();
  float a0[4], a1[4], a2[4];
  #pragma unroll
  for (int rr = 0; rr < 4; ++rr) { a0[rr] = Wb[t]; a1[rr] = Wb[256 + t]; a2[rr] = Wb[512 + t]; }
  for (int k = 0; k < 256; ++k) {
    const float w0 = Ww[k * 256 + t], w1 = Ww[65536 + k * 256 + t], w2 = Ww[131072 + k * 256 + t];
    #pragma unroll
    for (int rr = 0; rr < 4; ++rr) {
      const float xv = x[rr][k];
      a0[rr] += xv * w0; a1[rr] += xv * w1; a2[rr] += xv * w2;
    }
  }
  const int h = t >> 5, c = t & 31;
  #pragma unroll
  for (int rr = 0; rr < 4; ++rr) {
    const int row = r0 + rr, b = row / 96, j = row - b * 96;
    const int oi = ((b * 8 + h) * 96 + j) * 32 + c;
    nQ[oi] = a0[rr]; nK[oi] = a1[rr]; nV[oi] = a2[rr];
  }
}

// ---------------------------------------------------------------------------
// K2: fused node attention for one (b,i). 512 threads (8 waves). LDS 57856 B.
// b->XCD swizzle. kt-outer MFMA loops (B-fragments loaded once).
// ---------------------------------------------------------------------------
__global__ __launch_bounds__(512, 2)
void node_attn(const float* __restrict__ edge, const float* __restrict__ We_b,
               const unsigned short* __restrict__ WeF,
               const float* __restrict__ nQ, const float* __restrict__ nK,
               const float* __restrict__ nV, float* __restrict__ attw)
{
  __shared__ unsigned short Elds[96 * LDE];   // 50688 B
  __shared__ float sc[768];                   // 3072 B
  __shared__ float nQp[256];                  // 1024 B
  __shared__ float bias[768];                 // 3072 B

  const int tid = threadIdx.x, lane = tid & 63, wid = tid >> 6;
  const int b = blockIdx.x & 7, i = blockIdx.x >> 3;
  const size_t bi = (size_t)(b * 96 + i);

  if (tid < 256) nQp[tid] = nQ[((b * 8 + (tid >> 5)) * 96 + i) * 32 + (tid & 31)];
  for (int u = tid; u < 768; u += 512) bias[u] = We_b[u];

  const float* Erow = edge + bi * 24576;
  for (int u = tid; u < 96 * 64; u += 512) {
    const int j = u >> 6, g = u & 63;
    const float4 v = *(const float4*)(Erow + j * 256 + g * 4);
    const unsigned lo = (unsigned)f2bf(v.x) | ((unsigned)f2bf(v.y) << 16);
    const unsigned hi = (unsigned)f2bf(v.z) | ((unsigned)f2bf(v.w) << 16);
    *(uint2*)(Elds + j * LDE + g * 4) = make_uint2(lo, hi);
  }
  __syncthreads();

  // ---- Phase A: head h = wid; Q,K projections folded into score dot ----
  {
    const int h = wid;
    const unsigned short* wq0 = WeF + ((2 * h) * 64 + lane) * 8;
    const unsigned short* wq1 = WeF + ((2 * h + 1) * 64 + lane) * 8;
    const unsigned short* wk0 = WeF + ((16 + 2 * h) * 64 + lane) * 8;
    const unsigned short* wk1 = WeF + ((17 + 2 * h) * 64 + lane) * 8;
    const int c0 = h * 32 + (lane & 15), c1 = c0 + 16;
    const float qb0 = bias[c0] + nQp[c0], qb1 = bias[c1] + nQp[c1];
    const float kb0 = bias[256 + c0], kb1 = bias[256 + c1];
    for (int half = 0; half < 3; ++half) {
      const f32x4 z = {0.f, 0.f, 0.f, 0.f};
      f32x4 aq0[2] = {z, z}, aq1[2] = {z, z}, ak0[2] = {z, z}, ak1[2] = {z, z};
      for (int kt = 0; kt < 8; ++kt) {
        const bf16x8 b0 = *(const bf16x8*)(wq0 + kt * 24576);
        const bf16x8 b1 = *(const bf16x8*)(wq1 + kt * 24576);
        const bf16x8 b2 = *(const bf16x8*)(wk0 + kt * 24576);
        const bf16x8 b3 = *(const bf16x8*)(wk1 + kt * 24576);
        #pragma unroll
        for (int m = 0; m < 2; ++m) {
          const int mt = half * 2 + m;
          const bf16x8 afr = *(const bf16x8*)(Elds + (mt * 16 + (lane & 15)) * LDE
                                              + ((lane >> 4) << 3) + kt * 32);
          aq0[m] = MFMA(afr, b0, aq0[m]);
          aq1[m] = MFMA(afr, b1, aq1[m]);
          ak0[m] = MFMA(afr, b2, ak0[m]);
          ak1[m] = MFMA(afr, b3, ak1[m]);
        }
      }
      #pragma unroll
      for (int m = 0; m < 2; ++m) {
        const int mt = half * 2 + m;
        float prod[4];
        #pragma unroll
        for (int r = 0; r < 4; ++r) {
          const int j = mt * 16 + ((lane >> 4) << 2) + r;
          const int g = ((b * 8 + h) * 96 + j) * 32;
          const float k0v = ak0[m][r] + kb0 + nK[g + (lane & 15)];
          const float k1v = ak1[m][r] + kb1 + nK[g + 16 + (lane & 15)];
          prod[r] = (aq0[m][r] + qb0) * k0v + (aq1[m][r] + qb1) * k1v;
        }
        #pragma unroll
        for (int mm = 1; mm < 16; mm <<= 1) {
          #pragma unroll
          for (int r = 0; r < 4; ++r) prod[r] += __shfl_xor(prod[r], mm, 64);
        }
        if ((lane & 15) == 0) {
          #pragma unroll
          for (int r = 0; r < 4; ++r)
            sc[h * 96 + mt * 16 + ((lane >> 4) << 2) + r] = prod[r];
        }
      }
    }
  }
  __syncthreads();

  // ---- softmax: wave wid = head; 96 j over 64 lanes ----
  {
    const int h = wid;
    const float s0 = sc[h * 96 + lane] * SCALE;
    const float s1 = (lane < 32) ? sc[h * 96 + 64 + lane] * SCALE : -1e30f;
    float mx = fmaxf(s0, s1);
    #pragma unroll
    for (int m = 1; m < 64; m <<= 1) mx = fmaxf(mx, __shfl_xor(mx, m, 64));
    const float e0 = __expf(s0 - mx);
    const float e1 = (lane < 32) ? __expf(s1 - mx) : 0.f;
    float sm = e0 + e1;
    #pragma unroll
    for (int m = 1; m < 64; m <<= 1) sm += __shfl_xor(sm, m, 64);
    const float inv = 1.f / sm;
    sc[h * 96 + lane] = e0 * inv;
    if (lane < 32) sc[h * 96 + 64 + lane] = e1 * inv;
  }
  __syncthreads();

  // ---- Phase B: wave wid owns col tiles {wid, wid+8}; attn@V in regs ----
  {
    const f32x4 z = {0.f, 0.f, 0.f, 0.f};
    f32x4 acc[6][2] = {{z, z}, {z, z}, {z, z}, {z, z}, {z, z}, {z, z}};
    const unsigned short* wb0 = WeF + ((32 + wid) * 64 + lane) * 8;
    const unsigned short* wb1 = WeF + ((40 + wid) * 64 + lane) * 8;
    for (int kt = 0; kt < 8; ++kt) {
      const bf16x8 b0 = *(const bf16x8*)(wb0 + kt * 24576);
      const bf16x8 b1 = *(const bf16x8*)(wb1 + kt * 24576);
      #pragma unroll
      for (int mt = 0; mt < 6; ++mt) {
        const bf16x8 afr = *(const bf16x8*)(Elds + (mt * 16 + (lane & 15)) * LDE
                                            + ((lane >> 4) << 3) + kt * 32);
        acc[mt][0] = MFMA(afr, b0, acc[mt][0]);
        acc[mt][1] = MFMA(afr, b1, acc[mt][1]);
      }
    }
    const int col0 = wid * 16 + (lane & 15), col1 = col0 + 128;
    const int h0 = col0 >> 5, cc0 = col0 & 31;
    const int h1 = col1 >> 5, cc1 = col1 & 31;
    const float base0 = bias[512 + col0], base1 = bias[512 + col1];
    float nn[2] = {0.f, 0.f};
    #pragma unroll
    for (int mt = 0; mt < 6; ++mt) {
      #pragma unroll
      for (int r = 0; r < 4; ++r) {
        const int j = mt * 16 + ((lane >> 4) << 2) + r;
        const float v0 = acc[mt][0][r] + base0 + nV[((b * 8 + h0) * 96 + j) * 32 + cc0];
        const float v1 = acc[mt][1][r] + base1 + nV[((b * 8 + h1) * 96 + j) * 32 + cc1];
        nn[0] += sc[h0 * 96 + j] * v0;
        nn[1] += sc[h1 * 96 + j] * v1;
      }
    }
    #pragma unroll
    for (int s = 0; s < 2; ++s) {
      nn[s] += __shfl_xor(nn[s], 16, 64);
      nn[s] += __shfl_xor(nn[s], 32, 64);
    }
    if (lane < 16) {
      attw[bi * 256 + wid * 16 + lane] = nn[0];
      attw[bi * 256 + (wid + 8) * 16 + lane] = nn[1];
    }
  }
}

// ---------------------------------------------------------------------------
// K3: node FFN + residual + LayerNorm. 96 blocks x 256 threads, 8 rows each.
// ---------------------------------------------------------------------------
__global__ __launch_bounds__(256)
void node_ffn_ln(const float* __restrict__ attw, const float* __restrict__ node,
                 const float* __restrict__ W1, const float* __restrict__ B1,
                 const float* __restrict__ W2, const float* __restrict__ B2,
                 const float* __restrict__ g, const float* __restrict__ be,
                 float* __restrict__ node_out)
{
  __shared__ float xa[8][256];
  __shared__ float h1[8][256];
  __shared__ float xr[8][256];
  const int t = threadIdx.x, r0 = blockIdx.x * 8;
  #pragma unroll
  for (int rr = 0; rr < 8; ++rr) xa[rr][t] = attw[(r0 + rr) * 256 + t];
  __syncthreads();
  float acc[8];
  #pragma unroll
  for (int rr = 0; rr < 8; ++rr) acc[rr] = B1[t];
  for (int k = 0; k < 256; ++k) {
    const float w = W1[k * 256 + t];
    #pragma unroll
    for (int rr = 0; rr < 8; ++rr) acc[rr] += xa[rr][k] * w;
  }
  #pragma unroll
  for (int rr = 0; rr < 8; ++rr) h1[rr][t] = fmaxf(acc[rr], 0.f);
  __syncthreads();
  #pragma unroll
  for (int rr = 0; rr < 8; ++rr) acc[rr] = B2[t];
  for (int k = 0; k < 256; ++k) {
    const float w = W2[k * 256 + t];
    #pragma unroll
    for (int rr = 0; rr < 8; ++rr) acc[rr] += h1[rr][k] * w;
  }
  #pragma unroll
  for (int rr = 0; rr < 8; ++rr) xr[rr][t] = node[(r0 + rr) * 256 + t] + acc[rr];
  __syncthreads();
  const int wid = t >> 6, lane = t & 63;
  const float4 gv = *(const float4*)(g + (lane << 2));
  const float4 bv = *(const float4*)(be + (lane << 2));
  for (int rr = wid * 2; rr < wid * 2 + 2; ++rr) {
    const float4 xv = *(const float4*)(&xr[rr][lane << 2]);
    float s = xv.x + xv.y + xv.z + xv.w;
    float sq = xv.x * xv.x + xv.y * xv.y + xv.z * xv.z + xv.w * xv.w;
    #pragma unroll
    for (int m = 1; m < 64; m <<= 1) { s += __shfl_xor(s, m, 64); sq += __shfl_xor(sq, m, 64); }
    const float mean = s * (1.f / 256.f);
    const float rs = rsqrtf(sq * (1.f / 256.f) - mean * mean + 1e-5f);
    float4 o;
    o.x = (xv.x - mean) * rs * gv.x + bv.x;
    o.y = (xv.y - mean) * rs * gv.y + bv.y;
    o.z = (xv.z - mean) * rs * gv.z + bv.z;
    o.w = (xv.w - mean) * rs * gv.w + bv.w;
    *(float4*)(node_out + (r0 + rr) * 256 + (lane << 2)) = o;
  }
}

// ---------------------------------------------------------------------------
// K4: n1Q..n2V = node_out @ {Wn1,Wn2} (+bias), stored [B,H,N,HS].
// ---------------------------------------------------------------------------
__global__ __launch_bounds__(256)
void node_proj6(const float* __restrict__ nodeo,
                const float* __restrict__ W1, const float* __restrict__ B1,
                const float* __restrict__ W2, const float* __restrict__ B2,
                float* __restrict__ n1Q, float* __restrict__ n1K, float* __restrict__ n1V,
                float* __restrict__ n2Q, float* __restrict__ n2K, float* __restrict__ n2V)
{
  __shared__ float x[4][256];
  const int t = threadIdx.x, r0 = blockIdx.x * 4;
  #pragma unroll
  for (int rr = 0; rr < 4; ++rr) x[rr][t] = nodeo[(r0 + rr) * 256 + t];
  __syncthreads();
  float a[6][4];
  #pragma unroll
  for (int rr = 0; rr < 4; ++rr) {
    a[0][rr] = B1[t]; a[1][rr] = B1[256 + t]; a[2][rr] = B1[512 + t];
    a[3][rr] = B2[t]; a[4][rr] = B2[256 + t]; a[5][rr] = B2[512 + t];
  }
  for (int k = 0; k < 256; ++k) {
    const float w0 = W1[k * 256 + t], w1 = W1[65536 + k * 256 + t], w2 = W1[131072 + k * 256 + t];
    const float w3 = W2[k * 256 + t], w4 = W2[65536 + k * 256 + t], w5 = W2[131072 + k * 256 + t];
    #pragma unroll
    for (int rr = 0; rr < 4; ++rr) {
      const float xv = x[rr][k];
      a[0][rr] += xv * w0; a[1][rr] += xv * w1; a[2][rr] += xv * w2;
      a[3][rr] += xv * w3; a[4][rr] += xv * w4; a[5][rr] += xv * w5;
    }
  }
  const int h = t >> 5, c = t & 31;
  #pragma unroll
  for (int rr = 0; rr < 4; ++rr) {
    const int row = r0 + rr, b = row / 96, j = row - b * 96;
    const int oi = ((b * 8 + h) * 96 + j) * 32 + c;
    n1Q[oi] = a[0][rr]; n1K[oi] = a[1][rr]; n1V[oi] = a[2][rr];
    n2Q[oi] = a[3][rr]; n2K[oi] = a[4][rr]; n2V[oi] = a[5][rr];
  }
}

// ---------------------------------------------------------------------------
// K5: fused edge update for one (b,i). 512 threads (8 waves). LDS 62080 B.
// b->XCD swizzle. kt-outer MFMA loops; LN fused into EL2 epilogue; coalesced
// fp32 writeback from bf16-staged LN output.
// ---------------------------------------------------------------------------
__global__ __launch_bounds__(512, 2)
void edge_update(const float* __restrict__ edge, const float* __restrict__ Wee_b,
                 const unsigned short* __restrict__ WeeF,
                 const unsigned short* __restrict__ EL1F,
                 const unsigned short* __restrict__ EL2F,
                 const float* __restrict__ EL1_b, const float* __restrict__ EL2_b,
                 const float* __restrict__ n1Q, const float* __restrict__ n1K, const float* __restrict__ n1V,
                 const float* __restrict__ n2Q, const float* __restrict__ n2K, const float* __restrict__ n2V,
                 const float* __restrict__ lng, const float* __restrict__ lnb,
                 float* __restrict__ edge_out)
{
  __shared__ unsigned short Elds[96 * LDE];   // 50688 B (E -> attw_e -> hidden -> LN out)
  __shared__ float se[768];                   // 3072 B
  __shared__ float bn1[768];                  // 3072 B  (Wee_b + n1p)
  __shared__ float b12[512];                  // 2048 B
  __shared__ float lg[256], lb[256];          // 2048 B
  __shared__ float psum[8][16], psq[8][16];   // 1024 B
  __shared__ float statm[16], statr[16];      // 128 B

  const int tid = threadIdx.x, lane = tid & 63, wid = tid >> 6;
  const int b = blockIdx.x & 7, i = blockIdx.x >> 3;
  const size_t bi = (size_t)(b * 96 + i);

  for (int u = tid; u < 768; u += 512) {
    const int q = u >> 8, cn = u & 255, h = cn >> 5, c = cn & 31;
    const float* s = (q == 0) ? n1Q : (q == 1) ? n1K : n1V;
    bn1[u] = Wee_b[u] + s[((b * 8 + h) * 96 + i) * 32 + c];
  }
  b12[tid & 511] = (tid < 256) ? EL1_b[tid] : ((tid < 512) ? EL2_b[tid - 256] : 0.f);
  if (tid < 256) { lg[tid] = lng[tid]; lb[tid] = lnb[tid]; }

  const float* Erow = edge + bi * 24576;
  for (int u = tid; u < 96 * 64; u += 512) {
    const int j = u >> 6, g = u & 63;
    const float4 v = *(const float4*)(Erow + j * 256 + g * 4);
    const unsigned lo = (unsigned)f2bf(v.x) | ((unsigned)f2bf(v.y) << 16);
    const unsigned hi = (unsigned)f2bf(v.z) | ((unsigned)f2bf(v.w) << 16);
    *(uint2*)(Elds + j * LDE + g * 4) = make_uint2(lo, hi);
  }
  __syncthreads();

  // ---- Phase A: head h = wid; Qe,Ke projections folded into se dot ----
  {
    const int h = wid;
    const unsigned short* wq0 = WeeF + ((2 * h) * 64 + lane) * 8;
    const unsigned short* wq1 = WeeF + ((2 * h + 1) * 64 + lane) * 8;
    const unsigned short* wk0 = WeeF + ((16 + 2 * h) * 64 + lane) * 8;
    const unsigned short* wk1 = WeeF + ((17 + 2 * h) * 64 + lane) * 8;
    const int c0 = h * 32 + (lane & 15), c1 = c0 + 16;
    const float qb0 = bn1[c0], qb1 = bn1[c1];
    const float kb0 = bn1[256 + c0], kb1 = bn1[256 + c1];
    for (int half = 0; half < 3; ++half) {
      const f32x4 z = {0.f, 0.f, 0.f, 0.f};
      f32x4 aq0[2] = {z, z}, aq1[2] = {z, z}, ak0[2] = {z, z}, ak1[2] = {z, z};
      for (int kt = 0; kt < 8; ++kt) {
        const bf16x8 b0 = *(const bf16x8*)(wq0 + kt * 24576);
        const bf16x8 b1 = *(const bf16x8*)(wq1 + kt * 24576);
        const bf16x8 b2 = *(const bf16x8*)(wk0 + kt * 24576);
        const bf16x8 b3 = *(const bf16x8*)(wk1 + kt * 24576);
        #pragma unroll
        for (int m = 0; m < 2; ++m) {
          const int mt = half * 2 + m;
          const bf16x8 afr = *(const bf16x8*)(Elds + (mt * 16 + (lane & 15)) * LDE
                                              + ((lane >> 4) << 3) + kt * 32);
          aq0[m] = MFMA(afr, b0, aq0[m]);
          aq1[m] = MFMA(afr, b1, aq1[m]);
          ak0[m] = MFMA(afr, b2, ak0[m]);
          ak1[m] = MFMA(afr, b3, ak1[m]);
        }
      }
      #pragma unroll
      for (int m = 0; m < 2; ++m) {
        const int mt = half * 2 + m;
        float prod[4];
        #pragma unroll
        for (int r = 0; r < 4; ++r) {
          const int j = mt * 16 + ((lane >> 4) << 2) + r;
          const int g = ((b * 8 + h) * 96 + j) * 32;
          const float q0v = aq0[m][r] + qb0 + n2Q[g + (lane & 15)];
          const float q1v = aq1[m][r] + qb1 + n2Q[g + 16 + (lane & 15)];
          const float k0v = ak0[m][r] + kb0 + n2K[g + (lane & 15)];
          const float k1v = ak1[m][r] + kb1 + n2K[g + 16 + (lane & 15)];
          prod[r] = q0v * k0v + q1v * k1v;
        }
        #pragma unroll
        for (int mm = 1; mm < 16; mm <<= 1) {
          #pragma unroll
          for (int r = 0; r < 4; ++r) prod[r] += __shfl_xor(prod[r], mm, 64);
        }
        if ((lane & 15) == 0) {
          #pragma unroll
          for (int r = 0; r < 4; ++r)
            se[h * 96 + mt * 16 + ((lane >> 4) << 2) + r] = prod[r];
        }
      }
    }
  }
  __syncthreads();

  // ---- silu ----
  for (int u = tid; u < 768; u += 512) {
    const float s = se[u] * SCALE;
    se[u] = s / (1.f + __expf(-s));
  }
  __syncthreads();

  // ---- Phase B: Ve projection (kt-outer), scale by silu, in place ----
  {
    const f32x4 z = {0.f, 0.f, 0.f, 0.f};
    f32x4 acc[6][2] = {{z, z}, {z, z}, {z, z}, {z, z}, {z, z}, {z, z}};
    const unsigned short* wb0 = WeeF + ((32 + wid) * 64 + lane) * 8;
    const unsigned short* wb1 = WeeF + ((40 + wid) * 64 + lane) * 8;
    for (int kt = 0; kt < 8; ++kt) {
      const bf16x8 b0 = *(const bf16x8*)(wb0 + kt * 24576);
      const bf16x8 b1 = *(const bf16x8*)(wb1 + kt * 24576);
      #pragma unroll
      for (int mt = 0; mt < 6; ++mt) {
        const bf16x8 afr = *(const bf16x8*)(Elds + (mt * 16 + (lane & 15)) * LDE
                                            + ((lane >> 4) << 3) + kt * 32);
        acc[mt][0] = MFMA(afr, b0, acc[mt][0]);
        acc[mt][1] = MFMA(afr, b1, acc[mt][1]);
      }
    }
    __syncthreads();   // all E reads complete
    const int col0 = wid * 16 + (lane & 15), col1 = col0 + 128;
    const int h0 = col0 >> 5, cc0 = col0 & 31;
    const int h1 = col1 >> 5, cc1 = col1 & 31;
    const float base0 = bn1[512 + col0], base1 = bn1[512 + col1];
    #pragma unroll
    for (int mt = 0; mt < 6; ++mt) {
      #pragma unroll
      for (int r = 0; r < 4; ++r) {
        const int j = mt * 16 + ((lane >> 4) << 2) + r;
        const float v0 = acc[mt][0][r] + base0 + n2V[((b * 8 + h0) * 96 + j) * 32 + cc0];
        const float v1 = acc[mt][1][r] + base1 + n2V[((b * 8 + h1) * 96 + j) * 32 + cc1];
        Elds[j * LDE + col0] = f2bf(se[h0 * 96 + j] * v0);
        Elds[j * LDE + col1] = f2bf(se[h1 * 96 + j] * v1);
      }
    }
  }
  __syncthreads();

  // ---- EL1 + relu (kt-outer), in place (attw_e -> hidden) ----
  {
    const f32x4 z = {0.f, 0.f, 0.f, 0.f};
    f32x4 acc[6][2] = {{z, z}, {z, z}, {z, z}, {z, z}, {z, z}, {z, z}};
    const unsigned short* wb0 = EL1F + (wid * 64 + lane) * 8;
    const unsigned short* wb1 = EL1F + ((wid + 8) * 64 + lane) * 8;
    for (int kt = 0; kt < 8; ++kt) {
      const bf16x8 b0 = *(const bf16x8*)(wb0 + kt * 8192);
      const bf16x8 b1 = *(const bf16x8*)(wb1 + kt * 8192);
      #pragma unroll
      for (int mt = 0; mt < 6; ++mt) {
        const bf16x8 afr = *(const bf16x8*)(Elds + (mt * 16 + (lane & 15)) * LDE
                                            + ((lane >> 4) << 3) + kt * 32);
        acc[mt][0] = MFMA(afr, b0, acc[mt][0]);
        acc[mt][1] = MFMA(afr, b1, acc[mt][1]);
      }
    }
    __syncthreads();
    const int col0 = wid * 16 + (lane & 15), col1 = col0 + 128;
    const float bv0 = b12[col0], bv1 = b12[col1];
    #pragma unroll
    for (int mt = 0; mt < 6; ++mt) {
      #pragma unroll
      for (int r = 0; r < 4; ++r) {
        const int j = mt * 16 + ((lane >> 4) << 2) + r;
        Elds[j * LDE + col0] = f2bf(fmaxf(acc[mt][0][r] + bv0, 0.f));
        Elds[j * LDE + col1] = f2bf(fmaxf(acc[mt][1][r] + bv1, 0.f));
      }
    }
  }
  __syncthreads();

  // ---- EL2 (kt-outer) + residual + LayerNorm fused; bf16 LN out in place ----
  {
    const f32x4 z = {0.f, 0.f, 0.f, 0.f};
    f32x4 acc[6][2] = {{z, z}, {z, z}, {z, z}, {z, z}, {z, z}, {z, z}};
    const unsigned short* wb0 = EL2F + (wid * 64 + lane) * 8;
    const unsigned short* wb1 = EL2F + ((wid + 8) * 64 + lane) * 8;
    for (int kt = 0; kt < 8; ++kt) {
      const bf16x8 b0 = *(const bf16x8*)(wb0 + kt * 8192);
      const bf16x8 b1 = *(const bf16x8*)(wb1 + kt * 8192);
      #pragma unroll
      for (int mt = 0; mt < 6; ++mt) {
        const bf16x8 afr = *(const bf16x8*)(Elds + (mt * 16 + (lane & 15)) * LDE
                                            + ((lane >> 4) << 3) + kt * 32);
        acc[mt][0] = MFMA(afr, b0, acc[mt][0]);
        acc[mt][1] = MFMA(afr, b1, acc[mt][1]);
      }
    }
    __syncthreads();   // all hidden reads complete
    const int col0 = wid * 16 + (lane & 15), col1 = col0 + 128;
    const float bv0 = b12[256 + col0], bv1 = b12[256 + col1];
    const float g0 = lg[col0], g1 = lg[col1], be0 = lb[col0], be1 = lb[col1];
    for (int mt = 0; mt < 6; ++mt) {
      float v0[4], v1[4];
      #pragma unroll
      for (int r = 0; r < 4; ++r) {
        const int j = mt * 16 + ((lane >> 4) << 2) + r;
        v0[r] = acc[mt][0][r] + bv0 + Erow[j * 256 + col0];
        v1[r] = acc[mt][1][r] + bv1 + Erow[j * 256 + col1];
      }
      #pragma unroll
      for (int r = 0; r < 4; ++r) {
        float s = v0[r] + v1[r];
        float q = v0[r] * v0[r] + v1[r] * v1[r];
        #pragma unroll
        for (int m = 1; m < 16; m <<= 1) { s += __shfl_xor(s, m, 64); q += __shfl_xor(q, m, 64); }
        if ((lane & 15) == 0) {
          const int rloc = ((lane >> 4) << 2) + r;
          psum[wid][rloc] = s; psq[wid][rloc] = q;
        }
      }
      __syncthreads();
      if (tid < 16) {
        float s = 0.f, q = 0.f;
        #pragma unroll
        for (int w = 0; w < 8; ++w) { s += psum[w][tid]; q += psq[w][tid]; }
        const float mean = s * (1.f / 256.f);
        statm[tid] = mean;
        statr[tid] = rsqrtf(q * (1.f / 256.f) - mean * mean + 1e-5f);
      }
      __syncthreads();
      #pragma unroll
      for (int r = 0; r < 4; ++r) {
        const int rloc = ((lane >> 4) << 2) + r;
        const int j = mt * 16 + rloc;
        Elds[j * LDE + col0] = f2bf((v0[r] - statm[rloc]) * statr[rloc] * g0 + be0);
        Elds[j * LDE + col1] = f2bf((v1[r] - statm[rloc]) * statr[rloc] * g1 + be1);
      }
    }
  }
  __syncthreads();

  // ---- coalesced fp32 writeback: full 1KB rows ----
  float* orow = edge_out + bi * 24576;
  for (int j = wid; j < 96; j += 8) {
    const uint2 pk = *(const uint2*)(Elds + j * LDE + (lane << 2));
    float4 o;
    o.x = bf2f((unsigned short)(pk.x & 0xffff));
    o.y = bf2f((unsigned short)(pk.x >> 16));
    o.z = bf2f((unsigned short)(pk.y & 0xffff));
    o.w = bf2f((unsigned short)(pk.y >> 16));
    *(float4*)(orow + j * 256 + (lane << 2)) = o;
  }
}

// ---------------------------------------------------------------------------
extern "C" void kernel_launch(void* const* d_in, const int* in_sizes, int n_in,
                              void* d_out, int out_size, void* d_ws, size_t ws_size,
                              hipStream_t stream)
{
  (void)in_sizes; (void)n_in; (void)out_size; (void)ws_size;

  const float* node   = (const float*)d_in[0];
  const float* edge   = (const float*)d_in[1];
  const float* Wn_w   = (const float*)d_in[2];
  const float* Wn_b   = (const float*)d_in[3];
  const float* We_w   = (const float*)d_in[4];
  const float* We_b   = (const float*)d_in[5];
  const float* Wn1_w  = (const float*)d_in[6];
  const float* Wn1_b  = (const float*)d_in[7];
  const float* Wn2_w  = (const float*)d_in[8];
  const float* Wn2_b  = (const float*)d_in[9];
  const float* Wee_w  = (const float*)d_in[10];
  const float* Wee_b  = (const float*)d_in[11];
  const float* NL1_w  = (const float*)d_in[12];
  const float* NL1_b  = (const float*)d_in[13];
  const float* NL2_w  = (const float*)d_in[14];
  const float* NL2_b  = (const float*)d_in[15];
  const float* EL1_w  = (const float*)d_in[16];
  const float* EL1_b  = (const float*)d_in[17];
  const float* EL2_w  = (const float*)d_in[18];
  const float* EL2_b  = (const float*)d_in[19];
  const float* NLN1_g = (const float*)d_in[20];
  const float* NLN1_b = (const float*)d_in[21];
  const float* ELN1_g = (const float*)d_in[22];
  const float* ELN1_b = (const float*)d_in[23];

  float* out = (float*)d_out;
  float* node_out = out;               // [8,96,256]
  float* edge_out = out + 196608;      // [8,96,96,256]

  float* wsf = (float*)d_ws;
  float* nQ  = wsf;                float* nK  = wsf + 196608;   float* nV  = wsf + 393216;
  float* n1Q = wsf + 589824;       float* n1K = wsf + 786432;   float* n1V = wsf + 983040;
  float* n2Q = wsf + 1179648;      float* n2K = wsf + 1376256;  float* n2V = wsf + 1572864;
  float* attw = wsf + 1769472;
  unsigned short* fb   = (unsigned short*)(wsf + 1966080);
  unsigned short* WeF  = fb;                 // 196608
  unsigned short* WeeF = fb + 196608;        // 196608
  unsigned short* EL1F = fb + 393216;        // 65536
  unsigned short* EL2F = fb + 458752;        // 65536

  prep_frags<<<64, 256, 0, stream>>>(We_w, Wee_w, EL1_w, EL2_w, fb);
  node_qkv<<<192, 256, 0, stream>>>(node, Wn_w, Wn_b, nQ, nK, nV);
  node_attn<<<768, 512, 0, stream>>>(edge, We_b, WeF, nQ, nK, nV, attw);
  node_ffn_ln<<<96, 256, 0, stream>>>(attw, node, NL1_w, NL1_b, NL2_w, NL2_b,
                                      NLN1_g, NLN1_b, node_out);
  node_proj6<<<192, 256, 0, stream>>>(node_out, Wn1_w, Wn1_b, Wn2_w, Wn2_b,
                                      n1Q, n1K, n1V, n2Q, n2K, n2V);
  edge_update<<<768, 512, 0, stream>>>(edge, Wee_b, WeeF, EL1F, EL2F,
                                       EL1_b, EL2_b, n1Q, n1K, n1V,
                                       n2Q, n2K, n2V, ELN1_g, ELN1_b, edge_out);
}

// Round 7
// 285.373 us; speedup vs baseline: 2.4389x; 1.0287x over previous
//
#include <hip/hip_runtime.h>

// B=8 N=96 H=8 HS=32 NS=256.  bf16 MFMA 16x16x32 for all edge-side matmuls.
// v7: barrier attack. edge_update 21->9 barriers (silu fused into Phase A
// epilogue, Phase-B MFMA hoisted ahead of the se-publish barrier, EL2
// LayerNorm batched: all-mt partials -> 2 barriers). node_attn 8->3 barriers.
// prep_frags+node_qkv merged into one launch.

#define DI __device__ __forceinline__

typedef float f32x4 __attribute__((ext_vector_type(4)));
typedef short bf16x8 __attribute__((ext_vector_type(8)));

DI unsigned short f2bf(float f) {
  union { float f; unsigned u; } v; v.f = f;
  return (unsigned short)((v.u + 0x7FFFu + ((v.u >> 16) & 1u)) >> 16);
}
DI float bf2f(unsigned short h) {
  union { unsigned u; float f; } v; v.u = ((unsigned)h) << 16;
  return v.f;
}

#define LDE 264            // padded bf16 row stride
#define SCALE 0.17677669529663687f   // 1/sqrt(32)

#define MFMA(A, B, C) __builtin_amdgcn_mfma_f32_16x16x32_bf16((A), (B), (C), 0, 0, 0)

// ---------------------------------------------------------------------------
// K0: blocks 0-63: pack weights into bf16 MFMA B-fragment layout.
//     blocks 64-255: nQ/nK/nV = node @ Wn_w[q] + Wn_b[q]  ([B,H,N,HS]).
// ---------------------------------------------------------------------------
__global__ __launch_bounds__(256)
void prep_and_qkv(const float* __restrict__ We_w, const float* __restrict__ Wee_w,
                  const float* __restrict__ EL1_w, const float* __restrict__ EL2_w,
                  unsigned short* __restrict__ fb,
                  const float* __restrict__ node, const float* __restrict__ Ww,
                  const float* __restrict__ Wb, float* __restrict__ nQ,
                  float* __restrict__ nK, float* __restrict__ nV)
{
  __shared__ float Wl[32 * 256];
  const int t = threadIdx.x;
  if (blockIdx.x < 64) {
    const int blk = blockIdx.x, kt = blk & 7, ms = blk >> 3;
    const float* src; unsigned short* dst; int NT, ntbase;
    if (ms < 3)       { src = We_w  + ms * 65536;       dst = fb;          NT = 48; ntbase = ms * 16; }
    else if (ms < 6)  { src = Wee_w + (ms - 3) * 65536; dst = fb + 196608; NT = 48; ntbase = (ms - 3) * 16; }
    else if (ms == 6) { src = EL1_w;                    dst = fb + 393216; NT = 16; ntbase = 0; }
    else              { src = EL2_w;                    dst = fb + 458752; NT = 16; ntbase = 0; }
    for (int u = t; u < 32 * 64; u += 256) {
      const int r = u >> 6, c4 = (u & 63) << 2;
      *(float4*)(Wl + r * 256 + c4) = *(const float4*)(src + (kt * 32 + r) * 256 + c4);
    }
    __syncthreads();
    for (int u = t; u < 16 * 64; u += 256) {
      const int ntl = u >> 6, l = u & 63;
      const int kb = (l >> 4) << 3, c = ntl * 16 + (l & 15);
      unsigned short tmp[8];
      #pragma unroll
      for (int i = 0; i < 8; ++i) tmp[i] = f2bf(Wl[(kb + i) * 256 + c]);
      const int nt = ntbase + ntl;
      *(uint4*)(dst + ((size_t)(kt * NT + nt) * 64 + l) * 8) = *(const uint4*)tmp;
    }
  } else {
    float (*x)[256] = (float(*)[256])Wl;
    const int r0 = (blockIdx.x - 64) * 4;
    #pragma unroll
    for (int rr = 0; rr < 4; ++rr) x[rr][t] = node[(r0 + rr) * 256 + t];
    __syncthreads();
    float a0[4], a1[4], a2[4];
    #pragma unroll
    for (int rr = 0; rr < 4; ++rr) { a0[rr] = Wb[t]; a1[rr] = Wb[256 + t]; a2[rr] = Wb[512 + t]; }
    for (int k = 0; k < 256; ++k) {
      const float w0 = Ww[k * 256 + t], w1 = Ww[65536 + k * 256 + t], w2 = Ww[131072 + k * 256 + t];
      #pragma unroll
      for (int rr = 0; rr < 4; ++rr) {
        const float xv = x[rr][k];
        a0[rr] += xv * w0; a1[rr] += xv * w1; a2[rr] += xv * w2;
      }
    }
    const int h = t >> 5, c = t & 31;
    #pragma unroll
    for (int rr = 0; rr < 4; ++rr) {
      const int row = r0 + rr, b = row / 96, j = row - b * 96;
      const int oi = ((b * 8 + h) * 96 + j) * 32 + c;
      nQ[oi] = a0[rr]; nK[oi] = a1[rr]; nV[oi] = a2[rr];
    }
  }
}

// ---------------------------------------------------------------------------
// K2: fused node attention for one (b,i). 512 threads. LDS 57856 B.
// 3 barriers: stage | sc-publish (B-MFMA hoisted before) | attn-publish.
// ---------------------------------------------------------------------------
__global__ __launch_bounds__(512, 2)
void node_attn(const float* __restrict__ edge, const float* __restrict__ We_b,
               const unsigned short* __restrict__ WeF,
               const float* __restrict__ nQ, const float* __restrict__ nK,
               const float* __restrict__ nV, float* __restrict__ attw)
{
  __shared__ unsigned short Elds[96 * LDE];   // 50688 B
  __shared__ float sc[768];                   // 3072 B
  __shared__ float nQp[256];                  // 1024 B
  __shared__ float bias[768];                 // 3072 B

  const int tid = threadIdx.x, lane = tid & 63, wid = tid >> 6;
  const int b = blockIdx.x & 7, i = blockIdx.x >> 3;
  const size_t bi = (size_t)(b * 96 + i);

  if (tid < 256) nQp[tid] = nQ[((b * 8 + (tid >> 5)) * 96 + i) * 32 + (tid & 31)];
  for (int u = tid; u < 768; u += 512) bias[u] = We_b[u];

  const float* Erow = edge + bi * 24576;
  for (int u = tid; u < 96 * 64; u += 512) {
    const int j = u >> 6, g = u & 63;
    const float4 v = *(const float4*)(Erow + j * 256 + g * 4);
    const unsigned lo = (unsigned)f2bf(v.x) | ((unsigned)f2bf(v.y) << 16);
    const unsigned hi = (unsigned)f2bf(v.z) | ((unsigned)f2bf(v.w) << 16);
    *(uint2*)(Elds + j * LDE + g * 4) = make_uint2(lo, hi);
  }
  __syncthreads();                                   // bar1: E staged

  // ---- Phase A: head h = wid; Q,K projections folded into score dot ----
  {
    const int h = wid;
    const unsigned short* wq0 = WeF + ((2 * h) * 64 + lane) * 8;
    const unsigned short* wq1 = WeF + ((2 * h + 1) * 64 + lane) * 8;
    const unsigned short* wk0 = WeF + ((16 + 2 * h) * 64 + lane) * 8;
    const unsigned short* wk1 = WeF + ((17 + 2 * h) * 64 + lane) * 8;
    const int c0 = h * 32 + (lane & 15), c1 = c0 + 16;
    const float qb0 = bias[c0] + nQp[c0], qb1 = bias[c1] + nQp[c1];
    const float kb0 = bias[256 + c0], kb1 = bias[256 + c1];
    for (int half = 0; half < 3; ++half) {
      const f32x4 z = {0.f, 0.f, 0.f, 0.f};
      f32x4 aq0[2] = {z, z}, aq1[2] = {z, z}, ak0[2] = {z, z}, ak1[2] = {z, z};
      for (int kt = 0; kt < 8; ++kt) {
        const bf16x8 b0 = *(const bf16x8*)(wq0 + kt * 24576);
        const bf16x8 b1 = *(const bf16x8*)(wq1 + kt * 24576);
        const bf16x8 b2 = *(const bf16x8*)(wk0 + kt * 24576);
        const bf16x8 b3 = *(const bf16x8*)(wk1 + kt * 24576);
        #pragma unroll
        for (int m = 0; m < 2; ++m) {
          const int mt = half * 2 + m;
          const bf16x8 afr = *(const bf16x8*)(Elds + (mt * 16 + (lane & 15)) * LDE
                                              + ((lane >> 4) << 3) + kt * 32);
          aq0[m] = MFMA(afr, b0, aq0[m]);
          aq1[m] = MFMA(afr, b1, aq1[m]);
          ak0[m] = MFMA(afr, b2, ak0[m]);
          ak1[m] = MFMA(afr, b3, ak1[m]);
        }
      }
      #pragma unroll
      for (int m = 0; m < 2; ++m) {
        const int mt = half * 2 + m;
        float prod[4];
        #pragma unroll
        for (int r = 0; r < 4; ++r) {
          const int j = mt * 16 + ((lane >> 4) << 2) + r;
          const int g = ((b * 8 + h) * 96 + j) * 32;
          const float k0v = ak0[m][r] + kb0 + nK[g + (lane & 15)];
          const float k1v = ak1[m][r] + kb1 + nK[g + 16 + (lane & 15)];
          prod[r] = (aq0[m][r] + qb0) * k0v + (aq1[m][r] + qb1) * k1v;
        }
        #pragma unroll
        for (int mm = 1; mm < 16; mm <<= 1) {
          #pragma unroll
          for (int r = 0; r < 4; ++r) prod[r] += __shfl_xor(prod[r], mm, 64);
        }
        if ((lane & 15) == 0) {
          #pragma unroll
          for (int r = 0; r < 4; ++r)
            sc[h * 96 + mt * 16 + ((lane >> 4) << 2) + r] = prod[r];
        }
      }
    }
  }

  // ---- Phase B MFMA (independent of sc) hoisted before the barrier ----
  const f32x4 z = {0.f, 0.f, 0.f, 0.f};
  f32x4 accB[6][2] = {{z, z}, {z, z}, {z, z}, {z, z}, {z, z}, {z, z}};
  {
    const unsigned short* wb0 = WeF + ((32 + wid) * 64 + lane) * 8;
    const unsigned short* wb1 = WeF + ((40 + wid) * 64 + lane) * 8;
    for (int kt = 0; kt < 8; ++kt) {
      const bf16x8 b0 = *(const bf16x8*)(wb0 + kt * 24576);
      const bf16x8 b1 = *(const bf16x8*)(wb1 + kt * 24576);
      #pragma unroll
      for (int mt = 0; mt < 6; ++mt) {
        const bf16x8 afr = *(const bf16x8*)(Elds + (mt * 16 + (lane & 15)) * LDE
                                            + ((lane >> 4) << 3) + kt * 32);
        accB[mt][0] = MFMA(afr, b0, accB[mt][0]);
        accB[mt][1] = MFMA(afr, b1, accB[mt][1]);
      }
    }
  }
  __syncthreads();                                   // bar2: sc published

  // ---- softmax: wave wid = head wid (wave-local rows) ----
  {
    const int h = wid;
    const float s0 = sc[h * 96 + lane] * SCALE;
    const float s1 = (lane < 32) ? sc[h * 96 + 64 + lane] * SCALE : -1e30f;
    float mx = fmaxf(s0, s1);
    #pragma unroll
    for (int m = 1; m < 64; m <<= 1) mx = fmaxf(mx, __shfl_xor(mx, m, 64));
    const float e0 = __expf(s0 - mx);
    const float e1 = (lane < 32) ? __expf(s1 - mx) : 0.f;
    float sm = e0 + e1;
    #pragma unroll
    for (int m = 1; m < 64; m <<= 1) sm += __shfl_xor(sm, m, 64);
    const float inv = 1.f / sm;
    sc[h * 96 + lane] = e0 * inv;
    if (lane < 32) sc[h * 96 + 64 + lane] = e1 * inv;
  }
  __syncthreads();                                   // bar3: attn published

  // ---- Phase B epilogue: attn@V in regs ----
  {
    const int col0 = wid * 16 + (lane & 15), col1 = col0 + 128;
    const int h0 = col0 >> 5, cc0 = col0 & 31;
    const int h1 = col1 >> 5, cc1 = col1 & 31;
    const float base0 = bias[512 + col0], base1 = bias[512 + col1];
    float nn[2] = {0.f, 0.f};
    #pragma unroll
    for (int mt = 0; mt < 6; ++mt) {
      #pragma unroll
      for (int r = 0; r < 4; ++r) {
        const int j = mt * 16 + ((lane >> 4) << 2) + r;
        const float v0 = accB[mt][0][r] + base0 + nV[((b * 8 + h0) * 96 + j) * 32 + cc0];
        const float v1 = accB[mt][1][r] + base1 + nV[((b * 8 + h1) * 96 + j) * 32 + cc1];
        nn[0] += sc[h0 * 96 + j] * v0;
        nn[1] += sc[h1 * 96 + j] * v1;
      }
    }
    #pragma unroll
    for (int s = 0; s < 2; ++s) {
      nn[s] += __shfl_xor(nn[s], 16, 64);
      nn[s] += __shfl_xor(nn[s], 32, 64);
    }
    if (lane < 16) {
      attw[bi * 256 + wid * 16 + lane] = nn[0];
      attw[bi * 256 + (wid + 8) * 16 + lane] = nn[1];
    }
  }
}

// ---------------------------------------------------------------------------
// K3: node FFN + residual + LayerNorm. 96 blocks x 256 threads, 8 rows each.
// ---------------------------------------------------------------------------
__global__ __launch_bounds__(256)
void node_ffn_ln(const float* __restrict__ attw, const float* __restrict__ node,
                 const float* __restrict__ W1, const float* __restrict__ B1,
                 const float* __restrict__ W2, const float* __restrict__ B2,
                 const float* __restrict__ g, const float* __restrict__ be,
                 float* __restrict__ node_out)
{
  __shared__ float xa[8][256];
  __shared__ float h1[8][256];
  __shared__ float xr[8][256];
  const int t = threadIdx.x, r0 = blockIdx.x * 8;
  #pragma unroll
  for (int rr = 0; rr < 8; ++rr) xa[rr][t] = attw[(r0 + rr) * 256 + t];
  __syncthreads();
  float acc[8];
  #pragma unroll
  for (int rr = 0; rr < 8; ++rr) acc[rr] = B1[t];
  for (int k = 0; k < 256; ++k) {
    const float w = W1[k * 256 + t];
    #pragma unroll
    for (int rr = 0; rr < 8; ++rr) acc[rr] += xa[rr][k] * w;
  }
  #pragma unroll
  for (int rr = 0; rr < 8; ++rr) h1[rr][t] = fmaxf(acc[rr], 0.f);
  __syncthreads();
  #pragma unroll
  for (int rr = 0; rr < 8; ++rr) acc[rr] = B2[t];
  for (int k = 0; k < 256; ++k) {
    const float w = W2[k * 256 + t];
    #pragma unroll
    for (int rr = 0; rr < 8; ++rr) acc[rr] += h1[rr][k] * w;
  }
  #pragma unroll
  for (int rr = 0; rr < 8; ++rr) xr[rr][t] = node[(r0 + rr) * 256 + t] + acc[rr];
  __syncthreads();
  const int wid = t >> 6, lane = t & 63;
  const float4 gv = *(const float4*)(g + (lane << 2));
  const float4 bv = *(const float4*)(be + (lane << 2));
  for (int rr = wid * 2; rr < wid * 2 + 2; ++rr) {
    const float4 xv = *(const float4*)(&xr[rr][lane << 2]);
    float s = xv.x + xv.y + xv.z + xv.w;
    float sq = xv.x * xv.x + xv.y * xv.y + xv.z * xv.z + xv.w * xv.w;
    #pragma unroll
    for (int m = 1; m < 64; m <<= 1) { s += __shfl_xor(s, m, 64); sq += __shfl_xor(sq, m, 64); }
    const float mean = s * (1.f / 256.f);
    const float rs = rsqrtf(sq * (1.f / 256.f) - mean * mean + 1e-5f);
    float4 o;
    o.x = (xv.x - mean) * rs * gv.x + bv.x;
    o.y = (xv.y - mean) * rs * gv.y + bv.y;
    o.z = (xv.z - mean) * rs * gv.z + bv.z;
    o.w = (xv.w - mean) * rs * gv.w + bv.w;
    *(float4*)(node_out + (r0 + rr) * 256 + (lane << 2)) = o;
  }
}

// ---------------------------------------------------------------------------
// K4: n1Q..n2V = node_out @ {Wn1,Wn2} (+bias), stored [B,H,N,HS].
// ---------------------------------------------------------------------------
__global__ __launch_bounds__(256)
void node_proj6(const float* __restrict__ nodeo,
                const float* __restrict__ W1, const float* __restrict__ B1,
                const float* __restrict__ W2, const float* __restrict__ B2,
                float* __restrict__ n1Q, float* __restrict__ n1K, float* __restrict__ n1V,
                float* __restrict__ n2Q, float* __restrict__ n2K, float* __restrict__ n2V)
{
  __shared__ float x[4][256];
  const int t = threadIdx.x, r0 = blockIdx.x * 4;
  #pragma unroll
  for (int rr = 0; rr < 4; ++rr) x[rr][t] = nodeo[(r0 + rr) * 256 + t];
  __syncthreads();
  float a[6][4];
  #pragma unroll
  for (int rr = 0; rr < 4; ++rr) {
    a[0][rr] = B1[t]; a[1][rr] = B1[256 + t]; a[2][rr] = B1[512 + t];
    a[3][rr] = B2[t]; a[4][rr] = B2[256 + t]; a[5][rr] = B2[512 + t];
  }
  for (int k = 0; k < 256; ++k) {
    const float w0 = W1[k * 256 + t], w1 = W1[65536 + k * 256 + t], w2 = W1[131072 + k * 256 + t];
    const float w3 = W2[k * 256 + t], w4 = W2[65536 + k * 256 + t], w5 = W2[131072 + k * 256 + t];
    #pragma unroll
    for (int rr = 0; rr < 4; ++rr) {
      const float xv = x[rr][k];
      a[0][rr] += xv * w0; a[1][rr] += xv * w1; a[2][rr] += xv * w2;
      a[3][rr] += xv * w3; a[4][rr] += xv * w4; a[5][rr] += xv * w5;
    }
  }
  const int h = t >> 5, c = t & 31;
  #pragma unroll
  for (int rr = 0; rr < 4; ++rr) {
    const int row = r0 + rr, b = row / 96, j = row - b * 96;
    const int oi = ((b * 8 + h) * 96 + j) * 32 + c;
    n1Q[oi] = a[0][rr]; n1K[oi] = a[1][rr]; n1V[oi] = a[2][rr];
    n2Q[oi] = a[3][rr]; n2K[oi] = a[4][rr]; n2V[oi] = a[5][rr];
  }
}

// ---------------------------------------------------------------------------
// K5: fused edge update for one (b,i). 512 threads. LDS 60928 B. 9 barriers.
// silu fused into Phase A epilogue; B-MFMA hoisted; EL2 LN batched (2 bars).
// ---------------------------------------------------------------------------
__global__ __launch_bounds__(512, 2)
void edge_update(const float* __restrict__ edge, const float* __restrict__ Wee_b,
                 const unsigned short* __restrict__ WeeF,
                 const unsigned short* __restrict__ EL1F,
                 const unsigned short* __restrict__ EL2F,
                 const float* __restrict__ EL1_b, const float* __restrict__ EL2_b,
                 const float* __restrict__ n1Q, const float* __restrict__ n1K, const float* __restrict__ n1V,
                 const float* __restrict__ n2Q, const float* __restrict__ n2K, const float* __restrict__ n2V,
                 const float* __restrict__ lng, const float* __restrict__ lnb,
                 float* __restrict__ edge_out)
{
  __shared__ unsigned short Elds[96 * LDE];   // 50688 B (E -> attw_e -> hidden -> LN out)
  __shared__ float se[768];                   // silu(scores); later psum[8][96]
  __shared__ float bn1[768];                  // Wee_b + n1p;  later psq[8][96]
  __shared__ float b12[512];                  // EL1|EL2 bias; [0..191] later stats
  __shared__ float lg[256], lb[256];          // 2048 B

  const int tid = threadIdx.x, lane = tid & 63, wid = tid >> 6;
  const int b = blockIdx.x & 7, i = blockIdx.x >> 3;
  const size_t bi = (size_t)(b * 96 + i);

  for (int u = tid; u < 768; u += 512) {
    const int q = u >> 8, cn = u & 255, h = cn >> 5, c = cn & 31;
    const float* s = (q == 0) ? n1Q : (q == 1) ? n1K : n1V;
    bn1[u] = Wee_b[u] + s[((b * 8 + h) * 96 + i) * 32 + c];
  }
  b12[tid] = (tid < 256) ? EL1_b[tid] : EL2_b[tid - 256];
  if (tid < 256) { lg[tid] = lng[tid]; lb[tid] = lnb[tid]; }

  const float* Erow = edge + bi * 24576;
  for (int u = tid; u < 96 * 64; u += 512) {
    const int j = u >> 6, g = u & 63;
    const float4 v = *(const float4*)(Erow + j * 256 + g * 4);
    const unsigned lo = (unsigned)f2bf(v.x) | ((unsigned)f2bf(v.y) << 16);
    const unsigned hi = (unsigned)f2bf(v.z) | ((unsigned)f2bf(v.w) << 16);
    *(uint2*)(Elds + j * LDE + g * 4) = make_uint2(lo, hi);
  }
  __syncthreads();                                   // bar1: E staged

  // ---- Phase A: Qe,Ke projections folded into se dot; silu at write ----
  {
    const int h = wid;
    const unsigned short* wq0 = WeeF + ((2 * h) * 64 + lane) * 8;
    const unsigned short* wq1 = WeeF + ((2 * h + 1) * 64 + lane) * 8;
    const unsigned short* wk0 = WeeF + ((16 + 2 * h) * 64 + lane) * 8;
    const unsigned short* wk1 = WeeF + ((17 + 2 * h) * 64 + lane) * 8;
    const int c0 = h * 32 + (lane & 15), c1 = c0 + 16;
    const float qb0 = bn1[c0], qb1 = bn1[c1];
    const float kb0 = bn1[256 + c0], kb1 = bn1[256 + c1];
    for (int half = 0; half < 3; ++half) {
      const f32x4 z = {0.f, 0.f, 0.f, 0.f};
      f32x4 aq0[2] = {z, z}, aq1[2] = {z, z}, ak0[2] = {z, z}, ak1[2] = {z, z};
      for (int kt = 0; kt < 8; ++kt) {
        const bf16x8 b0 = *(const bf16x8*)(wq0 + kt * 24576);
        const bf16x8 b1 = *(const bf16x8*)(wq1 + kt * 24576);
        const bf16x8 b2 = *(const bf16x8*)(wk0 + kt * 24576);
        const bf16x8 b3 = *(const bf16x8*)(wk1 + kt * 24576);
        #pragma unroll
        for (int m = 0; m < 2; ++m) {
          const int mt = half * 2 + m;
          const bf16x8 afr = *(const bf16x8*)(Elds + (mt * 16 + (lane & 15)) * LDE
                                              + ((lane >> 4) << 3) + kt * 32);
          aq0[m] = MFMA(afr, b0, aq0[m]);
          aq1[m] = MFMA(afr, b1, aq1[m]);
          ak0[m] = MFMA(afr, b2, ak0[m]);
          ak1[m] = MFMA(afr, b3, ak1[m]);
        }
      }
      #pragma unroll
      for (int m = 0; m < 2; ++m) {
        const int mt = half * 2 + m;
        float prod[4];
        #pragma unroll
        for (int r = 0; r < 4; ++r) {
          const int j = mt * 16 + ((lane >> 4) << 2) + r;
          const int g = ((b * 8 + h) * 96 + j) * 32;
          const float q0v = aq0[m][r] + qb0 + n2Q[g + (lane & 15)];
          const float q1v = aq1[m][r] + qb1 + n2Q[g + 16 + (lane & 15)];
          const float k0v = ak0[m][r] + kb0 + n2K[g + (lane & 15)];
          const float k1v = ak1[m][r] + kb1 + n2K[g + 16 + (lane & 15)];
          prod[r] = q0v * k0v + q1v * k1v;
        }
        #pragma unroll
        for (int mm = 1; mm < 16; mm <<= 1) {
          #pragma unroll
          for (int r = 0; r < 4; ++r) prod[r] += __shfl_xor(prod[r], mm, 64);
        }
        if ((lane & 15) == 0) {
          #pragma unroll
          for (int r = 0; r < 4; ++r) {
            const float d = prod[r] * SCALE;
            se[h * 96 + mt * 16 + ((lane >> 4) << 2) + r] = d / (1.f + __expf(-d));
          }
        }
      }
    }
  }

  // ---- Phase B MFMA (reads E only) hoisted before the se barrier ----
  const f32x4 z = {0.f, 0.f, 0.f, 0.f};
  f32x4 acc[6][2] = {{z, z}, {z, z}, {z, z}, {z, z}, {z, z}, {z, z}};
  {
    const unsigned short* wb0 = WeeF + ((32 + wid) * 64 + lane) * 8;
    const unsigned short* wb1 = WeeF + ((40 + wid) * 64 + lane) * 8;
    for (int kt = 0; kt < 8; ++kt) {
      const bf16x8 b0 = *(const bf16x8*)(wb0 + kt * 24576);
      const bf16x8 b1 = *(const bf16x8*)(wb1 + kt * 24576);
      #pragma unroll
      for (int mt = 0; mt < 6; ++mt) {
        const bf16x8 afr = *(const bf16x8*)(Elds + (mt * 16 + (lane & 15)) * LDE
                                            + ((lane >> 4) << 3) + kt * 32);
        acc[mt][0] = MFMA(afr, b0, acc[mt][0]);
        acc[mt][1] = MFMA(afr, b1, acc[mt][1]);
      }
    }
  }
  __syncthreads();                                   // bar2: se done + E reads done

  // ---- Phase B epilogue: attw_e = silu * (Ve+...), write in place ----
  {
    const int col0 = wid * 16 + (lane & 15), col1 = col0 + 128;
    const int h0 = col0 >> 5, cc0 = col0 & 31;
    const int h1 = col1 >> 5, cc1 = col1 & 31;
    const float base0 = bn1[512 + col0], base1 = bn1[512 + col1];
    #pragma unroll
    for (int mt = 0; mt < 6; ++mt) {
      #pragma unroll
      for (int r = 0; r < 4; ++r) {
        const int j = mt * 16 + ((lane >> 4) << 2) + r;
        const float v0 = acc[mt][0][r] + base0 + n2V[((b * 8 + h0) * 96 + j) * 32 + cc0];
        const float v1 = acc[mt][1][r] + base1 + n2V[((b * 8 + h1) * 96 + j) * 32 + cc1];
        Elds[j * LDE + col0] = f2bf(se[h0 * 96 + j] * v0);
        Elds[j * LDE + col1] = f2bf(se[h1 * 96 + j] * v1);
      }
    }
  }
  __syncthreads();                                   // bar3: attw_e published

  // ---- EL1 + relu (kt-outer), in place ----
  {
    #pragma unroll
    for (int mt = 0; mt < 6; ++mt) { acc[mt][0] = z; acc[mt][1] = z; }
    const unsigned short* wb0 = EL1F + (wid * 64 + lane) * 8;
    const unsigned short* wb1 = EL1F + ((wid + 8) * 64 + lane) * 8;
    for (int kt = 0; kt < 8; ++kt) {
      const bf16x8 b0 = *(const bf16x8*)(wb0 + kt * 8192);
      const bf16x8 b1 = *(const bf16x8*)(wb1 + kt * 8192);
      #pragma unroll
      for (int mt = 0; mt < 6; ++mt) {
        const bf16x8 afr = *(const bf16x8*)(Elds + (mt * 16 + (lane & 15)) * LDE
                                            + ((lane >> 4) << 3) + kt * 32);
        acc[mt][0] = MFMA(afr, b0, acc[mt][0]);
        acc[mt][1] = MFMA(afr, b1, acc[mt][1]);
      }
    }
    __syncthreads();                                 // bar4: attw_e reads done
    const int col0 = wid * 16 + (lane & 15), col1 = col0 + 128;
    const float bv0 = b12[col0], bv1 = b12[col1];
    #pragma unroll
    for (int mt = 0; mt < 6; ++mt) {
      #pragma unroll
      for (int r = 0; r < 4; ++r) {
        const int j = mt * 16 + ((lane >> 4) << 2) + r;
        Elds[j * LDE + col0] = f2bf(fmaxf(acc[mt][0][r] + bv0, 0.f));
        Elds[j * LDE + col1] = f2bf(fmaxf(acc[mt][1][r] + bv1, 0.f));
      }
    }
  }
  __syncthreads();                                   // bar5: hidden published

  // ---- EL2 (kt-outer) + residual + batched LayerNorm ----
  {
    #pragma unroll
    for (int mt = 0; mt < 6; ++mt) { acc[mt][0] = z; acc[mt][1] = z; }
    const unsigned short* wb0 = EL2F + (wid * 64 + lane) * 8;
    const unsigned short* wb1 = EL2F + ((wid + 8) * 64 + lane) * 8;
    for (int kt = 0; kt < 8; ++kt) {
      const bf16x8 b0 = *(const bf16x8*)(wb0 + kt * 8192);
      const bf16x8 b1 = *(const bf16x8*)(wb1 + kt * 8192);
      #pragma unroll
      for (int mt = 0; mt < 6; ++mt) {
        const bf16x8 afr = *(const bf16x8*)(Elds + (mt * 16 + (lane & 15)) * LDE
                                            + ((lane >> 4) << 3) + kt * 32);
        acc[mt][0] = MFMA(afr, b0, acc[mt][0]);
        acc[mt][1] = MFMA(afr, b1, acc[mt][1]);
      }
    }
    const int col0 = wid * 16 + (lane & 15), col1 = col0 + 128;
    const float bv0 = b12[256 + col0], bv1 = b12[256 + col1];
    const float g0 = lg[col0], g1 = lg[col1], be0 = lb[col0], be1 = lb[col1];
    __syncthreads();                                 // bar6: hidden reads done (se/bn1 free)
    // v = acc + bias + E residual (reuse acc registers)
    #pragma unroll
    for (int mt = 0; mt < 6; ++mt) {
      #pragma unroll
      for (int r = 0; r < 4; ++r) {
        const int j = mt * 16 + ((lane >> 4) << 2) + r;
        acc[mt][0][r] += bv0 + Erow[j * 256 + col0];
        acc[mt][1][r] += bv1 + Erow[j * 256 + col1];
      }
    }
    // per-wave partials for all 6 mt into se/bn1 re-typed [8][96]
    #pragma unroll
    for (int mt = 0; mt < 6; ++mt) {
      #pragma unroll
      for (int r = 0; r < 4; ++r) {
        float s = acc[mt][0][r] + acc[mt][1][r];
        float q = acc[mt][0][r] * acc[mt][0][r] + acc[mt][1][r] * acc[mt][1][r];
        #pragma unroll
        for (int m = 1; m < 16; m <<= 1) { s += __shfl_xor(s, m, 64); q += __shfl_xor(q, m, 64); }
        if ((lane & 15) == 0) {
          const int j = mt * 16 + ((lane >> 4) << 2) + r;
          se[wid * 96 + j] = s; bn1[wid * 96 + j] = q;
        }
      }
    }
    __syncthreads();                                 // bar7: partials published
    if (tid < 96) {
      float s = 0.f, q = 0.f;
      #pragma unroll
      for (int w = 0; w < 8; ++w) { s += se[w * 96 + tid]; q += bn1[w * 96 + tid]; }
      const float mean = s * (1.f / 256.f);
      b12[tid] = mean;
      b12[96 + tid] = rsqrtf(q * (1.f / 256.f) - mean * mean + 1e-5f);
    }
    __syncthreads();                                 // bar8: stats published
    #pragma unroll
    for (int mt = 0; mt < 6; ++mt) {
      #pragma unroll
      for (int r = 0; r < 4; ++r) {
        const int j = mt * 16 + ((lane >> 4) << 2) + r;
        const float mean = b12[j], rs = b12[96 + j];
        Elds[j * LDE + col0] = f2bf((acc[mt][0][r] - mean) * rs * g0 + be0);
        Elds[j * LDE + col1] = f2bf((acc[mt][1][r] - mean) * rs * g1 + be1);
      }
    }
  }
  __syncthreads();                                   // bar9: LN out staged

  // ---- coalesced fp32 writeback: full 1KB rows ----
  float* orow = edge_out + bi * 24576;
  for (int j = wid; j < 96; j += 8) {
    const uint2 pk = *(const uint2*)(Elds + j * LDE + (lane << 2));
    float4 o;
    o.x = bf2f((unsigned short)(pk.x & 0xffff));
    o.y = bf2f((unsigned short)(pk.x >> 16));
    o.z = bf2f((unsigned short)(pk.y & 0xffff));
    o.w = bf2f((unsigned short)(pk.y >> 16));
    *(float4*)(orow + j * 256 + (lane << 2)) = o;
  }
}

// ---------------------------------------------------------------------------
extern "C" void kernel_launch(void* const* d_in, const int* in_sizes, int n_in,
                              void* d_out, int out_size, void* d_ws, size_t ws_size,
                              hipStream_t stream)
{
  (void)in_sizes; (void)n_in; (void)out_size; (void)ws_size;

  const float* node   = (const float*)d_in[0];
  const float* edge   = (const float*)d_in[1];
  const float* Wn_w   = (const float*)d_in[2];
  const float* Wn_b   = (const float*)d_in[3];
  const float* We_w   = (const float*)d_in[4];
  const float* We_b   = (const float*)d_in[5];
  const float* Wn1_w  = (const float*)d_in[6];
  const float* Wn1_b  = (const float*)d_in[7];
  const float* Wn2_w  = (const float*)d_in[8];
  const float* Wn2_b  = (const float*)d_in[9];
  const float* Wee_w  = (const float*)d_in[10];
  const float* Wee_b  = (const float*)d_in[11];
  const float* NL1_w  = (const float*)d_in[12];
  const float* NL1_b  = (const float*)d_in[13];
  const float* NL2_w  = (const float*)d_in[14];
  const float* NL2_b  = (const float*)d_in[15];
  const float* EL1_w  = (const float*)d_in[16];
  const float* EL1_b  = (const float*)d_in[17];
  const float* EL2_w  = (const float*)d_in[18];
  const float* EL2_b  = (const float*)d_in[19];
  const float* NLN1_g = (const float*)d_in[20];
  const float* NLN1_b = (const float*)d_in[21];
  const float* ELN1_g = (const float*)d_in[22];
  const float* ELN1_b = (const float*)d_in[23];

  float* out = (float*)d_out;
  float* node_out = out;               // [8,96,256]
  float* edge_out = out + 196608;      // [8,96,96,256]

  float* wsf = (float*)d_ws;
  float* nQ  = wsf;                float* nK  = wsf + 196608;   float* nV  = wsf + 393216;
  float* n1Q = wsf + 589824;       float* n1K = wsf + 786432;   float* n1V = wsf + 983040;
  float* n2Q = wsf + 1179648;      float* n2K = wsf + 1376256;  float* n2V = wsf + 1572864;
  float* attw = wsf + 1769472;
  unsigned short* fb   = (unsigned short*)(wsf + 1966080);
  unsigned short* WeF  = fb;                 // 196608
  unsigned short* WeeF = fb + 196608;        // 196608
  unsigned short* EL1F = fb + 393216;        // 65536
  unsigned short* EL2F = fb + 458752;        // 65536

  prep_and_qkv<<<256, 256, 0, stream>>>(We_w, Wee_w, EL1_w, EL2_w, fb,
                                        node, Wn_w, Wn_b, nQ, nK, nV);
  node_attn<<<768, 512, 0, stream>>>(edge, We_b, WeF, nQ, nK, nV, attw);
  node_ffn_ln<<<96, 256, 0, stream>>>(attw, node, NL1_w, NL1_b, NL2_w, NL2_b,
                                      NLN1_g, NLN1_b, node_out);
  node_proj6<<<192, 256, 0, stream>>>(node_out, Wn1_w, Wn1_b, Wn2_w, Wn2_b,
                                      n1Q, n1K, n1V, n2Q, n2K, n2V);
  edge_update<<<768, 512, 0, stream>>>(edge, Wee_b, WeeF, EL1F, EL2F,
                                       EL1_b, EL2_b, n1Q, n1K, n1V,
                                       n2Q, n2K, n2V, ELN1_g, ELN1_b, edge_out);
}

// Round 8
// 271.621 us; speedup vs baseline: 2.5623x; 1.0506x over previous
//
#include <hip/hip_runtime.h>

// B=8 N=96 H=8 HS=32 NS=256.  bf16 MFMA 16x16x32 for all edge-side matmuls.
// v8: Phase A B-load cut (2 passes x 3 mt, 64 loads/wave vs 96), s_setprio
// around MFMA clusters, node FFN+proj6 fused into one row-local kernel.

#define DI __device__ __forceinline__

typedef float f32x4 __attribute__((ext_vector_type(4)));
typedef short bf16x8 __attribute__((ext_vector_type(8)));

DI unsigned short f2bf(float f) {
  union { float f; unsigned u; } v; v.f = f;
  return (unsigned short)((v.u + 0x7FFFu + ((v.u >> 16) & 1u)) >> 16);
}
DI float bf2f(unsigned short h) {
  union { unsigned u; float f; } v; v.u = ((unsigned)h) << 16;
  return v.f;
}

#define LDE 264            // padded bf16 row stride
#define SCALE 0.17677669529663687f   // 1/sqrt(32)

#define MFMA(A, B, C) __builtin_amdgcn_mfma_f32_16x16x32_bf16((A), (B), (C), 0, 0, 0)

// ---------------------------------------------------------------------------
// K0: blocks 0-63: pack weights into bf16 MFMA B-fragment layout.
//     blocks 64-255: nQ/nK/nV = node @ Wn_w[q] + Wn_b[q]  ([B,H,N,HS]).
// ---------------------------------------------------------------------------
__global__ __launch_bounds__(256)
void prep_and_qkv(const float* __restrict__ We_w, const float* __restrict__ Wee_w,
                  const float* __restrict__ EL1_w, const float* __restrict__ EL2_w,
                  unsigned short* __restrict__ fb,
                  const float* __restrict__ node, const float* __restrict__ Ww,
                  const float* __restrict__ Wb, float* __restrict__ nQ,
                  float* __restrict__ nK, float* __restrict__ nV)
{
  __shared__ float Wl[32 * 256];
  const int t = threadIdx.x;
  if (blockIdx.x < 64) {
    const int blk = blockIdx.x, kt = blk & 7, ms = blk >> 3;
    const float* src; unsigned short* dst; int NT, ntbase;
    if (ms < 3)       { src = We_w  + ms * 65536;       dst = fb;          NT = 48; ntbase = ms * 16; }
    else if (ms < 6)  { src = Wee_w + (ms - 3) * 65536; dst = fb + 196608; NT = 48; ntbase = (ms - 3) * 16; }
    else if (ms == 6) { src = EL1_w;                    dst = fb + 393216; NT = 16; ntbase = 0; }
    else              { src = EL2_w;                    dst = fb + 458752; NT = 16; ntbase = 0; }
    for (int u = t; u < 32 * 64; u += 256) {
      const int r = u >> 6, c4 = (u & 63) << 2;
      *(float4*)(Wl + r * 256 + c4) = *(const float4*)(src + (kt * 32 + r) * 256 + c4);
    }
    __syncthreads();
    for (int u = t; u < 16 * 64; u += 256) {
      const int ntl = u >> 6, l = u & 63;
      const int kb = (l >> 4) << 3, c = ntl * 16 + (l & 15);
      unsigned short tmp[8];
      #pragma unroll
      for (int i = 0; i < 8; ++i) tmp[i] = f2bf(Wl[(kb + i) * 256 + c]);
      const int nt = ntbase + ntl;
      *(uint4*)(dst + ((size_t)(kt * NT + nt) * 64 + l) * 8) = *(const uint4*)tmp;
    }
  } else {
    float (*x)[256] = (float(*)[256])Wl;
    const int r0 = (blockIdx.x - 64) * 4;
    #pragma unroll
    for (int rr = 0; rr < 4; ++rr) x[rr][t] = node[(r0 + rr) * 256 + t];
    __syncthreads();
    float a0[4], a1[4], a2[4];
    #pragma unroll
    for (int rr = 0; rr < 4; ++rr) { a0[rr] = Wb[t]; a1[rr] = Wb[256 + t]; a2[rr] = Wb[512 + t]; }
    for (int k = 0; k < 256; ++k) {
      const float w0 = Ww[k * 256 + t], w1 = Ww[65536 + k * 256 + t], w2 = Ww[131072 + k * 256 + t];
      #pragma unroll
      for (int rr = 0; rr < 4; ++rr) {
        const float xv = x[rr][k];
        a0[rr] += xv * w0; a1[rr] += xv * w1; a2[rr] += xv * w2;
      }
    }
    const int h = t >> 5, c = t & 31;
    #pragma unroll
    for (int rr = 0; rr < 4; ++rr) {
      const int row = r0 + rr, b = row / 96, j = row - b * 96;
      const int oi = ((b * 8 + h) * 96 + j) * 32 + c;
      nQ[oi] = a0[rr]; nK[oi] = a1[rr]; nV[oi] = a2[rr];
    }
  }
}

// ---------------------------------------------------------------------------
// K2: fused node attention for one (b,i). 512 threads. LDS 57856 B.
// ---------------------------------------------------------------------------
__global__ __launch_bounds__(512, 2)
void node_attn(const float* __restrict__ edge, const float* __restrict__ We_b,
               const unsigned short* __restrict__ WeF,
               const float* __restrict__ nQ, const float* __restrict__ nK,
               const float* __restrict__ nV, float* __restrict__ attw)
{
  __shared__ unsigned short Elds[96 * LDE];   // 50688 B
  __shared__ float sc[768];                   // 3072 B
  __shared__ float nQp[256];                  // 1024 B
  __shared__ float bias[768];                 // 3072 B

  const int tid = threadIdx.x, lane = tid & 63, wid = tid >> 6;
  const int b = blockIdx.x & 7, i = blockIdx.x >> 3;
  const size_t bi = (size_t)(b * 96 + i);

  if (tid < 256) nQp[tid] = nQ[((b * 8 + (tid >> 5)) * 96 + i) * 32 + (tid & 31)];
  for (int u = tid; u < 768; u += 512) bias[u] = We_b[u];

  const float* Erow = edge + bi * 24576;
  for (int u = tid; u < 96 * 64; u += 512) {
    const int j = u >> 6, g = u & 63;
    const float4 v = *(const float4*)(Erow + j * 256 + g * 4);
    const unsigned lo = (unsigned)f2bf(v.x) | ((unsigned)f2bf(v.y) << 16);
    const unsigned hi = (unsigned)f2bf(v.z) | ((unsigned)f2bf(v.w) << 16);
    *(uint2*)(Elds + j * LDE + g * 4) = make_uint2(lo, hi);
  }
  __syncthreads();                                   // bar1: E staged

  // ---- Phase A: head h = wid; 2 passes x 3 mt (64 B-loads/wave) ----
  {
    const int h = wid;
    const unsigned short* wq0 = WeF + ((2 * h) * 64 + lane) * 8;
    const unsigned short* wq1 = WeF + ((2 * h + 1) * 64 + lane) * 8;
    const unsigned short* wk0 = WeF + ((16 + 2 * h) * 64 + lane) * 8;
    const unsigned short* wk1 = WeF + ((17 + 2 * h) * 64 + lane) * 8;
    const int c0 = h * 32 + (lane & 15), c1 = c0 + 16;
    const float qb0 = bias[c0] + nQp[c0], qb1 = bias[c1] + nQp[c1];
    const float kb0 = bias[256 + c0], kb1 = bias[256 + c1];
    for (int pass = 0; pass < 2; ++pass) {
      const f32x4 z = {0.f, 0.f, 0.f, 0.f};
      f32x4 aq0[3] = {z, z, z}, aq1[3] = {z, z, z}, ak0[3] = {z, z, z}, ak1[3] = {z, z, z};
      __builtin_amdgcn_s_setprio(1);
      for (int kt = 0; kt < 8; ++kt) {
        const bf16x8 b0 = *(const bf16x8*)(wq0 + kt * 24576);
        const bf16x8 b1 = *(const bf16x8*)(wq1 + kt * 24576);
        const bf16x8 b2 = *(const bf16x8*)(wk0 + kt * 24576);
        const bf16x8 b3 = *(const bf16x8*)(wk1 + kt * 24576);
        #pragma unroll
        for (int m = 0; m < 3; ++m) {
          const int mt = pass * 3 + m;
          const bf16x8 afr = *(const bf16x8*)(Elds + (mt * 16 + (lane & 15)) * LDE
                                              + ((lane >> 4) << 3) + kt * 32);
          aq0[m] = MFMA(afr, b0, aq0[m]);
          aq1[m] = MFMA(afr, b1, aq1[m]);
          ak0[m] = MFMA(afr, b2, ak0[m]);
          ak1[m] = MFMA(afr, b3, ak1[m]);
        }
      }
      __builtin_amdgcn_s_setprio(0);
      #pragma unroll
      for (int m = 0; m < 3; ++m) {
        const int mt = pass * 3 + m;
        float prod[4];
        #pragma unroll
        for (int r = 0; r < 4; ++r) {
          const int j = mt * 16 + ((lane >> 4) << 2) + r;
          const int g = ((b * 8 + h) * 96 + j) * 32;
          const float k0v = ak0[m][r] + kb0 + nK[g + (lane & 15)];
          const float k1v = ak1[m][r] + kb1 + nK[g + 16 + (lane & 15)];
          prod[r] = (aq0[m][r] + qb0) * k0v + (aq1[m][r] + qb1) * k1v;
        }
        #pragma unroll
        for (int mm = 1; mm < 16; mm <<= 1) {
          #pragma unroll
          for (int r = 0; r < 4; ++r) prod[r] += __shfl_xor(prod[r], mm, 64);
        }
        if ((lane & 15) == 0) {
          #pragma unroll
          for (int r = 0; r < 4; ++r)
            sc[h * 96 + mt * 16 + ((lane >> 4) << 2) + r] = prod[r];
        }
      }
    }
  }

  // ---- Phase B MFMA (independent of sc) hoisted before the barrier ----
  const f32x4 z = {0.f, 0.f, 0.f, 0.f};
  f32x4 accB[6][2] = {{z, z}, {z, z}, {z, z}, {z, z}, {z, z}, {z, z}};
  {
    const unsigned short* wb0 = WeF + ((32 + wid) * 64 + lane) * 8;
    const unsigned short* wb1 = WeF + ((40 + wid) * 64 + lane) * 8;
    __builtin_amdgcn_s_setprio(1);
    for (int kt = 0; kt < 8; ++kt) {
      const bf16x8 b0 = *(const bf16x8*)(wb0 + kt * 24576);
      const bf16x8 b1 = *(const bf16x8*)(wb1 + kt * 24576);
      #pragma unroll
      for (int mt = 0; mt < 6; ++mt) {
        const bf16x8 afr = *(const bf16x8*)(Elds + (mt * 16 + (lane & 15)) * LDE
                                            + ((lane >> 4) << 3) + kt * 32);
        accB[mt][0] = MFMA(afr, b0, accB[mt][0]);
        accB[mt][1] = MFMA(afr, b1, accB[mt][1]);
      }
    }
    __builtin_amdgcn_s_setprio(0);
  }
  __syncthreads();                                   // bar2: sc published

  // ---- softmax: wave wid = head ----
  {
    const int h = wid;
    const float s0 = sc[h * 96 + lane] * SCALE;
    const float s1 = (lane < 32) ? sc[h * 96 + 64 + lane] * SCALE : -1e30f;
    float mx = fmaxf(s0, s1);
    #pragma unroll
    for (int m = 1; m < 64; m <<= 1) mx = fmaxf(mx, __shfl_xor(mx, m, 64));
    const float e0 = __expf(s0 - mx);
    const float e1 = (lane < 32) ? __expf(s1 - mx) : 0.f;
    float sm = e0 + e1;
    #pragma unroll
    for (int m = 1; m < 64; m <<= 1) sm += __shfl_xor(sm, m, 64);
    const float inv = 1.f / sm;
    sc[h * 96 + lane] = e0 * inv;
    if (lane < 32) sc[h * 96 + 64 + lane] = e1 * inv;
  }
  __syncthreads();                                   // bar3: attn published

  // ---- Phase B epilogue: attn@V in regs ----
  {
    const int col0 = wid * 16 + (lane & 15), col1 = col0 + 128;
    const int h0 = col0 >> 5, cc0 = col0 & 31;
    const int h1 = col1 >> 5, cc1 = col1 & 31;
    const float base0 = bias[512 + col0], base1 = bias[512 + col1];
    float nn[2] = {0.f, 0.f};
    #pragma unroll
    for (int mt = 0; mt < 6; ++mt) {
      #pragma unroll
      for (int r = 0; r < 4; ++r) {
        const int j = mt * 16 + ((lane >> 4) << 2) + r;
        const float v0 = accB[mt][0][r] + base0 + nV[((b * 8 + h0) * 96 + j) * 32 + cc0];
        const float v1 = accB[mt][1][r] + base1 + nV[((b * 8 + h1) * 96 + j) * 32 + cc1];
        nn[0] += sc[h0 * 96 + j] * v0;
        nn[1] += sc[h1 * 96 + j] * v1;
      }
    }
    #pragma unroll
    for (int s = 0; s < 2; ++s) {
      nn[s] += __shfl_xor(nn[s], 16, 64);
      nn[s] += __shfl_xor(nn[s], 32, 64);
    }
    if (lane < 16) {
      attw[bi * 256 + wid * 16 + lane] = nn[0];
      attw[bi * 256 + (wid + 8) * 16 + lane] = nn[1];
    }
  }
}

// ---------------------------------------------------------------------------
// K3: node tail: FFN + residual + LayerNorm + all 6 projections (row-local).
// 192 blocks x 256 threads, 4 rows each.
// ---------------------------------------------------------------------------
__global__ __launch_bounds__(256)
void node_tail(const float* __restrict__ attw, const float* __restrict__ node,
               const float* __restrict__ W1, const float* __restrict__ B1,
               const float* __restrict__ W2, const float* __restrict__ B2,
               const float* __restrict__ g, const float* __restrict__ be,
               const float* __restrict__ P1w, const float* __restrict__ P1b,
               const float* __restrict__ P2w, const float* __restrict__ P2b,
               float* __restrict__ node_out,
               float* __restrict__ n1Q, float* __restrict__ n1K, float* __restrict__ n1V,
               float* __restrict__ n2Q, float* __restrict__ n2K, float* __restrict__ n2V)
{
  __shared__ float xa[4][256];
  __shared__ float h1[4][256];
  __shared__ float xo[4][256];
  const int t = threadIdx.x, r0 = blockIdx.x * 4;
  #pragma unroll
  for (int rr = 0; rr < 4; ++rr) xa[rr][t] = attw[(r0 + rr) * 256 + t];
  __syncthreads();
  float acc[4];
  #pragma unroll
  for (int rr = 0; rr < 4; ++rr) acc[rr] = B1[t];
  for (int k = 0; k < 256; ++k) {
    const float w = W1[k * 256 + t];
    #pragma unroll
    for (int rr = 0; rr < 4; ++rr) acc[rr] += xa[rr][k] * w;
  }
  #pragma unroll
  for (int rr = 0; rr < 4; ++rr) h1[rr][t] = fmaxf(acc[rr], 0.f);
  __syncthreads();
  #pragma unroll
  for (int rr = 0; rr < 4; ++rr) acc[rr] = B2[t];
  for (int k = 0; k < 256; ++k) {
    const float w = W2[k * 256 + t];
    #pragma unroll
    for (int rr = 0; rr < 4; ++rr) acc[rr] += h1[rr][k] * w;
  }
  #pragma unroll
  for (int rr = 0; rr < 4; ++rr) xo[rr][t] = node[(r0 + rr) * 256 + t] + acc[rr];
  __syncthreads();
  // LayerNorm: wave wid handles row wid
  {
    const int wid = t >> 6, lane = t & 63;
    const float4 gv = *(const float4*)(g + (lane << 2));
    const float4 bv = *(const float4*)(be + (lane << 2));
    const float4 xv = *(const float4*)(&xo[wid][lane << 2]);
    float s = xv.x + xv.y + xv.z + xv.w;
    float sq = xv.x * xv.x + xv.y * xv.y + xv.z * xv.z + xv.w * xv.w;
    #pragma unroll
    for (int m = 1; m < 64; m <<= 1) { s += __shfl_xor(s, m, 64); sq += __shfl_xor(sq, m, 64); }
    const float mean = s * (1.f / 256.f);
    const float rs = rsqrtf(sq * (1.f / 256.f) - mean * mean + 1e-5f);
    float4 o;
    o.x = (xv.x - mean) * rs * gv.x + bv.x;
    o.y = (xv.y - mean) * rs * gv.y + bv.y;
    o.z = (xv.z - mean) * rs * gv.z + bv.z;
    o.w = (xv.w - mean) * rs * gv.w + bv.w;
    *(float4*)(&xo[wid][lane << 2]) = o;
    *(float4*)(node_out + (r0 + wid) * 256 + (lane << 2)) = o;
  }
  __syncthreads();
  // 6 projections of node_out (row-local)
  float a[6][4];
  #pragma unroll
  for (int rr = 0; rr < 4; ++rr) {
    a[0][rr] = P1b[t]; a[1][rr] = P1b[256 + t]; a[2][rr] = P1b[512 + t];
    a[3][rr] = P2b[t]; a[4][rr] = P2b[256 + t]; a[5][rr] = P2b[512 + t];
  }
  for (int k = 0; k < 256; ++k) {
    const float w0 = P1w[k * 256 + t], w1 = P1w[65536 + k * 256 + t], w2 = P1w[131072 + k * 256 + t];
    const float w3 = P2w[k * 256 + t], w4 = P2w[65536 + k * 256 + t], w5 = P2w[131072 + k * 256 + t];
    #pragma unroll
    for (int rr = 0; rr < 4; ++rr) {
      const float xv = xo[rr][k];
      a[0][rr] += xv * w0; a[1][rr] += xv * w1; a[2][rr] += xv * w2;
      a[3][rr] += xv * w3; a[4][rr] += xv * w4; a[5][rr] += xv * w5;
    }
  }
  const int h = t >> 5, c = t & 31;
  #pragma unroll
  for (int rr = 0; rr < 4; ++rr) {
    const int row = r0 + rr, b = row / 96, j = row - b * 96;
    const int oi = ((b * 8 + h) * 96 + j) * 32 + c;
    n1Q[oi] = a[0][rr]; n1K[oi] = a[1][rr]; n1V[oi] = a[2][rr];
    n2Q[oi] = a[3][rr]; n2K[oi] = a[4][rr]; n2V[oi] = a[5][rr];
  }
}

// ---------------------------------------------------------------------------
// K5: fused edge update for one (b,i). 512 threads. LDS 60928 B.
// ---------------------------------------------------------------------------
__global__ __launch_bounds__(512, 2)
void edge_update(const float* __restrict__ edge, const float* __restrict__ Wee_b,
                 const unsigned short* __restrict__ WeeF,
                 const unsigned short* __restrict__ EL1F,
                 const unsigned short* __restrict__ EL2F,
                 const float* __restrict__ EL1_b, const float* __restrict__ EL2_b,
                 const float* __restrict__ n1Q, const float* __restrict__ n1K, const float* __restrict__ n1V,
                 const float* __restrict__ n2Q, const float* __restrict__ n2K, const float* __restrict__ n2V,
                 const float* __restrict__ lng, const float* __restrict__ lnb,
                 float* __restrict__ edge_out)
{
  __shared__ unsigned short Elds[96 * LDE];   // 50688 B (E -> attw_e -> hidden -> LN out)
  __shared__ float se[768];                   // silu(scores); later psum[8][96]
  __shared__ float bn1[768];                  // Wee_b + n1p;  later psq[8][96]
  __shared__ float b12[512];                  // EL1|EL2 bias; [0..191] later stats
  __shared__ float lg[256], lb[256];          // 2048 B

  const int tid = threadIdx.x, lane = tid & 63, wid = tid >> 6;
  const int b = blockIdx.x & 7, i = blockIdx.x >> 3;
  const size_t bi = (size_t)(b * 96 + i);

  for (int u = tid; u < 768; u += 512) {
    const int q = u >> 8, cn = u & 255, h = cn >> 5, c = cn & 31;
    const float* s = (q == 0) ? n1Q : (q == 1) ? n1K : n1V;
    bn1[u] = Wee_b[u] + s[((b * 8 + h) * 96 + i) * 32 + c];
  }
  b12[tid] = (tid < 256) ? EL1_b[tid] : EL2_b[tid - 256];
  if (tid < 256) { lg[tid] = lng[tid]; lb[tid] = lnb[tid]; }

  const float* Erow = edge + bi * 24576;
  for (int u = tid; u < 96 * 64; u += 512) {
    const int j = u >> 6, g = u & 63;
    const float4 v = *(const float4*)(Erow + j * 256 + g * 4);
    const unsigned lo = (unsigned)f2bf(v.x) | ((unsigned)f2bf(v.y) << 16);
    const unsigned hi = (unsigned)f2bf(v.z) | ((unsigned)f2bf(v.w) << 16);
    *(uint2*)(Elds + j * LDE + g * 4) = make_uint2(lo, hi);
  }
  __syncthreads();                                   // bar1: E staged

  // ---- Phase A: head h = wid; 2 passes x 3 mt; silu at write ----
  {
    const int h = wid;
    const unsigned short* wq0 = WeeF + ((2 * h) * 64 + lane) * 8;
    const unsigned short* wq1 = WeeF + ((2 * h + 1) * 64 + lane) * 8;
    const unsigned short* wk0 = WeeF + ((16 + 2 * h) * 64 + lane) * 8;
    const unsigned short* wk1 = WeeF + ((17 + 2 * h) * 64 + lane) * 8;
    const int c0 = h * 32 + (lane & 15), c1 = c0 + 16;
    const float qb0 = bn1[c0], qb1 = bn1[c1];
    const float kb0 = bn1[256 + c0], kb1 = bn1[256 + c1];
    for (int pass = 0; pass < 2; ++pass) {
      const f32x4 z = {0.f, 0.f, 0.f, 0.f};
      f32x4 aq0[3] = {z, z, z}, aq1[3] = {z, z, z}, ak0[3] = {z, z, z}, ak1[3] = {z, z, z};
      __builtin_amdgcn_s_setprio(1);
      for (int kt = 0; kt < 8; ++kt) {
        const bf16x8 b0 = *(const bf16x8*)(wq0 + kt * 24576);
        const bf16x8 b1 = *(const bf16x8*)(wq1 + kt * 24576);
        const bf16x8 b2 = *(const bf16x8*)(wk0 + kt * 24576);
        const bf16x8 b3 = *(const bf16x8*)(wk1 + kt * 24576);
        #pragma unroll
        for (int m = 0; m < 3; ++m) {
          const int mt = pass * 3 + m;
          const bf16x8 afr = *(const bf16x8*)(Elds + (mt * 16 + (lane & 15)) * LDE
                                              + ((lane >> 4) << 3) + kt * 32);
          aq0[m] = MFMA(afr, b0, aq0[m]);
          aq1[m] = MFMA(afr, b1, aq1[m]);
          ak0[m] = MFMA(afr, b2, ak0[m]);
          ak1[m] = MFMA(afr, b3, ak1[m]);
        }
      }
      __builtin_amdgcn_s_setprio(0);
      #pragma unroll
      for (int m = 0; m < 3; ++m) {
        const int mt = pass * 3 + m;
        float prod[4];
        #pragma unroll
        for (int r = 0; r < 4; ++r) {
          const int j = mt * 16 + ((lane >> 4) << 2) + r;
          const int g = ((b * 8 + h) * 96 + j) * 32;
          const float q0v = aq0[m][r] + qb0 + n2Q[g + (lane & 15)];
          const float q1v = aq1[m][r] + qb1 + n2Q[g + 16 + (lane & 15)];
          const float k0v = ak0[m][r] + kb0 + n2K[g + (lane & 15)];
          const float k1v = ak1[m][r] + kb1 + n2K[g + 16 + (lane & 15)];
          prod[r] = q0v * k0v + q1v * k1v;
        }
        #pragma unroll
        for (int mm = 1; mm < 16; mm <<= 1) {
          #pragma unroll
          for (int r = 0; r < 4; ++r) prod[r] += __shfl_xor(prod[r], mm, 64);
        }
        if ((lane & 15) == 0) {
          #pragma unroll
          for (int r = 0; r < 4; ++r) {
            const float d = prod[r] * SCALE;
            se[h * 96 + mt * 16 + ((lane >> 4) << 2) + r] = d / (1.f + __expf(-d));
          }
        }
      }
    }
  }

  // ---- Phase B MFMA (reads E only) hoisted before the se barrier ----
  const f32x4 z = {0.f, 0.f, 0.f, 0.f};
  f32x4 acc[6][2] = {{z, z}, {z, z}, {z, z}, {z, z}, {z, z}, {z, z}};
  {
    const unsigned short* wb0 = WeeF + ((32 + wid) * 64 + lane) * 8;
    const unsigned short* wb1 = WeeF + ((40 + wid) * 64 + lane) * 8;
    __builtin_amdgcn_s_setprio(1);
    for (int kt = 0; kt < 8; ++kt) {
      const bf16x8 b0 = *(const bf16x8*)(wb0 + kt * 24576);
      const bf16x8 b1 = *(const bf16x8*)(wb1 + kt * 24576);
      #pragma unroll
      for (int mt = 0; mt < 6; ++mt) {
        const bf16x8 afr = *(const bf16x8*)(Elds + (mt * 16 + (lane & 15)) * LDE
                                            + ((lane >> 4) << 3) + kt * 32);
        acc[mt][0] = MFMA(afr, b0, acc[mt][0]);
        acc[mt][1] = MFMA(afr, b1, acc[mt][1]);
      }
    }
    __builtin_amdgcn_s_setprio(0);
  }
  __syncthreads();                                   // bar2: se done + E reads done

  // ---- Phase B epilogue: attw_e = silu * (Ve+...), write in place ----
  {
    const int col0 = wid * 16 + (lane & 15), col1 = col0 + 128;
    const int h0 = col0 >> 5, cc0 = col0 & 31;
    const int h1 = col1 >> 5, cc1 = col1 & 31;
    const float base0 = bn1[512 + col0], base1 = bn1[512 + col1];
    #pragma unroll
    for (int mt = 0; mt < 6; ++mt) {
      #pragma unroll
      for (int r = 0; r < 4; ++r) {
        const int j = mt * 16 + ((lane >> 4) << 2) + r;
        const float v0 = acc[mt][0][r] + base0 + n2V[((b * 8 + h0) * 96 + j) * 32 + cc0];
        const float v1 = acc[mt][1][r] + base1 + n2V[((b * 8 + h1) * 96 + j) * 32 + cc1];
        Elds[j * LDE + col0] = f2bf(se[h0 * 96 + j] * v0);
        Elds[j * LDE + col1] = f2bf(se[h1 * 96 + j] * v1);
      }
    }
  }
  __syncthreads();                                   // bar3: attw_e published

  // ---- EL1 + relu (kt-outer), in place ----
  {
    #pragma unroll
    for (int mt = 0; mt < 6; ++mt) { acc[mt][0] = z; acc[mt][1] = z; }
    const unsigned short* wb0 = EL1F + (wid * 64 + lane) * 8;
    const unsigned short* wb1 = EL1F + ((wid + 8) * 64 + lane) * 8;
    __builtin_amdgcn_s_setprio(1);
    for (int kt = 0; kt < 8; ++kt) {
      const bf16x8 b0 = *(const bf16x8*)(wb0 + kt * 8192);
      const bf16x8 b1 = *(const bf16x8*)(wb1 + kt * 8192);
      #pragma unroll
      for (int mt = 0; mt < 6; ++mt) {
        const bf16x8 afr = *(const bf16x8*)(Elds + (mt * 16 + (lane & 15)) * LDE
                                            + ((lane >> 4) << 3) + kt * 32);
        acc[mt][0] = MFMA(afr, b0, acc[mt][0]);
        acc[mt][1] = MFMA(afr, b1, acc[mt][1]);
      }
    }
    __builtin_amdgcn_s_setprio(0);
    __syncthreads();                                 // bar4: attw_e reads done
    const int col0 = wid * 16 + (lane & 15), col1 = col0 + 128;
    const float bv0 = b12[col0], bv1 = b12[col1];
    #pragma unroll
    for (int mt = 0; mt < 6; ++mt) {
      #pragma unroll
      for (int r = 0; r < 4; ++r) {
        const int j = mt * 16 + ((lane >> 4) << 2) + r;
        Elds[j * LDE + col0] = f2bf(fmaxf(acc[mt][0][r] + bv0, 0.f));
        Elds[j * LDE + col1] = f2bf(fmaxf(acc[mt][1][r] + bv1, 0.f));
      }
    }
  }
  __syncthreads();                                   // bar5: hidden published

  // ---- EL2 (kt-outer) + residual + batched LayerNorm ----
  {
    #pragma unroll
    for (int mt = 0; mt < 6; ++mt) { acc[mt][0] = z; acc[mt][1] = z; }
    const unsigned short* wb0 = EL2F + (wid * 64 + lane) * 8;
    const unsigned short* wb1 = EL2F + ((wid + 8) * 64 + lane) * 8;
    __builtin_amdgcn_s_setprio(1);
    for (int kt = 0; kt < 8; ++kt) {
      const bf16x8 b0 = *(const bf16x8*)(wb0 + kt * 8192);
      const bf16x8 b1 = *(const bf16x8*)(wb1 + kt * 8192);
      #pragma unroll
      for (int mt = 0; mt < 6; ++mt) {
        const bf16x8 afr = *(const bf16x8*)(Elds + (mt * 16 + (lane & 15)) * LDE
                                            + ((lane >> 4) << 3) + kt * 32);
        acc[mt][0] = MFMA(afr, b0, acc[mt][0]);
        acc[mt][1] = MFMA(afr, b1, acc[mt][1]);
      }
    }
    __builtin_amdgcn_s_setprio(0);
    const int col0 = wid * 16 + (lane & 15), col1 = col0 + 128;
    const float bv0 = b12[256 + col0], bv1 = b12[256 + col1];
    const float g0 = lg[col0], g1 = lg[col1], be0 = lb[col0], be1 = lb[col1];
    __syncthreads();                                 // bar6: hidden reads done (se/bn1 free)
    #pragma unroll
    for (int mt = 0; mt < 6; ++mt) {
      #pragma unroll
      for (int r = 0; r < 4; ++r) {
        const int j = mt * 16 + ((lane >> 4) << 2) + r;
        acc[mt][0][r] += bv0 + Erow[j * 256 + col0];
        acc[mt][1][r] += bv1 + Erow[j * 256 + col1];
      }
    }
    #pragma unroll
    for (int mt = 0; mt < 6; ++mt) {
      #pragma unroll
      for (int r = 0; r < 4; ++r) {
        float s = acc[mt][0][r] + acc[mt][1][r];
        float q = acc[mt][0][r] * acc[mt][0][r] + acc[mt][1][r] * acc[mt][1][r];
        #pragma unroll
        for (int m = 1; m < 16; m <<= 1) { s += __shfl_xor(s, m, 64); q += __shfl_xor(q, m, 64); }
        if ((lane & 15) == 0) {
          const int j = mt * 16 + ((lane >> 4) << 2) + r;
          se[wid * 96 + j] = s; bn1[wid * 96 + j] = q;
        }
      }
    }
    __syncthreads();                                 // bar7: partials published
    if (tid < 96) {
      float s = 0.f, q = 0.f;
      #pragma unroll
      for (int w = 0; w < 8; ++w) { s += se[w * 96 + tid]; q += bn1[w * 96 + tid]; }
      const float mean = s * (1.f / 256.f);
      b12[tid] = mean;
      b12[96 + tid] = rsqrtf(q * (1.f / 256.f) - mean * mean + 1e-5f);
    }
    __syncthreads();                                 // bar8: stats published
    #pragma unroll
    for (int mt = 0; mt < 6; ++mt) {
      #pragma unroll
      for (int r = 0; r < 4; ++r) {
        const int j = mt * 16 + ((lane >> 4) << 2) + r;
        const float mean = b12[j], rs = b12[96 + j];
        Elds[j * LDE + col0] = f2bf((acc[mt][0][r] - mean) * rs * g0 + be0);
        Elds[j * LDE + col1] = f2bf((acc[mt][1][r] - mean) * rs * g1 + be1);
      }
    }
  }
  __syncthreads();                                   // bar9: LN out staged

  // ---- coalesced fp32 writeback: full 1KB rows ----
  float* orow = edge_out + bi * 24576;
  for (int j = wid; j < 96; j += 8) {
    const uint2 pk = *(const uint2*)(Elds + j * LDE + (lane << 2));
    float4 o;
    o.x = bf2f((unsigned short)(pk.x & 0xffff));
    o.y = bf2f((unsigned short)(pk.x >> 16));
    o.z = bf2f((unsigned short)(pk.y & 0xffff));
    o.w = bf2f((unsigned short)(pk.y >> 16));
    *(float4*)(orow + j * 256 + (lane << 2)) = o;
  }
}

// ---------------------------------------------------------------------------
extern "C" void kernel_launch(void* const* d_in, const int* in_sizes, int n_in,
                              void* d_out, int out_size, void* d_ws, size_t ws_size,
                              hipStream_t stream)
{
  (void)in_sizes; (void)n_in; (void)out_size; (void)ws_size;

  const float* node   = (const float*)d_in[0];
  const float* edge   = (const float*)d_in[1];
  const float* Wn_w   = (const float*)d_in[2];
  const float* Wn_b   = (const float*)d_in[3];
  const float* We_w   = (const float*)d_in[4];
  const float* We_b   = (const float*)d_in[5];
  const float* Wn1_w  = (const float*)d_in[6];
  const float* Wn1_b  = (const float*)d_in[7];
  const float* Wn2_w  = (const float*)d_in[8];
  const float* Wn2_b  = (const float*)d_in[9];
  const float* Wee_w  = (const float*)d_in[10];
  const float* Wee_b  = (const float*)d_in[11];
  const float* NL1_w  = (const float*)d_in[12];
  const float* NL1_b  = (const float*)d_in[13];
  const float* NL2_w  = (const float*)d_in[14];
  const float* NL2_b  = (const float*)d_in[15];
  const float* EL1_w  = (const float*)d_in[16];
  const float* EL1_b  = (const float*)d_in[17];
  const float* EL2_w  = (const float*)d_in[18];
  const float* EL2_b  = (const float*)d_in[19];
  const float* NLN1_g = (const float*)d_in[20];
  const float* NLN1_b = (const float*)d_in[21];
  const float* ELN1_g = (const float*)d_in[22];
  const float* ELN1_b = (const float*)d_in[23];

  float* out = (float*)d_out;
  float* node_out = out;               // [8,96,256]
  float* edge_out = out + 196608;      // [8,96,96,256]

  float* wsf = (float*)d_ws;
  float* nQ  = wsf;                float* nK  = wsf + 196608;   float* nV  = wsf + 393216;
  float* n1Q = wsf + 589824;       float* n1K = wsf + 786432;   float* n1V = wsf + 983040;
  float* n2Q = wsf + 1179648;      float* n2K = wsf + 1376256;  float* n2V = wsf + 1572864;
  float* attw = wsf + 1769472;
  unsigned short* fb   = (unsigned short*)(wsf + 1966080);
  unsigned short* WeF  = fb;                 // 196608
  unsigned short* WeeF = fb + 196608;        // 196608
  unsigned short* EL1F = fb + 393216;        // 65536
  unsigned short* EL2F = fb + 458752;        // 65536

  prep_and_qkv<<<256, 256, 0, stream>>>(We_w, Wee_w, EL1_w, EL2_w, fb,
                                        node, Wn_w, Wn_b, nQ, nK, nV);
  node_attn<<<768, 512, 0, stream>>>(edge, We_b, WeF, nQ, nK, nV, attw);
  node_tail<<<192, 256, 0, stream>>>(attw, node, NL1_w, NL1_b, NL2_w, NL2_b,
                                     NLN1_g, NLN1_b, Wn1_w, Wn1_b, Wn2_w, Wn2_b,
                                     node_out, n1Q, n1K, n1V, n2Q, n2K, n2V);
  edge_update<<<768, 512, 0, stream>>>(edge, Wee_b, WeeF, EL1F, EL2F,
                                       EL1_b, EL2_b, n1Q, n1K, n1V,
                                       n2Q, n2K, n2V, ELN1_g, ELN1_b, edge_out);
}

// Round 9
// 261.383 us; speedup vs baseline: 2.6627x; 1.0392x over previous
//
#include <hip/hip_runtime.h>

// B=8 N=96 H=8 HS=32 NS=256.  bf16 MFMA 16x16x32 everywhere.
// v9: node_tail MFMA-ized (was 122us of latency-exposed scalar matmul at
// 1 wave/SIMD). prep packs NL1/NL2/Wn1/Wn2 frags too. Edge path unchanged.

#define DI __device__ __forceinline__

typedef float f32x4 __attribute__((ext_vector_type(4)));
typedef short bf16x8 __attribute__((ext_vector_type(8)));

DI unsigned short f2bf(float f) {
  union { float f; unsigned u; } v; v.f = f;
  return (unsigned short)((v.u + 0x7FFFu + ((v.u >> 16) & 1u)) >> 16);
}
DI float bf2f(unsigned short h) {
  union { unsigned u; float f; } v; v.u = ((unsigned)h) << 16;
  return v.f;
}

#define LDE 264            // padded bf16 row stride
#define SCALE 0.17677669529663687f   // 1/sqrt(32)

#define MFMA(A, B, C) __builtin_amdgcn_mfma_f32_16x16x32_bf16((A), (B), (C), 0, 0, 0)

// ---------------------------------------------------------------------------
// K0: blocks 0-127: pack 16 weight mats into bf16 MFMA B-fragment layout.
//     blocks 128-319: nQ/nK/nV = node @ Wn_w[q] + Wn_b[q]  ([B,H,N,HS]).
// ---------------------------------------------------------------------------
__global__ __launch_bounds__(256)
void prep_and_qkv(const float* __restrict__ We_w, const float* __restrict__ Wee_w,
                  const float* __restrict__ EL1_w, const float* __restrict__ EL2_w,
                  const float* __restrict__ NL1_w, const float* __restrict__ NL2_w,
                  const float* __restrict__ Wn1_w, const float* __restrict__ Wn2_w,
                  unsigned short* __restrict__ fb,
                  const float* __restrict__ node, const float* __restrict__ Ww,
                  const float* __restrict__ Wb, float* __restrict__ nQ,
                  float* __restrict__ nK, float* __restrict__ nV)
{
  __shared__ float Wl[32 * 256];
  const int t = threadIdx.x;
  if (blockIdx.x < 128) {
    const int blk = blockIdx.x, kt = blk & 7, ms = blk >> 3;
    const float* src; unsigned short* dst; int NT, ntbase;
    if (ms < 3)       { src = We_w  + ms * 65536;        dst = fb;          NT = 48; ntbase = ms * 16; }
    else if (ms < 6)  { src = Wee_w + (ms - 3) * 65536;  dst = fb + 196608; NT = 48; ntbase = (ms - 3) * 16; }
    else if (ms == 6) { src = EL1_w;                     dst = fb + 393216; NT = 16; ntbase = 0; }
    else if (ms == 7) { src = EL2_w;                     dst = fb + 458752; NT = 16; ntbase = 0; }
    else if (ms == 8) { src = NL1_w;                     dst = fb + 524288; NT = 16; ntbase = 0; }
    else if (ms == 9) { src = NL2_w;                     dst = fb + 589824; NT = 16; ntbase = 0; }
    else if (ms < 13) { src = Wn1_w + (ms - 10) * 65536; dst = fb + 655360; NT = 48; ntbase = (ms - 10) * 16; }
    else              { src = Wn2_w + (ms - 13) * 65536; dst = fb + 851968; NT = 48; ntbase = (ms - 13) * 16; }
    for (int u = t; u < 32 * 64; u += 256) {
      const int r = u >> 6, c4 = (u & 63) << 2;
      *(float4*)(Wl + r * 256 + c4) = *(const float4*)(src + (kt * 32 + r) * 256 + c4);
    }
    __syncthreads();
    for (int u = t; u < 16 * 64; u += 256) {
      const int ntl = u >> 6, l = u & 63;
      const int kb = (l >> 4) << 3, c = ntl * 16 + (l & 15);
      unsigned short tmp[8];
      #pragma unroll
      for (int i = 0; i < 8; ++i) tmp[i] = f2bf(Wl[(kb + i) * 256 + c]);
      const int nt = ntbase + ntl;
      *(uint4*)(dst + ((size_t)(kt * NT + nt) * 64 + l) * 8) = *(const uint4*)tmp;
    }
  } else {
    float (*x)[256] = (float(*)[256])Wl;
    const int r0 = (blockIdx.x - 128) * 4;
    #pragma unroll
    for (int rr = 0; rr < 4; ++rr) x[rr][t] = node[(r0 + rr) * 256 + t];
    __syncthreads();
    float a0[4], a1[4], a2[4];
    #pragma unroll
    for (int rr = 0; rr < 4; ++rr) { a0[rr] = Wb[t]; a1[rr] = Wb[256 + t]; a2[rr] = Wb[512 + t]; }
    for (int k = 0; k < 256; ++k) {
      const float w0 = Ww[k * 256 + t], w1 = Ww[65536 + k * 256 + t], w2 = Ww[131072 + k * 256 + t];
      #pragma unroll
      for (int rr = 0; rr < 4; ++rr) {
        const float xv = x[rr][k];
        a0[rr] += xv * w0; a1[rr] += xv * w1; a2[rr] += xv * w2;
      }
    }
    const int h = t >> 5, c = t & 31;
    #pragma unroll
    for (int rr = 0; rr < 4; ++rr) {
      const int row = r0 + rr, b = row / 96, j = row - b * 96;
      const int oi = ((b * 8 + h) * 96 + j) * 32 + c;
      nQ[oi] = a0[rr]; nK[oi] = a1[rr]; nV[oi] = a2[rr];
    }
  }
}

// ---------------------------------------------------------------------------
// K2: fused node attention for one (b,i). 512 threads. LDS 57856 B.
// ---------------------------------------------------------------------------
__global__ __launch_bounds__(512, 2)
void node_attn(const float* __restrict__ edge, const float* __restrict__ We_b,
               const unsigned short* __restrict__ WeF,
               const float* __restrict__ nQ, const float* __restrict__ nK,
               const float* __restrict__ nV, float* __restrict__ attw)
{
  __shared__ unsigned short Elds[96 * LDE];   // 50688 B
  __shared__ float sc[768];                   // 3072 B
  __shared__ float nQp[256];                  // 1024 B
  __shared__ float bias[768];                 // 3072 B

  const int tid = threadIdx.x, lane = tid & 63, wid = tid >> 6;
  const int b = blockIdx.x & 7, i = blockIdx.x >> 3;
  const size_t bi = (size_t)(b * 96 + i);

  if (tid < 256) nQp[tid] = nQ[((b * 8 + (tid >> 5)) * 96 + i) * 32 + (tid & 31)];
  for (int u = tid; u < 768; u += 512) bias[u] = We_b[u];

  const float* Erow = edge + bi * 24576;
  for (int u = tid; u < 96 * 64; u += 512) {
    const int j = u >> 6, g = u & 63;
    const float4 v = *(const float4*)(Erow + j * 256 + g * 4);
    const unsigned lo = (unsigned)f2bf(v.x) | ((unsigned)f2bf(v.y) << 16);
    const unsigned hi = (unsigned)f2bf(v.z) | ((unsigned)f2bf(v.w) << 16);
    *(uint2*)(Elds + j * LDE + g * 4) = make_uint2(lo, hi);
  }
  __syncthreads();                                   // bar1: E staged

  // ---- Phase A: head h = wid; 2 passes x 3 mt (64 B-loads/wave) ----
  {
    const int h = wid;
    const unsigned short* wq0 = WeF + ((2 * h) * 64 + lane) * 8;
    const unsigned short* wq1 = WeF + ((2 * h + 1) * 64 + lane) * 8;
    const unsigned short* wk0 = WeF + ((16 + 2 * h) * 64 + lane) * 8;
    const unsigned short* wk1 = WeF + ((17 + 2 * h) * 64 + lane) * 8;
    const int c0 = h * 32 + (lane & 15), c1 = c0 + 16;
    const float qb0 = bias[c0] + nQp[c0], qb1 = bias[c1] + nQp[c1];
    const float kb0 = bias[256 + c0], kb1 = bias[256 + c1];
    for (int pass = 0; pass < 2; ++pass) {
      const f32x4 z = {0.f, 0.f, 0.f, 0.f};
      f32x4 aq0[3] = {z, z, z}, aq1[3] = {z, z, z}, ak0[3] = {z, z, z}, ak1[3] = {z, z, z};
      __builtin_amdgcn_s_setprio(1);
      for (int kt = 0; kt < 8; ++kt) {
        const bf16x8 b0 = *(const bf16x8*)(wq0 + kt * 24576);
        const bf16x8 b1 = *(const bf16x8*)(wq1 + kt * 24576);
        const bf16x8 b2 = *(const bf16x8*)(wk0 + kt * 24576);
        const bf16x8 b3 = *(const bf16x8*)(wk1 + kt * 24576);
        #pragma unroll
        for (int m = 0; m < 3; ++m) {
          const int mt = pass * 3 + m;
          const bf16x8 afr = *(const bf16x8*)(Elds + (mt * 16 + (lane & 15)) * LDE
                                              + ((lane >> 4) << 3) + kt * 32);
          aq0[m] = MFMA(afr, b0, aq0[m]);
          aq1[m] = MFMA(afr, b1, aq1[m]);
          ak0[m] = MFMA(afr, b2, ak0[m]);
          ak1[m] = MFMA(afr, b3, ak1[m]);
        }
      }
      __builtin_amdgcn_s_setprio(0);
      #pragma unroll
      for (int m = 0; m < 3; ++m) {
        const int mt = pass * 3 + m;
        float prod[4];
        #pragma unroll
        for (int r = 0; r < 4; ++r) {
          const int j = mt * 16 + ((lane >> 4) << 2) + r;
          const int g = ((b * 8 + h) * 96 + j) * 32;
          const float k0v = ak0[m][r] + kb0 + nK[g + (lane & 15)];
          const float k1v = ak1[m][r] + kb1 + nK[g + 16 + (lane & 15)];
          prod[r] = (aq0[m][r] + qb0) * k0v + (aq1[m][r] + qb1) * k1v;
        }
        #pragma unroll
        for (int mm = 1; mm < 16; mm <<= 1) {
          #pragma unroll
          for (int r = 0; r < 4; ++r) prod[r] += __shfl_xor(prod[r], mm, 64);
        }
        if ((lane & 15) == 0) {
          #pragma unroll
          for (int r = 0; r < 4; ++r)
            sc[h * 96 + mt * 16 + ((lane >> 4) << 2) + r] = prod[r];
        }
      }
    }
  }

  // ---- Phase B MFMA (independent of sc) hoisted before the barrier ----
  const f32x4 z = {0.f, 0.f, 0.f, 0.f};
  f32x4 accB[6][2] = {{z, z}, {z, z}, {z, z}, {z, z}, {z, z}, {z, z}};
  {
    const unsigned short* wb0 = WeF + ((32 + wid) * 64 + lane) * 8;
    const unsigned short* wb1 = WeF + ((40 + wid) * 64 + lane) * 8;
    __builtin_amdgcn_s_setprio(1);
    for (int kt = 0; kt < 8; ++kt) {
      const bf16x8 b0 = *(const bf16x8*)(wb0 + kt * 24576);
      const bf16x8 b1 = *(const bf16x8*)(wb1 + kt * 24576);
      #pragma unroll
      for (int mt = 0; mt < 6; ++mt) {
        const bf16x8 afr = *(const bf16x8*)(Elds + (mt * 16 + (lane & 15)) * LDE
                                            + ((lane >> 4) << 3) + kt * 32);
        accB[mt][0] = MFMA(afr, b0, accB[mt][0]);
        accB[mt][1] = MFMA(afr, b1, accB[mt][1]);
      }
    }
    __builtin_amdgcn_s_setprio(0);
  }
  __syncthreads();                                   // bar2: sc published

  // ---- softmax: wave wid = head ----
  {
    const int h = wid;
    const float s0 = sc[h * 96 + lane] * SCALE;
    const float s1 = (lane < 32) ? sc[h * 96 + 64 + lane] * SCALE : -1e30f;
    float mx = fmaxf(s0, s1);
    #pragma unroll
    for (int m = 1; m < 64; m <<= 1) mx = fmaxf(mx, __shfl_xor(mx, m, 64));
    const float e0 = __expf(s0 - mx);
    const float e1 = (lane < 32) ? __expf(s1 - mx) : 0.f;
    float sm = e0 + e1;
    #pragma unroll
    for (int m = 1; m < 64; m <<= 1) sm += __shfl_xor(sm, m, 64);
    const float inv = 1.f / sm;
    sc[h * 96 + lane] = e0 * inv;
    if (lane < 32) sc[h * 96 + 64 + lane] = e1 * inv;
  }
  __syncthreads();                                   // bar3: attn published

  // ---- Phase B epilogue: attn@V in regs ----
  {
    const int col0 = wid * 16 + (lane & 15), col1 = col0 + 128;
    const int h0 = col0 >> 5, cc0 = col0 & 31;
    const int h1 = col1 >> 5, cc1 = col1 & 31;
    const float base0 = bias[512 + col0], base1 = bias[512 + col1];
    float nn[2] = {0.f, 0.f};
    #pragma unroll
    for (int mt = 0; mt < 6; ++mt) {
      #pragma unroll
      for (int r = 0; r < 4; ++r) {
        const int j = mt * 16 + ((lane >> 4) << 2) + r;
        const float v0 = accB[mt][0][r] + base0 + nV[((b * 8 + h0) * 96 + j) * 32 + cc0];
        const float v1 = accB[mt][1][r] + base1 + nV[((b * 8 + h1) * 96 + j) * 32 + cc1];
        nn[0] += sc[h0 * 96 + j] * v0;
        nn[1] += sc[h1 * 96 + j] * v1;
      }
    }
    #pragma unroll
    for (int s = 0; s < 2; ++s) {
      nn[s] += __shfl_xor(nn[s], 16, 64);
      nn[s] += __shfl_xor(nn[s], 32, 64);
    }
    if (lane < 16) {
      attw[bi * 256 + wid * 16 + lane] = nn[0];
      attw[bi * 256 + (wid + 8) * 16 + lane] = nn[1];
    }
  }
}

// ---------------------------------------------------------------------------
// K3: node tail, MFMA. 48 blocks x 256 threads, 16 node rows each.
// stage attw -> NL1+relu -> NL2 + residual + LN (node_out) -> 6 projections.
// ---------------------------------------------------------------------------
__global__ __launch_bounds__(256)
void node_tail(const float* __restrict__ attw, const float* __restrict__ node,
               const unsigned short* __restrict__ NL1F, const float* __restrict__ B1,
               const unsigned short* __restrict__ NL2F, const float* __restrict__ B2,
               const float* __restrict__ g, const float* __restrict__ be,
               const unsigned short* __restrict__ Wn1F, const float* __restrict__ P1b,
               const unsigned short* __restrict__ Wn2F, const float* __restrict__ P2b,
               float* __restrict__ node_out,
               float* __restrict__ n1Q, float* __restrict__ n1K, float* __restrict__ n1V,
               float* __restrict__ n2Q, float* __restrict__ n2K, float* __restrict__ n2V)
{
  __shared__ unsigned short Xl[16 * LDE];     // 8448 B (attw -> LN out)
  __shared__ unsigned short Hl[16 * LDE];     // 8448 B (relu hidden)
  __shared__ float bb[1024];                  // B1|B2|g|be
  __shared__ float p1b[768], p2b[768];
  __shared__ float psum[4][16], psq[4][16];
  __shared__ float statm[16], statr[16];

  const int t = threadIdx.x, lane = t & 63, w = t >> 6;
  const int bt = blockIdx.x, r0 = bt * 16;
  const int b = bt / 6, nbase = (bt % 6) * 16;

  bb[t] = B1[t]; bb[256 + t] = B2[t]; bb[512 + t] = g[t]; bb[768 + t] = be[t];
  for (int u = t; u < 768; u += 256) { p1b[u] = P1b[u]; p2b[u] = P2b[u]; }

  for (int u = t; u < 16 * 64; u += 256) {
    const int j = u >> 6, gg = u & 63;
    const float4 v = *(const float4*)(attw + (size_t)(r0 + j) * 256 + gg * 4);
    const unsigned lo = (unsigned)f2bf(v.x) | ((unsigned)f2bf(v.y) << 16);
    const unsigned hi = (unsigned)f2bf(v.z) | ((unsigned)f2bf(v.w) << 16);
    *(uint2*)(Xl + j * LDE + gg * 4) = make_uint2(lo, hi);
  }
  __syncthreads();                                   // bar1: attw staged

  const f32x4 z = {0.f, 0.f, 0.f, 0.f};

  // ---- NL1 + relu -> Hl ----
  {
    f32x4 a1[4] = {z, z, z, z};
    for (int kt = 0; kt < 8; ++kt) {
      const bf16x8 afr = *(const bf16x8*)(Xl + (lane & 15) * LDE + ((lane >> 4) << 3) + kt * 32);
      #pragma unroll
      for (int p = 0; p < 4; ++p) {
        const bf16x8 bf = *(const bf16x8*)(NL1F + (((kt << 4) + (w * 4 + p)) * 64 + lane) * 8);
        a1[p] = MFMA(afr, bf, a1[p]);
      }
    }
    #pragma unroll
    for (int p = 0; p < 4; ++p) {
      const int col = (w * 4 + p) * 16 + (lane & 15);
      const float bv = bb[col];
      #pragma unroll
      for (int r = 0; r < 4; ++r) {
        const int j = ((lane >> 4) << 2) + r;
        Hl[j * LDE + col] = f2bf(fmaxf(a1[p][r] + bv, 0.f));
      }
    }
  }
  __syncthreads();                                   // bar2: Hl published

  // ---- NL2 + residual + LayerNorm -> node_out + Xl(bf16) ----
  float xv[4][4];
  {
    f32x4 a2[4] = {z, z, z, z};
    for (int kt = 0; kt < 8; ++kt) {
      const bf16x8 afr = *(const bf16x8*)(Hl + (lane & 15) * LDE + ((lane >> 4) << 3) + kt * 32);
      #pragma unroll
      for (int p = 0; p < 4; ++p) {
        const bf16x8 bf = *(const bf16x8*)(NL2F + (((kt << 4) + (w * 4 + p)) * 64 + lane) * 8);
        a2[p] = MFMA(afr, bf, a2[p]);
      }
    }
    #pragma unroll
    for (int p = 0; p < 4; ++p) {
      const int col = (w * 4 + p) * 16 + (lane & 15);
      const float bv = bb[256 + col];
      #pragma unroll
      for (int r = 0; r < 4; ++r) {
        const int j = ((lane >> 4) << 2) + r;
        xv[p][r] = a2[p][r] + bv + node[(size_t)(r0 + j) * 256 + col];
      }
    }
    #pragma unroll
    for (int r = 0; r < 4; ++r) {
      float s = 0.f, q = 0.f;
      #pragma unroll
      for (int p = 0; p < 4; ++p) { s += xv[p][r]; q += xv[p][r] * xv[p][r]; }
      #pragma unroll
      for (int m = 1; m < 16; m <<= 1) { s += __shfl_xor(s, m, 64); q += __shfl_xor(q, m, 64); }
      if ((lane & 15) == 0) {
        const int rl = ((lane >> 4) << 2) + r;
        psum[w][rl] = s; psq[w][rl] = q;
      }
    }
  }
  __syncthreads();                                   // bar3: partials
  if (t < 16) {
    const float s = psum[0][t] + psum[1][t] + psum[2][t] + psum[3][t];
    const float q = psq[0][t] + psq[1][t] + psq[2][t] + psq[3][t];
    const float mean = s * (1.f / 256.f);
    statm[t] = mean;
    statr[t] = rsqrtf(q * (1.f / 256.f) - mean * mean + 1e-5f);
  }
  __syncthreads();                                   // bar4: stats
  #pragma unroll
  for (int p = 0; p < 4; ++p) {
    const int col = (w * 4 + p) * 16 + (lane & 15);
    const float gv = bb[512 + col], bv = bb[768 + col];
    #pragma unroll
    for (int r = 0; r < 4; ++r) {
      const int j = ((lane >> 4) << 2) + r;
      const float o = (xv[p][r] - statm[j]) * statr[j] * gv + bv;
      node_out[(size_t)(r0 + j) * 256 + col] = o;
      Xl[j * LDE + col] = f2bf(o);
    }
  }
  __syncthreads();                                   // bar5: LN out in Xl

  // ---- 6 projections: Xl @ {Wn1F, Wn2F} (48 nt each, 12/wave) ----
  bf16x8 xfr[8];
  #pragma unroll
  for (int kt = 0; kt < 8; ++kt)
    xfr[kt] = *(const bf16x8*)(Xl + (lane & 15) * LDE + ((lane >> 4) << 3) + kt * 32);
  #pragma unroll
  for (int ps = 0; ps < 2; ++ps) {
    const unsigned short* WF = ps ? Wn2F : Wn1F;
    const float* pb = ps ? p2b : p1b;
    f32x4 ac[12] = {z, z, z, z, z, z, z, z, z, z, z, z};
    __builtin_amdgcn_s_setprio(1);
    for (int kt = 0; kt < 8; ++kt) {
      #pragma unroll
      for (int m = 0; m < 12; ++m) {
        const int nt = w * 12 + m;
        const bf16x8 bf = *(const bf16x8*)(WF + ((kt * 48 + nt) * 64 + lane) * 8);
        ac[m] = MFMA(xfr[kt], bf, ac[m]);
      }
    }
    __builtin_amdgcn_s_setprio(0);
    #pragma unroll
    for (int m = 0; m < 12; ++m) {
      const int nt = w * 12 + m;
      const int colg = nt * 16 + (lane & 15);
      const int q = colg >> 8, cn = colg & 255, h = cn >> 5, c = cn & 31;
      float* o = (q == 0) ? (ps ? n2Q : n1Q)
               : (q == 1) ? (ps ? n2K : n1K)
                          : (ps ? n2V : n1V);
      const float bv = pb[colg];
      #pragma unroll
      for (int r = 0; r < 4; ++r) {
        const int j = ((lane >> 4) << 2) + r;
        o[((b * 8 + h) * 96 + nbase + j) * 32 + c] = ac[m][r] + bv;
      }
    }
  }
}

// ---------------------------------------------------------------------------
// K5: fused edge update for one (b,i). 512 threads. LDS 60928 B.
// ---------------------------------------------------------------------------
__global__ __launch_bounds__(512, 2)
void edge_update(const float* __restrict__ edge, const float* __restrict__ Wee_b,
                 const unsigned short* __restrict__ WeeF,
                 const unsigned short* __restrict__ EL1F,
                 const unsigned short* __restrict__ EL2F,
                 const float* __restrict__ EL1_b, const float* __restrict__ EL2_b,
                 const float* __restrict__ n1Q, const float* __restrict__ n1K, const float* __restrict__ n1V,
                 const float* __restrict__ n2Q, const float* __restrict__ n2K, const float* __restrict__ n2V,
                 const float* __restrict__ lng, const float* __restrict__ lnb,
                 float* __restrict__ edge_out)
{
  __shared__ unsigned short Elds[96 * LDE];   // 50688 B (E -> attw_e -> hidden -> LN out)
  __shared__ float se[768];                   // silu(scores); later psum[8][96]
  __shared__ float bn1[768];                  // Wee_b + n1p;  later psq[8][96]
  __shared__ float b12[512];                  // EL1|EL2 bias; [0..191] later stats
  __shared__ float lg[256], lb[256];          // 2048 B

  const int tid = threadIdx.x, lane = tid & 63, wid = tid >> 6;
  const int b = blockIdx.x & 7, i = blockIdx.x >> 3;
  const size_t bi = (size_t)(b * 96 + i);

  for (int u = tid; u < 768; u += 512) {
    const int q = u >> 8, cn = u & 255, h = cn >> 5, c = cn & 31;
    const float* s = (q == 0) ? n1Q : (q == 1) ? n1K : n1V;
    bn1[u] = Wee_b[u] + s[((b * 8 + h) * 96 + i) * 32 + c];
  }
  b12[tid] = (tid < 256) ? EL1_b[tid] : EL2_b[tid - 256];
  if (tid < 256) { lg[tid] = lng[tid]; lb[tid] = lnb[tid]; }

  const float* Erow = edge + bi * 24576;
  for (int u = tid; u < 96 * 64; u += 512) {
    const int j = u >> 6, g = u & 63;
    const float4 v = *(const float4*)(Erow + j * 256 + g * 4);
    const unsigned lo = (unsigned)f2bf(v.x) | ((unsigned)f2bf(v.y) << 16);
    const unsigned hi = (unsigned)f2bf(v.z) | ((unsigned)f2bf(v.w) << 16);
    *(uint2*)(Elds + j * LDE + g * 4) = make_uint2(lo, hi);
  }
  __syncthreads();                                   // bar1: E staged

  // ---- Phase A: head h = wid; 2 passes x 3 mt; silu at write ----
  {
    const int h = wid;
    const unsigned short* wq0 = WeeF + ((2 * h) * 64 + lane) * 8;
    const unsigned short* wq1 = WeeF + ((2 * h + 1) * 64 + lane) * 8;
    const unsigned short* wk0 = WeeF + ((16 + 2 * h) * 64 + lane) * 8;
    const unsigned short* wk1 = WeeF + ((17 + 2 * h) * 64 + lane) * 8;
    const int c0 = h * 32 + (lane & 15), c1 = c0 + 16;
    const float qb0 = bn1[c0], qb1 = bn1[c1];
    const float kb0 = bn1[256 + c0], kb1 = bn1[256 + c1];
    for (int pass = 0; pass < 2; ++pass) {
      const f32x4 z = {0.f, 0.f, 0.f, 0.f};
      f32x4 aq0[3] = {z, z, z}, aq1[3] = {z, z, z}, ak0[3] = {z, z, z}, ak1[3] = {z, z, z};
      __builtin_amdgcn_s_setprio(1);
      for (int kt = 0; kt < 8; ++kt) {
        const bf16x8 b0 = *(const bf16x8*)(wq0 + kt * 24576);
        const bf16x8 b1 = *(const bf16x8*)(wq1 + kt * 24576);
        const bf16x8 b2 = *(const bf16x8*)(wk0 + kt * 24576);
        const bf16x8 b3 = *(const bf16x8*)(wk1 + kt * 24576);
        #pragma unroll
        for (int m = 0; m < 3; ++m) {
          const int mt = pass * 3 + m;
          const bf16x8 afr = *(const bf16x8*)(Elds + (mt * 16 + (lane & 15)) * LDE
                                              + ((lane >> 4) << 3) + kt * 32);
          aq0[m] = MFMA(afr, b0, aq0[m]);
          aq1[m] = MFMA(afr, b1, aq1[m]);
          ak0[m] = MFMA(afr, b2, ak0[m]);
          ak1[m] = MFMA(afr, b3, ak1[m]);
        }
      }
      __builtin_amdgcn_s_setprio(0);
      #pragma unroll
      for (int m = 0; m < 3; ++m) {
        const int mt = pass * 3 + m;
        float prod[4];
        #pragma unroll
        for (int r = 0; r < 4; ++r) {
          const int j = mt * 16 + ((lane >> 4) << 2) + r;
          const int g = ((b * 8 + h) * 96 + j) * 32;
          const float q0v = aq0[m][r] + qb0 + n2Q[g + (lane & 15)];
          const float q1v = aq1[m][r] + qb1 + n2Q[g + 16 + (lane & 15)];
          const float k0v = ak0[m][r] + kb0 + n2K[g + (lane & 15)];
          const float k1v = ak1[m][r] + kb1 + n2K[g + 16 + (lane & 15)];
          prod[r] = q0v * k0v + q1v * k1v;
        }
        #pragma unroll
        for (int mm = 1; mm < 16; mm <<= 1) {
          #pragma unroll
          for (int r = 0; r < 4; ++r) prod[r] += __shfl_xor(prod[r], mm, 64);
        }
        if ((lane & 15) == 0) {
          #pragma unroll
          for (int r = 0; r < 4; ++r) {
            const float d = prod[r] * SCALE;
            se[h * 96 + mt * 16 + ((lane >> 4) << 2) + r] = d / (1.f + __expf(-d));
          }
        }
      }
    }
  }

  // ---- Phase B MFMA (reads E only) hoisted before the se barrier ----
  const f32x4 z = {0.f, 0.f, 0.f, 0.f};
  f32x4 acc[6][2] = {{z, z}, {z, z}, {z, z}, {z, z}, {z, z}, {z, z}};
  {
    const unsigned short* wb0 = WeeF + ((32 + wid) * 64 + lane) * 8;
    const unsigned short* wb1 = WeeF + ((40 + wid) * 64 + lane) * 8;
    __builtin_amdgcn_s_setprio(1);
    for (int kt = 0; kt < 8; ++kt) {
      const bf16x8 b0 = *(const bf16x8*)(wb0 + kt * 24576);
      const bf16x8 b1 = *(const bf16x8*)(wb1 + kt * 24576);
      #pragma unroll
      for (int mt = 0; mt < 6; ++mt) {
        const bf16x8 afr = *(const bf16x8*)(Elds + (mt * 16 + (lane & 15)) * LDE
                                            + ((lane >> 4) << 3) + kt * 32);
        acc[mt][0] = MFMA(afr, b0, acc[mt][0]);
        acc[mt][1] = MFMA(afr, b1, acc[mt][1]);
      }
    }
    __builtin_amdgcn_s_setprio(0);
  }
  __syncthreads();                                   // bar2: se done + E reads done

  // ---- Phase B epilogue: attw_e = silu * (Ve+...), write in place ----
  {
    const int col0 = wid * 16 + (lane & 15), col1 = col0 + 128;
    const int h0 = col0 >> 5, cc0 = col0 & 31;
    const int h1 = col1 >> 5, cc1 = col1 & 31;
    const float base0 = bn1[512 + col0], base1 = bn1[512 + col1];
    #pragma unroll
    for (int mt = 0; mt < 6; ++mt) {
      #pragma unroll
      for (int r = 0; r < 4; ++r) {
        const int j = mt * 16 + ((lane >> 4) << 2) + r;
        const float v0 = acc[mt][0][r] + base0 + n2V[((b * 8 + h0) * 96 + j) * 32 + cc0];
        const float v1 = acc[mt][1][r] + base1 + n2V[((b * 8 + h1) * 96 + j) * 32 + cc1];
        Elds[j * LDE + col0] = f2bf(se[h0 * 96 + j] * v0);
        Elds[j * LDE + col1] = f2bf(se[h1 * 96 + j] * v1);
      }
    }
  }
  __syncthreads();                                   // bar3: attw_e published

  // ---- EL1 + relu (kt-outer), in place ----
  {
    #pragma unroll
    for (int mt = 0; mt < 6; ++mt) { acc[mt][0] = z; acc[mt][1] = z; }
    const unsigned short* wb0 = EL1F + (wid * 64 + lane) * 8;
    const unsigned short* wb1 = EL1F + ((wid + 8) * 64 + lane) * 8;
    __builtin_amdgcn_s_setprio(1);
    for (int kt = 0; kt < 8; ++kt) {
      const bf16x8 b0 = *(const bf16x8*)(wb0 + kt * 8192);
      const bf16x8 b1 = *(const bf16x8*)(wb1 + kt * 8192);
      #pragma unroll
      for (int mt = 0; mt < 6; ++mt) {
        const bf16x8 afr = *(const bf16x8*)(Elds + (mt * 16 + (lane & 15)) * LDE
                                            + ((lane >> 4) << 3) + kt * 32);
        acc[mt][0] = MFMA(afr, b0, acc[mt][0]);
        acc[mt][1] = MFMA(afr, b1, acc[mt][1]);
      }
    }
    __builtin_amdgcn_s_setprio(0);
    __syncthreads();                                 // bar4: attw_e reads done
    const int col0 = wid * 16 + (lane & 15), col1 = col0 + 128;
    const float bv0 = b12[col0], bv1 = b12[col1];
    #pragma unroll
    for (int mt = 0; mt < 6; ++mt) {
      #pragma unroll
      for (int r = 0; r < 4; ++r) {
        const int j = mt * 16 + ((lane >> 4) << 2) + r;
        Elds[j * LDE + col0] = f2bf(fmaxf(acc[mt][0][r] + bv0, 0.f));
        Elds[j * LDE + col1] = f2bf(fmaxf(acc[mt][1][r] + bv1, 0.f));
      }
    }
  }
  __syncthreads();                                   // bar5: hidden published

  // ---- EL2 (kt-outer) + residual + batched LayerNorm ----
  {
    #pragma unroll
    for (int mt = 0; mt < 6; ++mt) { acc[mt][0] = z; acc[mt][1] = z; }
    const unsigned short* wb0 = EL2F + (wid * 64 + lane) * 8;
    const unsigned short* wb1 = EL2F + ((wid + 8) * 64 + lane) * 8;
    __builtin_amdgcn_s_setprio(1);
    for (int kt = 0; kt < 8; ++kt) {
      const bf16x8 b0 = *(const bf16x8*)(wb0 + kt * 8192);
      const bf16x8 b1 = *(const bf16x8*)(wb1 + kt * 8192);
      #pragma unroll
      for (int mt = 0; mt < 6; ++mt) {
        const bf16x8 afr = *(const bf16x8*)(Elds + (mt * 16 + (lane & 15)) * LDE
                                            + ((lane >> 4) << 3) + kt * 32);
        acc[mt][0] = MFMA(afr, b0, acc[mt][0]);
        acc[mt][1] = MFMA(afr, b1, acc[mt][1]);
      }
    }
    __builtin_amdgcn_s_setprio(0);
    const int col0 = wid * 16 + (lane & 15), col1 = col0 + 128;
    const float bv0 = b12[256 + col0], bv1 = b12[256 + col1];
    const float g0 = lg[col0], g1 = lg[col1], be0 = lb[col0], be1 = lb[col1];
    __syncthreads();                                 // bar6: hidden reads done (se/bn1 free)
    #pragma unroll
    for (int mt = 0; mt < 6; ++mt) {
      #pragma unroll
      for (int r = 0; r < 4; ++r) {
        const int j = mt * 16 + ((lane >> 4) << 2) + r;
        acc[mt][0][r] += bv0 + Erow[j * 256 + col0];
        acc[mt][1][r] += bv1 + Erow[j * 256 + col1];
      }
    }
    #pragma unroll
    for (int mt = 0; mt < 6; ++mt) {
      #pragma unroll
      for (int r = 0; r < 4; ++r) {
        float s = acc[mt][0][r] + acc[mt][1][r];
        float q = acc[mt][0][r] * acc[mt][0][r] + acc[mt][1][r] * acc[mt][1][r];
        #pragma unroll
        for (int m = 1; m < 16; m <<= 1) { s += __shfl_xor(s, m, 64); q += __shfl_xor(q, m, 64); }
        if ((lane & 15) == 0) {
          const int j = mt * 16 + ((lane >> 4) << 2) + r;
          se[wid * 96 + j] = s; bn1[wid * 96 + j] = q;
        }
      }
    }
    __syncthreads();                                 // bar7: partials published
    if (tid < 96) {
      float s = 0.f, q = 0.f;
      #pragma unroll
      for (int w = 0; w < 8; ++w) { s += se[w * 96 + tid]; q += bn1[w * 96 + tid]; }
      const float mean = s * (1.f / 256.f);
      b12[tid] = mean;
      b12[96 + tid] = rsqrtf(q * (1.f / 256.f) - mean * mean + 1e-5f);
    }
    __syncthreads();                                 // bar8: stats published
    #pragma unroll
    for (int mt = 0; mt < 6; ++mt) {
      #pragma unroll
      for (int r = 0; r < 4; ++r) {
        const int j = mt * 16 + ((lane >> 4) << 2) + r;
        const float mean = b12[j], rs = b12[96 + j];
        Elds[j * LDE + col0] = f2bf((acc[mt][0][r] - mean) * rs * g0 + be0);
        Elds[j * LDE + col1] = f2bf((acc[mt][1][r] - mean) * rs * g1 + be1);
      }
    }
  }
  __syncthreads();                                   // bar9: LN out staged

  // ---- coalesced fp32 writeback: full 1KB rows ----
  float* orow = edge_out + bi * 24576;
  for (int j = wid; j < 96; j += 8) {
    const uint2 pk = *(const uint2*)(Elds + j * LDE + (lane << 2));
    float4 o;
    o.x = bf2f((unsigned short)(pk.x & 0xffff));
    o.y = bf2f((unsigned short)(pk.x >> 16));
    o.z = bf2f((unsigned short)(pk.y & 0xffff));
    o.w = bf2f((unsigned short)(pk.y >> 16));
    *(float4*)(orow + j * 256 + (lane << 2)) = o;
  }
}

// ---------------------------------------------------------------------------
extern "C" void kernel_launch(void* const* d_in, const int* in_sizes, int n_in,
                              void* d_out, int out_size, void* d_ws, size_t ws_size,
                              hipStream_t stream)
{
  (void)in_sizes; (void)n_in; (void)out_size; (void)ws_size;

  const float* node   = (const float*)d_in[0];
  const float* edge   = (const float*)d_in[1];
  const float* Wn_w   = (const float*)d_in[2];
  const float* Wn_b   = (const float*)d_in[3];
  const float* We_w   = (const float*)d_in[4];
  const float* We_b   = (const float*)d_in[5];
  const float* Wn1_w  = (const float*)d_in[6];
  const float* Wn1_b  = (const float*)d_in[7];
  const float* Wn2_w  = (const float*)d_in[8];
  const float* Wn2_b  = (const float*)d_in[9];
  const float* Wee_w  = (const float*)d_in[10];
  const float* Wee_b  = (const float*)d_in[11];
  const float* NL1_w  = (const float*)d_in[12];
  const float* NL1_b  = (const float*)d_in[13];
  const float* NL2_w  = (const float*)d_in[14];
  const float* NL2_b  = (const float*)d_in[15];
  const float* EL1_w  = (const float*)d_in[16];
  const float* EL1_b  = (const float*)d_in[17];
  const float* EL2_w  = (const float*)d_in[18];
  const float* EL2_b  = (const float*)d_in[19];
  const float* NLN1_g = (const float*)d_in[20];
  const float* NLN1_b = (const float*)d_in[21];
  const float* ELN1_g = (const float*)d_in[22];
  const float* ELN1_b = (const float*)d_in[23];

  float* out = (float*)d_out;
  float* node_out = out;               // [8,96,256]
  float* edge_out = out + 196608;      // [8,96,96,256]

  float* wsf = (float*)d_ws;
  float* nQ  = wsf;                float* nK  = wsf + 196608;   float* nV  = wsf + 393216;
  float* n1Q = wsf + 589824;       float* n1K = wsf + 786432;   float* n1V = wsf + 983040;
  float* n2Q = wsf + 1179648;      float* n2K = wsf + 1376256;  float* n2V = wsf + 1572864;
  float* attw = wsf + 1769472;
  unsigned short* fb   = (unsigned short*)(wsf + 1966080);
  unsigned short* WeF  = fb;                 // 196608
  unsigned short* WeeF = fb + 196608;        // 196608
  unsigned short* EL1F = fb + 393216;        // 65536
  unsigned short* EL2F = fb + 458752;        // 65536
  unsigned short* NL1F = fb + 524288;        // 65536
  unsigned short* NL2F = fb + 589824;        // 65536
  unsigned short* Wn1F = fb + 655360;        // 196608
  unsigned short* Wn2F = fb + 851968;        // 196608

  prep_and_qkv<<<320, 256, 0, stream>>>(We_w, Wee_w, EL1_w, EL2_w,
                                        NL1_w, NL2_w, Wn1_w, Wn2_w, fb,
                                        node, Wn_w, Wn_b, nQ, nK, nV);
  node_attn<<<768, 512, 0, stream>>>(edge, We_b, WeF, nQ, nK, nV, attw);
  node_tail<<<48, 256, 0, stream>>>(attw, node, NL1F, NL1_b, NL2F, NL2_b,
                                    NLN1_g, NLN1_b, Wn1F, Wn1_b, Wn2F, Wn2_b,
                                    node_out, n1Q, n1K, n1V, n2Q, n2K, n2V);
  edge_update<<<768, 512, 0, stream>>>(edge, Wee_b, WeeF, EL1F, EL2F,
                                       EL1_b, EL2_b, n1Q, n1K, n1V,
                                       n2Q, n2K, n2V, ELN1_g, ELN1_b, edge_out);
}